// Round 1
// baseline (5004.719 us; speedup 1.0000x reference)
//
#include <hip/hip_runtime.h>
#include <hip/hip_bf16.h>
#include <math.h>

#define NTOK 8000
#define KCAP 3200
#define BATCH 2
#define DM 256
#define DFF 1024

__device__ __forceinline__ float gelu_tanh(float x) {
  const float x3 = x * x * x;
  return 0.5f * x * (1.0f + tanhf(0.7978845608028654f * (x + 0.044715f * x3)));
}

// ---- top-k: rank each token's salience; ranks < KCAP fill sorted index list ----
__global__ __launch_bounds__(256) void topk_kernel(const float* __restrict__ sal,
                                                   int* __restrict__ sidx) {
  const int b = blockIdx.x >> 5;    // 32 blocks per batch
  const int blk = blockIdx.x & 31;
  __shared__ float s[NTOK];
  const float* sb = sal + (size_t)b * NTOK;
  for (int j = threadIdx.x; j < NTOK; j += 256) s[j] = sb[j];
  __syncthreads();
  const int i = blk * 256 + threadIdx.x;
  if (i >= NTOK) return;
  const float si = s[i];
  int rank = 0;
#pragma unroll 4
  for (int j = 0; j < NTOK; ++j) {
    const float sj = s[j];
    rank += (int)((sj > si) || (sj == si && j < i));
  }
  if (rank < KCAP) sidx[b * KCAP + rank] = i;
}

// ---- gather selected tokens + LayerNorm1 (writes x and h) ----
__global__ __launch_bounds__(256) void gather_ln_kernel(
    const float* __restrict__ feat, const int* __restrict__ sidx,
    const float* __restrict__ g, const float* __restrict__ bb,
    float* __restrict__ x, float* __restrict__ h, int klen) {
  const int m = blockIdx.x;
  const int b = m / klen;
  const int t = m - b * klen;
  const int tok = sidx[b * KCAP + t];
  const int c = threadIdx.x;
  const float val = feat[((size_t)(b * NTOK + tok)) * DM + c];
  x[((size_t)(b * KCAP + t)) * DM + c] = val;
  __shared__ float red[256];
  red[c] = val;
  __syncthreads();
#pragma unroll
  for (int s = 128; s > 0; s >>= 1) {
    if (c < s) red[c] += red[c + s];
    __syncthreads();
  }
  const float mu = red[0] * (1.0f / DM);
  __syncthreads();
  const float dv = val - mu;
  red[c] = dv * dv;
  __syncthreads();
#pragma unroll
  for (int s = 128; s > 0; s >>= 1) {
    if (c < s) red[c] += red[c + s];
    __syncthreads();
  }
  const float var = red[0] * (1.0f / DM);
  h[((size_t)(b * KCAP + t)) * DM + c] = dv * rsqrtf(var + 1e-5f) * g[c] + bb[c];
}

// ---- LayerNorm2 (x buffer -> h buffer) ----
__global__ __launch_bounds__(256) void ln_kernel(
    const float* __restrict__ x, const float* __restrict__ g,
    const float* __restrict__ bb, float* __restrict__ h, int klen) {
  const int m = blockIdx.x;
  const int b = m / klen;
  const int t = m - b * klen;
  const int c = threadIdx.x;
  const float val = x[((size_t)(b * KCAP + t)) * DM + c];
  __shared__ float red[256];
  red[c] = val;
  __syncthreads();
#pragma unroll
  for (int s = 128; s > 0; s >>= 1) {
    if (c < s) red[c] += red[c + s];
    __syncthreads();
  }
  const float mu = red[0] * (1.0f / DM);
  __syncthreads();
  const float dv = val - mu;
  red[c] = dv * dv;
  __syncthreads();
#pragma unroll
  for (int s = 128; s > 0; s >>= 1) {
    if (c < s) red[c] += red[c + s];
    __syncthreads();
  }
  const float var = red[0] * (1.0f / DM);
  h[((size_t)(b * KCAP + t)) * DM + c] = dv * rsqrtf(var + 1e-5f) * g[c] + bb[c];
}

// ---- GEMM: C[m,j] = act(A[m,:] @ W[:,j]) (+Res). 8 rows x 256 cols per block ----
template <int ACT, bool RES>
__global__ __launch_bounds__(256) void rowgemm_kernel(
    const float* __restrict__ A, const float* __restrict__ W,
    const float* __restrict__ Res, float* __restrict__ C,
    int klen, int K, int Ncols) {
  extern __shared__ float at[];  // [K][8] transposed A tile
  const int rowsPerB = klen >> 3;
  const int b = blockIdx.x / rowsPerB;
  const int t0 = (blockIdx.x - b * rowsPerB) << 3;
  const int tid = threadIdx.x;
  const int total = K << 3;
  for (int e = tid; e < total; e += 256) {
    const int r = e / K;
    const int c = e - r * K;
    at[c * 8 + r] = A[((size_t)(b * KCAP + t0 + r)) * K + c];
  }
  __syncthreads();
  const int j = blockIdx.y * 256 + tid;
  float acc[8] = {0.f, 0.f, 0.f, 0.f, 0.f, 0.f, 0.f, 0.f};
  const float* Wp = W + j;
#pragma unroll 4
  for (int c = 0; c < K; ++c) {
    const float w = Wp[(size_t)c * Ncols];
    const float4 a0 = *reinterpret_cast<const float4*>(&at[c * 8]);
    const float4 a1 = *reinterpret_cast<const float4*>(&at[c * 8 + 4]);
    acc[0] = fmaf(a0.x, w, acc[0]);
    acc[1] = fmaf(a0.y, w, acc[1]);
    acc[2] = fmaf(a0.z, w, acc[2]);
    acc[3] = fmaf(a0.w, w, acc[3]);
    acc[4] = fmaf(a1.x, w, acc[4]);
    acc[5] = fmaf(a1.y, w, acc[5]);
    acc[6] = fmaf(a1.z, w, acc[6]);
    acc[7] = fmaf(a1.w, w, acc[7]);
  }
#pragma unroll
  for (int r = 0; r < 8; ++r) {
    const size_t off = ((size_t)(b * KCAP + t0 + r)) * Ncols + j;
    float v = acc[r];
    if (ACT == 1) v = gelu_tanh(v);
    C[off] = RES ? (Res[off] + v) : v;
  }
}

// ---- flash-style attention: 2 queries/thread, 64-key LDS tiles, online softmax ----
__global__ __launch_bounds__(256, 2) void attn_kernel(
    const float* __restrict__ Q, const float* __restrict__ Kb,
    const float* __restrict__ Vb, float* __restrict__ O, int klen) {
  const int hh = blockIdx.y;
  const int b = blockIdx.z;
  const int tid = threadIdx.x;
  const int t0 = blockIdx.x * 512;
  __shared__ float kl[64 * 32];
  __shared__ float vl[64 * 32];
  const int tA = t0 + tid, tB = t0 + 256 + tid;
  const bool aA = tA < klen, aB = tB < klen;
  const int cA = aA ? tA : (klen - 1);
  const int cB = aB ? tB : (klen - 1);
  float qA[32], qB[32];
  {
    const float4* qp = reinterpret_cast<const float4*>(Q + ((size_t)(b * KCAP + cA)) * DM + hh * 32);
    const float4* qp2 = reinterpret_cast<const float4*>(Q + ((size_t)(b * KCAP + cB)) * DM + hh * 32);
#pragma unroll
    for (int i = 0; i < 8; ++i) {
      const float4 f = qp[i];
      qA[4 * i] = f.x; qA[4 * i + 1] = f.y; qA[4 * i + 2] = f.z; qA[4 * i + 3] = f.w;
      const float4 f2 = qp2[i];
      qB[4 * i] = f2.x; qB[4 * i + 1] = f2.y; qB[4 * i + 2] = f2.z; qB[4 * i + 3] = f2.w;
    }
  }
  float mA = -INFINITY, mB = -INFINITY, lA = 0.f, lB = 0.f;
  float oA[32], oB[32];
#pragma unroll
  for (int d = 0; d < 32; ++d) { oA[d] = 0.f; oB[d] = 0.f; }
  const float scale = 0.17677669529663687f;  // 1/sqrt(32)
  const int ntile = (klen + 63) >> 6;
  for (int kt = 0; kt < ntile; ++kt) {
    const int base = kt << 6;
    __syncthreads();
#pragma unroll
    for (int i = 0; i < 8; ++i) {
      const int e = tid + i * 256;
      const int kr = e >> 5, kd = e & 31;
      const int kk = base + kr;
      float kv = 0.f, vv = 0.f;
      if (kk < klen) {
        const size_t off = ((size_t)(b * KCAP + kk)) * DM + hh * 32 + kd;
        kv = Kb[off];
        vv = Vb[off];
      }
      kl[e] = kv;
      vl[e] = vv;
    }
    __syncthreads();
    const int jmax = min(64, klen - base);
    for (int j = 0; j < jmax; ++j) {
      float sA = 0.f, sB = 0.f;
#pragma unroll
      for (int d = 0; d < 32; ++d) {
        const float kv = kl[j * 32 + d];
        sA = fmaf(qA[d], kv, sA);
        sB = fmaf(qB[d], kv, sB);
      }
      sA *= scale;
      sB *= scale;
      const float nmA = fmaxf(mA, sA);
      const float corA = __expf(mA - nmA);
      const float pA = __expf(sA - nmA);
      mA = nmA;
      lA = lA * corA + pA;
      const float nmB = fmaxf(mB, sB);
      const float corB = __expf(mB - nmB);
      const float pB = __expf(sB - nmB);
      mB = nmB;
      lB = lB * corB + pB;
#pragma unroll
      for (int d = 0; d < 32; ++d) {
        const float vv = vl[j * 32 + d];
        oA[d] = fmaf(oA[d], corA, pA * vv);
        oB[d] = fmaf(oB[d], corB, pB * vv);
      }
    }
  }
  if (aA) {
    const float inv = 1.0f / lA;
    float4* op = reinterpret_cast<float4*>(O + ((size_t)(b * KCAP + tA)) * DM + hh * 32);
#pragma unroll
    for (int i = 0; i < 8; ++i) {
      float4 f;
      f.x = oA[4 * i] * inv; f.y = oA[4 * i + 1] * inv;
      f.z = oA[4 * i + 2] * inv; f.w = oA[4 * i + 3] * inv;
      op[i] = f;
    }
  }
  if (aB) {
    const float inv = 1.0f / lB;
    float4* op = reinterpret_cast<float4*>(O + ((size_t)(b * KCAP + tB)) * DM + hh * 32);
#pragma unroll
    for (int i = 0; i < 8; ++i) {
      float4 f;
      f.x = oB[4 * i] * inv; f.y = oB[4 * i + 1] * inv;
      f.z = oB[4 * i + 2] * inv; f.w = oB[4 * i + 3] * inv;
      op[i] = f;
    }
  }
}

// ---- scatter updated tokens back into the feature bank ----
__global__ __launch_bounds__(256) void scatter_kernel(
    const float* __restrict__ x, const int* __restrict__ sidx,
    float* __restrict__ feat, int klen) {
  const int m = blockIdx.x;
  const int b = m / klen;
  const int t = m - b * klen;
  const int tok = sidx[b * KCAP + t];
  feat[((size_t)(b * NTOK + tok)) * DM + threadIdx.x] =
      x[((size_t)(b * KCAP + t)) * DM + threadIdx.x];
}

extern "C" void kernel_launch(void* const* d_in, const int* in_sizes, int n_in,
                              void* d_out, int out_size, void* d_ws, size_t ws_size,
                              hipStream_t stream) {
  (void)in_sizes; (void)n_in; (void)out_size; (void)ws_size;
  const float* features = (const float*)d_in[0];
  const float* salience = (const float*)d_in[1];
  const float* Wq = (const float*)d_in[2];
  const float* Wk = (const float*)d_in[3];
  const float* Wv = (const float*)d_in[4];
  const float* Wo = (const float*)d_in[5];
  const float* W1 = (const float*)d_in[6];
  const float* W2 = (const float*)d_in[7];
  const float* ln1g = (const float*)d_in[8];
  const float* ln1b = (const float*)d_in[9];
  const float* ln2g = (const float*)d_in[10];
  const float* ln2b = (const float*)d_in[11];
  float* out = (float*)d_out;

  // workspace layout (bytes):
  //   [0, 32768)                 : sorted top-k indices (B*KCAP ints)
  //   x  : B*KCAP*DM floats      (6.55 MB)
  //   h  : B*KCAP*DM floats      (6.55 MB)
  //   big: B*KCAP*DFF floats     (26.2 MB) — holds q|k|v|o, later overlaid by ffn
  char* ws = (char*)d_ws;
  int* sidx = (int*)ws;
  float* xb = (float*)(ws + 32768);
  const size_t SLAB = (size_t)BATCH * KCAP * DM;
  float* hb = xb + SLAB;
  float* big = hb + SLAB;
  float* qb = big;
  float* kb = big + SLAB;
  float* vb = big + 2 * SLAB;
  float* ob = big + 3 * SLAB;
  float* fb = big;  // ffn intermediate overlays q|k|v|o (all consumed by then)

  hipMemcpyAsync(out, features, (size_t)BATCH * NTOK * DM * sizeof(float),
                 hipMemcpyDeviceToDevice, stream);
  topk_kernel<<<64, 256, 0, stream>>>(salience, sidx);

  const int klens[4] = {3200, 2400, 2000, 1600};
  for (int l = 0; l < 4; ++l) {
    const int klen = klens[l];
    const int MB = BATCH * klen;
    const int GB = BATCH * (klen >> 3);
    const size_t wOff = (size_t)l * DM * DM;
    gather_ln_kernel<<<MB, 256, 0, stream>>>(out, sidx, ln1g + l * DM, ln1b + l * DM, xb, hb, klen);
    rowgemm_kernel<0, false><<<dim3(GB, 1), 256, 8 * DM * 4, stream>>>(hb, Wq + wOff, nullptr, qb, klen, DM, DM);
    rowgemm_kernel<0, false><<<dim3(GB, 1), 256, 8 * DM * 4, stream>>>(hb, Wk + wOff, nullptr, kb, klen, DM, DM);
    rowgemm_kernel<0, false><<<dim3(GB, 1), 256, 8 * DM * 4, stream>>>(hb, Wv + wOff, nullptr, vb, klen, DM, DM);
    attn_kernel<<<dim3((klen + 511) / 512, 8, BATCH), 256, 0, stream>>>(qb, kb, vb, ob, klen);
    rowgemm_kernel<0, true><<<dim3(GB, 1), 256, 8 * DM * 4, stream>>>(ob, Wo + wOff, xb, xb, klen, DM, DM);
    ln_kernel<<<MB, 256, 0, stream>>>(xb, ln2g + l * DM, ln2b + l * DM, hb, klen);
    rowgemm_kernel<1, false><<<dim3(GB, 4), 256, 8 * DM * 4, stream>>>(hb, W1 + (size_t)l * DM * DFF, nullptr, fb, klen, DM, DFF);
    rowgemm_kernel<0, true><<<dim3(GB, 1), 256, 8 * DFF * 4, stream>>>(fb, W2 + (size_t)l * DFF * DM, xb, xb, klen, DFF, DM);
    scatter_kernel<<<MB, 256, 0, stream>>>(xb, sidx, out, klen);
  }
}

// Round 2
// 3038.256 us; speedup vs baseline: 1.6472x; 1.6472x over previous
//
#include <hip/hip_runtime.h>
#include <hip/hip_bf16.h>
#include <math.h>

#define NTOK 8000
#define KCAP 3200
#define BATCH 2
#define DM 256
#define DFF 1024

__device__ __forceinline__ float gelu_tanh(float x) {
  const float x3 = x * x * x;
  return 0.5f * x * (1.0f + tanhf(0.7978845608028654f * (x + 0.044715f * x3)));
}

// LDS XOR swizzle: bijective on float index, preserves float4 alignment
__device__ __forceinline__ int swz1(int a) { return a ^ (((a >> 6) & 7) << 2); }
__device__ __forceinline__ int swz4(int fi) { return fi ^ ((fi >> 4) & 7); }

// ---- top-k: rank each token's salience; ranks < KCAP fill sorted index list ----
__global__ __launch_bounds__(256) void topk_kernel(const float* __restrict__ sal,
                                                   int* __restrict__ sidx) {
  const int b = blockIdx.x >> 5;  // 32 blocks per batch
  const int blk = blockIdx.x & 31;
  __shared__ float s[NTOK];
  const float* sb = sal + (size_t)b * NTOK;
  for (int j = threadIdx.x; j < NTOK; j += 256) s[j] = sb[j];
  __syncthreads();
  const int i = blk * 256 + threadIdx.x;
  if (i >= NTOK) return;
  const float si = s[i];
  int rank = 0;
#pragma unroll 4
  for (int j = 0; j < NTOK; ++j) {
    const float sj = s[j];
    rank += (int)((sj > si) || (sj == si && j < i));
  }
  if (rank < KCAP) sidx[b * KCAP + rank] = i;
}

// ---- gather selected tokens + LayerNorm1 (writes x and h) ----
__global__ __launch_bounds__(256) void gather_ln_kernel(
    const float* __restrict__ feat, const int* __restrict__ sidx,
    const float* __restrict__ g, const float* __restrict__ bb,
    float* __restrict__ x, float* __restrict__ h, int klen) {
  const int m = blockIdx.x;
  const int b = m / klen;
  const int t = m - b * klen;
  const int tok = sidx[b * KCAP + t];
  const int c = threadIdx.x;
  const float val = feat[((size_t)(b * NTOK + tok)) * DM + c];
  x[((size_t)(b * KCAP + t)) * DM + c] = val;
  __shared__ float red[256];
  red[c] = val;
  __syncthreads();
#pragma unroll
  for (int s = 128; s > 0; s >>= 1) {
    if (c < s) red[c] += red[c + s];
    __syncthreads();
  }
  const float mu = red[0] * (1.0f / DM);
  __syncthreads();
  const float dv = val - mu;
  red[c] = dv * dv;
  __syncthreads();
#pragma unroll
  for (int s = 128; s > 0; s >>= 1) {
    if (c < s) red[c] += red[c + s];
    __syncthreads();
  }
  const float var = red[0] * (1.0f / DM);
  h[((size_t)(b * KCAP + t)) * DM + c] = dv * rsqrtf(var + 1e-5f) * g[c] + bb[c];
}

// ---- LayerNorm2 (x buffer -> h buffer) ----
__global__ __launch_bounds__(256) void ln_kernel(
    const float* __restrict__ x, const float* __restrict__ g,
    const float* __restrict__ bb, float* __restrict__ h, int klen) {
  const int m = blockIdx.x;
  const int b = m / klen;
  const int t = m - b * klen;
  const int c = threadIdx.x;
  const float val = x[((size_t)(b * KCAP + t)) * DM + c];
  __shared__ float red[256];
  red[c] = val;
  __syncthreads();
#pragma unroll
  for (int s = 128; s > 0; s >>= 1) {
    if (c < s) red[c] += red[c + s];
    __syncthreads();
  }
  const float mu = red[0] * (1.0f / DM);
  __syncthreads();
  const float dv = val - mu;
  red[c] = dv * dv;
  __syncthreads();
#pragma unroll
  for (int s = 128; s > 0; s >>= 1) {
    if (c < s) red[c] += red[c + s];
    __syncthreads();
  }
  const float var = red[0] * (1.0f / DM);
  h[((size_t)(b * KCAP + t)) * DM + c] = dv * rsqrtf(var + 1e-5f) * g[c] + bb[c];
}

// ---- GEMM body: C[m,j] = act(A[m,:] @ W[:,j]) (+Res). ROWS rows x 256 cols / block ----
template <int ACT, bool RES, int ROWS, int K, int NC>
__device__ __forceinline__ void gemm_body(
    float* at, const float* __restrict__ A, const float* __restrict__ W,
    const float* __restrict__ Res, float* __restrict__ C, int klen,
    int bx, int by) {
  const int rowsPerB = klen / ROWS;
  const int b = bx / rowsPerB;
  const int t0 = (bx - b * rowsPerB) * ROWS;
  const int tid = threadIdx.x;
  constexpr int NF4 = ROWS * K / 4;  // total float4 in A tile
  constexpr int F4PR = K / 4;        // float4 per row
#pragma unroll
  for (int e4 = tid; e4 < NF4; e4 += 256) {
    const int r = e4 / F4PR;
    const int c4 = e4 - r * F4PR;
    const float4 av =
        reinterpret_cast<const float4*>(A + ((size_t)(b * KCAP + t0 + r)) * K)[c4];
    const int cb = c4 * 4;
    at[swz1((cb + 0) * ROWS + r)] = av.x;
    at[swz1((cb + 1) * ROWS + r)] = av.y;
    at[swz1((cb + 2) * ROWS + r)] = av.z;
    at[swz1((cb + 3) * ROWS + r)] = av.w;
  }
  __syncthreads();
  const int j = by * 256 + tid;
  float acc[ROWS];
#pragma unroll
  for (int r = 0; r < ROWS; ++r) acc[r] = 0.f;
  const float* Wp = W + j;
  const float4* at4 = reinterpret_cast<const float4*>(at);
  constexpr int R4 = ROWS / 4;
#pragma unroll 4
  for (int c = 0; c < K; ++c) {
    const float w = Wp[(size_t)c * NC];
#pragma unroll
    for (int k = 0; k < R4; ++k) {
      const float4 a = at4[swz4(c * R4 + k)];
      acc[4 * k + 0] = fmaf(a.x, w, acc[4 * k + 0]);
      acc[4 * k + 1] = fmaf(a.y, w, acc[4 * k + 1]);
      acc[4 * k + 2] = fmaf(a.z, w, acc[4 * k + 2]);
      acc[4 * k + 3] = fmaf(a.w, w, acc[4 * k + 3]);
    }
  }
#pragma unroll
  for (int r = 0; r < ROWS; ++r) {
    const size_t off = ((size_t)(b * KCAP + t0 + r)) * NC + j;
    float v = acc[r];
    if (ACT == 1) v = gelu_tanh(v);
    C[off] = RES ? (Res[off] + v) : v;
  }
}

template <int ACT, bool RES, int ROWS, int K, int NC>
__global__ __launch_bounds__(256) void gemm_kernel(
    const float* __restrict__ A, const float* __restrict__ W,
    const float* __restrict__ Res, float* __restrict__ C, int klen) {
  __shared__ float at[K * ROWS];
  gemm_body<ACT, RES, ROWS, K, NC>(at, A, W, Res, C, klen, blockIdx.x, blockIdx.y);
}

// fused Q/K/V projection: blockIdx.z selects weight + output slab
__global__ __launch_bounds__(256) void qkv_kernel(
    const float* __restrict__ A, const float* __restrict__ Wq,
    const float* __restrict__ Wk, const float* __restrict__ Wv,
    float* __restrict__ Obase, int klen) {
  __shared__ float at[256 * 16];
  const float* W = blockIdx.z == 0 ? Wq : (blockIdx.z == 1 ? Wk : Wv);
  float* C = Obase + (size_t)blockIdx.z * ((size_t)BATCH * KCAP * DM);
  gemm_body<0, false, 16, 256, 256>(at, A, W, nullptr, C, klen, blockIdx.x, 0);
}

// ---- attention: 4 threads/query (8-dim slices), 64 queries/block, defer-max softmax ----
__global__ __launch_bounds__(256) void attn_kernel(
    const float* __restrict__ Q, const float* __restrict__ Kb,
    const float* __restrict__ Vb, float* __restrict__ O, int klen) {
  const int hh = blockIdx.y, b = blockIdx.z, tid = threadIdx.x;
  const int q = blockIdx.x * 64 + (tid >> 2);
  const int qc = q < klen ? q : klen - 1;
  const int d0 = (tid & 3) * 8;
  __shared__ float4 kl[512];  // 64 keys x 32 dims
  __shared__ float4 vl[512];
  const float scale = 0.17677669529663687f;  // 1/sqrt(32)
  const float4* qp =
      reinterpret_cast<const float4*>(Q + ((size_t)(b * KCAP + qc)) * DM + hh * 32 + d0);
  float4 qv0 = qp[0], qv1 = qp[1];
  qv0.x *= scale; qv0.y *= scale; qv0.z *= scale; qv0.w *= scale;
  qv1.x *= scale; qv1.y *= scale; qv1.z *= scale; qv1.w *= scale;
  float m = -INFINITY, l = 0.f;
  float o[8] = {0.f, 0.f, 0.f, 0.f, 0.f, 0.f, 0.f, 0.f};
  const float4* K4 = reinterpret_cast<const float4*>(Kb);
  const float4* V4 = reinterpret_cast<const float4*>(Vb);
  const int ntile = (klen + 63) >> 6;
  for (int kt = 0; kt < ntile; ++kt) {
    const int base = kt << 6;
    __syncthreads();
#pragma unroll
    for (int i = 0; i < 2; ++i) {
      const int idx4 = tid + i * 256;
      const int row = idx4 >> 3, dim4 = idx4 & 7;
      const int kk = base + row;
      float4 kv = {0.f, 0.f, 0.f, 0.f}, vv = {0.f, 0.f, 0.f, 0.f};
      if (kk < klen) {
        const size_t off4 = ((size_t)(b * KCAP + kk)) * (DM / 4) + hh * 8 + dim4;
        kv = K4[off4];
        vv = V4[off4];
      }
      kl[idx4] = kv;
      vl[idx4] = vv;
    }
    __syncthreads();
    const int jmax = min(64, klen - base);
#pragma unroll 2
    for (int j = 0; j < jmax; ++j) {
      const int kb4 = j * 8 + (tid & 3) * 2;
      const float4 k0 = kl[kb4], k1 = kl[kb4 + 1];
      float s = qv0.x * k0.x;
      s = fmaf(qv0.y, k0.y, s);
      s = fmaf(qv0.z, k0.z, s);
      s = fmaf(qv0.w, k0.w, s);
      s = fmaf(qv1.x, k1.x, s);
      s = fmaf(qv1.y, k1.y, s);
      s = fmaf(qv1.z, k1.z, s);
      s = fmaf(qv1.w, k1.w, s);
      s += __shfl_xor(s, 1, 64);
      s += __shfl_xor(s, 2, 64);
      const float dlt = s - m;
      float p;
      if (dlt > 8.0f) {  // new max beyond slack: rescale (rare, ~ln(klen) times)
        const float cor = __expf(-dlt);
        l *= cor;
#pragma unroll
        for (int d = 0; d < 8; ++d) o[d] *= cor;
        m = s;
        p = 1.0f;
      } else {
        p = __expf(dlt);  // bounded by e^8; fp32 accumulators have headroom
      }
      l += p;
      const float4 v0 = vl[kb4], v1 = vl[kb4 + 1];
      o[0] = fmaf(p, v0.x, o[0]);
      o[1] = fmaf(p, v0.y, o[1]);
      o[2] = fmaf(p, v0.z, o[2]);
      o[3] = fmaf(p, v0.w, o[3]);
      o[4] = fmaf(p, v1.x, o[4]);
      o[5] = fmaf(p, v1.y, o[5]);
      o[6] = fmaf(p, v1.z, o[6]);
      o[7] = fmaf(p, v1.w, o[7]);
    }
  }
  if (q < klen) {
    const float inv = 1.0f / l;
    float4* op =
        reinterpret_cast<float4*>(O + ((size_t)(b * KCAP + q)) * DM + hh * 32 + d0);
    float4 f0 = {o[0] * inv, o[1] * inv, o[2] * inv, o[3] * inv};
    float4 f1 = {o[4] * inv, o[5] * inv, o[6] * inv, o[7] * inv};
    op[0] = f0;
    op[1] = f1;
  }
}

// ---- scatter updated tokens back into the feature bank ----
__global__ __launch_bounds__(256) void scatter_kernel(
    const float* __restrict__ x, const int* __restrict__ sidx,
    float* __restrict__ feat, int klen) {
  const int m = blockIdx.x;
  const int b = m / klen;
  const int t = m - b * klen;
  const int tok = sidx[b * KCAP + t];
  feat[((size_t)(b * NTOK + tok)) * DM + threadIdx.x] =
      x[((size_t)(b * KCAP + t)) * DM + threadIdx.x];
}

extern "C" void kernel_launch(void* const* d_in, const int* in_sizes, int n_in,
                              void* d_out, int out_size, void* d_ws, size_t ws_size,
                              hipStream_t stream) {
  (void)in_sizes; (void)n_in; (void)out_size; (void)ws_size;
  const float* features = (const float*)d_in[0];
  const float* salience = (const float*)d_in[1];
  const float* Wq = (const float*)d_in[2];
  const float* Wk = (const float*)d_in[3];
  const float* Wv = (const float*)d_in[4];
  const float* Wo = (const float*)d_in[5];
  const float* W1 = (const float*)d_in[6];
  const float* W2 = (const float*)d_in[7];
  const float* ln1g = (const float*)d_in[8];
  const float* ln1b = (const float*)d_in[9];
  const float* ln2g = (const float*)d_in[10];
  const float* ln2b = (const float*)d_in[11];
  float* out = (float*)d_out;

  // workspace layout:
  //   [0, 32768)            : sorted top-k indices (B*KCAP ints)
  //   x  : B*KCAP*DM floats (6.55 MB)
  //   h  : B*KCAP*DM floats (6.55 MB)
  //   big: B*KCAP*DFF floats (26.2 MB) — q|k|v|o, later overlaid by ffn
  char* ws = (char*)d_ws;
  int* sidx = (int*)ws;
  float* xb = (float*)(ws + 32768);
  const size_t SLAB = (size_t)BATCH * KCAP * DM;
  float* hb = xb + SLAB;
  float* big = hb + SLAB;
  float* qb = big;
  float* kb = big + SLAB;
  float* vb = big + 2 * SLAB;
  float* ob = big + 3 * SLAB;
  float* fb = big;  // ffn intermediate overlays q|k|v|o (all consumed by then)

  hipMemcpyAsync(out, features, (size_t)BATCH * NTOK * DM * sizeof(float),
                 hipMemcpyDeviceToDevice, stream);
  topk_kernel<<<64, 256, 0, stream>>>(salience, sidx);

  const int klens[4] = {3200, 2400, 2000, 1600};
  for (int l = 0; l < 4; ++l) {
    const int klen = klens[l];
    const int MB = BATCH * klen;
    const size_t wOff = (size_t)l * DM * DM;
    gather_ln_kernel<<<MB, 256, 0, stream>>>(out, sidx, ln1g + l * DM, ln1b + l * DM,
                                             xb, hb, klen);
    qkv_kernel<<<dim3(BATCH * klen / 16, 1, 3), 256, 0, stream>>>(
        hb, Wq + wOff, Wk + wOff, Wv + wOff, qb, klen);
    attn_kernel<<<dim3((klen + 63) / 64, 8, BATCH), 256, 0, stream>>>(qb, kb, vb, ob,
                                                                      klen);
    gemm_kernel<0, true, 16, 256, 256><<<dim3(BATCH * klen / 16, 1), 256, 0, stream>>>(
        ob, Wo + wOff, xb, xb, klen);
    ln_kernel<<<MB, 256, 0, stream>>>(xb, ln2g + l * DM, ln2b + l * DM, hb, klen);
    gemm_kernel<1, false, 16, 256, 1024><<<dim3(BATCH * klen / 16, 4), 256, 0, stream>>>(
        hb, W1 + (size_t)l * DM * DFF, nullptr, fb, klen);
    gemm_kernel<0, true, 8, 1024, 256><<<dim3(BATCH * klen / 8, 1), 256, 0, stream>>>(
        fb, W2 + (size_t)l * DFF * DM, xb, xb, klen);
    scatter_kernel<<<MB, 256, 0, stream>>>(xb, sidx, out, klen);
  }
}

// Round 3
// 1166.231 us; speedup vs baseline: 4.2914x; 2.6052x over previous
//
#include <hip/hip_runtime.h>
#include <math.h>

#define NTOK 8000
#define KCAP 3200
#define BATCH 2
#define DM 256
#define DFF 1024

typedef __attribute__((ext_vector_type(4))) short s16x4;
typedef __attribute__((ext_vector_type(16))) float f32x16;

#define MFMA_B(a, b, c) __builtin_amdgcn_mfma_f32_32x32x8bf16_1k(a, b, c, 0, 0, 0)

__device__ __forceinline__ ushort f2bf(float f) {  // RNE float->bf16 bits
  unsigned u = __float_as_uint(f);
  u += 0x7fffu + ((u >> 16) & 1u);
  return (ushort)(u >> 16);
}
__device__ __forceinline__ float gelu_tanh(float x) {
  const float z = 0.7978845608028654f * (x + 0.044715f * x * x * x);
  return x * (1.0f / (1.0f + __expf(-2.0f * z)));  // == 0.5x(1+tanh(z))
}
__device__ __forceinline__ f32x16 zero16() {
  f32x16 z;
#pragma unroll
  for (int i = 0; i < 16; ++i) z[i] = 0.f;
  return z;
}

// ---- top-k: rank each token's salience; ranks < KCAP fill sorted index list ----
__global__ __launch_bounds__(256) void topk_kernel(const float* __restrict__ sal,
                                                   int* __restrict__ sidx) {
  const int b = blockIdx.x >> 5;
  const int blk = blockIdx.x & 31;
  __shared__ float s[NTOK];
  const float* sb = sal + (size_t)b * NTOK;
  for (int j = threadIdx.x; j < NTOK; j += 256) s[j] = sb[j];
  __syncthreads();
  const int i = blk * 256 + threadIdx.x;
  if (i >= NTOK) return;
  const float si = s[i];
  int rank = 0;
#pragma unroll 4
  for (int j = 0; j < NTOK; ++j) {
    const float sj = s[j];
    rank += (int)((sj > si) || (sj == si && j < i));
  }
  if (rank < KCAP) sidx[b * KCAP + rank] = i;
}

// ---- weight prep: fp32 W[l][K][N] -> bf16 transposed Wt[l][N][K] ----
__global__ __launch_bounds__(256) void wprep_kernel(
    const float* __restrict__ Wq, const float* __restrict__ Wk,
    const float* __restrict__ Wv, const float* __restrict__ Wo,
    const float* __restrict__ W1, const float* __restrict__ W2,
    ushort* __restrict__ wqt, ushort* __restrict__ wkt, ushort* __restrict__ wvt,
    ushort* __restrict__ wot, ushort* __restrict__ w1t, ushort* __restrict__ w2t) {
  const int z = blockIdx.z;
  const float* src;
  ushort* dst;
  int KD, N, lsh;
  switch (z) {
    case 0: src = Wq; dst = wqt; KD = 256; N = 256; lsh = 8; break;
    case 1: src = Wk; dst = wkt; KD = 256; N = 256; lsh = 8; break;
    case 2: src = Wv; dst = wvt; KD = 256; N = 256; lsh = 8; break;
    case 3: src = Wo; dst = wot; KD = 256; N = 256; lsh = 8; break;
    case 4: src = W1; dst = w1t; KD = 256; N = 1024; lsh = 10; break;
    default: src = W2; dst = w2t; KD = 1024; N = 256; lsh = 8; break;
  }
  if (blockIdx.x >= (unsigned)(4 * N)) return;
  const int l = blockIdx.x >> lsh;
  const int n = blockIdx.x & (N - 1);
  const float* s = src + (size_t)l * KD * N + n;
  ushort* d = dst + ((size_t)l * N + n) * KD;
  for (int k = threadIdx.x; k < KD; k += 256) d[k] = f2bf(s[(size_t)k * N]);
}

// ---- gather + LayerNorm1: wave per token, writes x (f32) and h (bf16) ----
__global__ __launch_bounds__(256) void gather_ln_kernel(
    const float* __restrict__ feat, const int* __restrict__ sidx,
    const float* __restrict__ g, const float* __restrict__ bb,
    float* __restrict__ x, ushort* __restrict__ h, int klen) {
  const int w = threadIdx.x >> 6, lane = threadIdx.x & 63;
  const int m = blockIdx.x * 4 + w;
  const int b = m / klen, t = m - b * klen;
  const int tok = sidx[b * KCAP + t];
  const float4 v4 =
      reinterpret_cast<const float4*>(feat + ((size_t)b * NTOK + tok) * DM)[lane];
  reinterpret_cast<float4*>(x + ((size_t)b * KCAP + t) * DM)[lane] = v4;
  float s = v4.x + v4.y + v4.z + v4.w;
#pragma unroll
  for (int off = 1; off < 64; off <<= 1) s += __shfl_xor(s, off);
  const float mu = s * (1.0f / DM);
  const float4 dv = {v4.x - mu, v4.y - mu, v4.z - mu, v4.w - mu};
  float vs = dv.x * dv.x + dv.y * dv.y + dv.z * dv.z + dv.w * dv.w;
#pragma unroll
  for (int off = 1; off < 64; off <<= 1) vs += __shfl_xor(vs, off);
  const float rstd = rsqrtf(vs * (1.0f / DM) + 1e-5f);
  const float4 g4 = reinterpret_cast<const float4*>(g)[lane];
  const float4 b4 = reinterpret_cast<const float4*>(bb)[lane];
  union { unsigned long long u; ushort us[4]; } o;
  o.us[0] = f2bf(dv.x * rstd * g4.x + b4.x);
  o.us[1] = f2bf(dv.y * rstd * g4.y + b4.y);
  o.us[2] = f2bf(dv.z * rstd * g4.z + b4.z);
  o.us[3] = f2bf(dv.w * rstd * g4.w + b4.w);
  reinterpret_cast<unsigned long long*>(h + ((size_t)b * KCAP + t) * DM)[lane] = o.u;
}

// ---- LayerNorm2: wave per token, x (f32) -> h (bf16) ----
__global__ __launch_bounds__(256) void ln2_kernel(
    const float* __restrict__ x, const float* __restrict__ g,
    const float* __restrict__ bb, ushort* __restrict__ h, int klen) {
  const int w = threadIdx.x >> 6, lane = threadIdx.x & 63;
  const int m = blockIdx.x * 4 + w;
  const int b = m / klen, t = m - b * klen;
  const float4 v4 = reinterpret_cast<const float4*>(x + ((size_t)b * KCAP + t) * DM)[lane];
  float s = v4.x + v4.y + v4.z + v4.w;
#pragma unroll
  for (int off = 1; off < 64; off <<= 1) s += __shfl_xor(s, off);
  const float mu = s * (1.0f / DM);
  const float4 dv = {v4.x - mu, v4.y - mu, v4.z - mu, v4.w - mu};
  float vs = dv.x * dv.x + dv.y * dv.y + dv.z * dv.z + dv.w * dv.w;
#pragma unroll
  for (int off = 1; off < 64; off <<= 1) vs += __shfl_xor(vs, off);
  const float rstd = rsqrtf(vs * (1.0f / DM) + 1e-5f);
  const float4 g4 = reinterpret_cast<const float4*>(g)[lane];
  const float4 b4 = reinterpret_cast<const float4*>(bb)[lane];
  union { unsigned long long u; ushort us[4]; } o;
  o.us[0] = f2bf(dv.x * rstd * g4.x + b4.x);
  o.us[1] = f2bf(dv.y * rstd * g4.y + b4.y);
  o.us[2] = f2bf(dv.z * rstd * g4.z + b4.z);
  o.us[3] = f2bf(dv.w * rstd * g4.w + b4.w);
  reinterpret_cast<unsigned long long*>(h + ((size_t)b * KCAP + t) * DM)[lane] = o.u;
}

// ---- MFMA GEMM: wave computes 32x32 tile of C = A[M,KD] @ Wt[N,KD]^T ----
// MODE 0: bf16 out (row stride ND, optional gelu)   MODE 1: f32 out = Res + v
// MODE 2: Q head layout (pre-scaled)  MODE 3: K head layout  MODE 4: V transposed
template <int KD, int ND, int MODE, int ACT>
__global__ __launch_bounds__(256) void mgemm_kernel(
    const ushort* __restrict__ A, const ushort* __restrict__ Wt,
    const float* __restrict__ Res, void* __restrict__ Cv, int klen) {
  const int tid = threadIdx.x;
  const int w = tid >> 6, lane = tid & 63, l31 = lane & 31, hi = lane >> 5;
  const int wrow = w >> 1, wcol = w & 1;
  const int nrb = (klen + 63) >> 6;
  const int b = blockIdx.x / nrb;
  const int t0 = (blockIdx.x - b * nrb) * 64 + wrow * 32;
  const int n0 = blockIdx.y * 64 + wcol * 32;
  const int row = min(t0 + l31, klen - 1);
  const int n = n0 + l31;
  const ushort* Ap = A + ((size_t)b * KCAP + row) * KD + hi * 4;
  const ushort* Wp = Wt + (size_t)n * KD + hi * 4;
  f32x16 acc = zero16();
#pragma unroll 4
  for (int k = 0; k < KD; k += 8) {
    const s16x4 af = *reinterpret_cast<const s16x4*>(Ap + k);
    const s16x4 bf = *reinterpret_cast<const s16x4*>(Wp + k);
    acc = MFMA_B(af, bf, acc);
  }
  const int hh = n0 >> 5;  // head (MODE 2/3/4)
  const int hi4 = 4 * hi;
#pragma unroll
  for (int r = 0; r < 16; ++r) {
    const int gm = t0 + ((r & 3) + 8 * (r >> 2) + hi4);
    if (gm < klen) {
      const float v0 = acc[r];
      if constexpr (MODE == 0) {
        float v = v0;
        if (ACT) v = gelu_tanh(v);
        ((ushort*)Cv)[((size_t)b * KCAP + gm) * ND + n] = f2bf(v);
      } else if constexpr (MODE == 1) {
        float* C = (float*)Cv;
        const size_t off = ((size_t)b * KCAP + gm) * ND + n;
        C[off] = Res[off] + v0;
      } else if constexpr (MODE == 2) {
        ((ushort*)Cv)[((size_t)(b * 8 + hh) * KCAP + gm) * 32 + l31] =
            f2bf(v0 * 0.17677669529663687f);
      } else if constexpr (MODE == 3) {
        ((ushort*)Cv)[((size_t)(b * 8 + hh) * KCAP + gm) * 32 + l31] = f2bf(v0);
      } else {
        ((ushort*)Cv)[((size_t)(b * 8 + hh) * 32 + l31) * KCAP + gm] = f2bf(v0);
      }
    }
  }
}

// ---- flash attention: wave per 32-query tile, swapped QK^T, defer-max softmax ----
// Q,K: [b*8+h][t][32] bf16 (Q pre-scaled); Vt: [b*8+h][32][KCAP] bf16; O: [b*KCAP+t][256]
__global__ __launch_bounds__(256) void attn_kernel(
    const ushort* __restrict__ Q, const ushort* __restrict__ Kb,
    const ushort* __restrict__ Vt, ushort* __restrict__ O, int klen) {
  const int hh = blockIdx.y, b = blockIdx.z;
  const int bh = b * 8 + hh;
  const int tid = threadIdx.x;
  const int w = tid >> 6, lane = tid & 63, l31 = lane & 31, hi = lane >> 5;
  __shared__ uint4 kl[128], vl[128];
  const int q0 = (blockIdx.x * 4 + w) * 32;
  const int qg = min(q0 + l31, klen - 1);
  const ushort* qrow = Q + ((size_t)bh * KCAP + qg) * 32;
  const s16x4 qf0 = *reinterpret_cast<const s16x4*>(qrow + 0 + hi * 4);
  const s16x4 qf1 = *reinterpret_cast<const s16x4*>(qrow + 8 + hi * 4);
  const s16x4 qf2 = *reinterpret_cast<const s16x4*>(qrow + 16 + hi * 4);
  const s16x4 qf3 = *reinterpret_cast<const s16x4*>(qrow + 24 + hi * 4);
  f32x16 oacc = zero16();
  float mrun = -INFINITY, lrun = 0.f;
  const ushort* kbase = Kb + (size_t)bh * KCAP * 32;
  const ushort* vbase = Vt + (size_t)bh * 32 * KCAP;
  const int nkb = (klen + 31) >> 5;
  for (int kt = 0; kt < nkb; ++kt) {
    const int kb = kt << 5;
    __syncthreads();
    if (tid < 128) {  // stage K tile: chunk (dc, key) -> kl[dc*32+key]
      const int key = tid & 31, dc = tid >> 5;
      uint4 val = {0u, 0u, 0u, 0u};
      if (kb + key < klen)
        val = *reinterpret_cast<const uint4*>(kbase + ((size_t)(kb + key)) * 32 + dc * 8);
      kl[tid] = val;
    } else {  // stage V^T tile: chunk (kc, d) -> vl[kc*32+d]
      const int d = tid & 31, kc = (tid >> 5) & 3;
      uint4 val = {0u, 0u, 0u, 0u};
      if (kb + kc * 8 < klen)  // klen % 8 == 0 -> chunk fully valid or fully out
        val = *reinterpret_cast<const uint4*>(vbase + (size_t)d * KCAP + kb + kc * 8);
      vl[tid - 128] = val;
    }
    __syncthreads();
    // S^T[key][q] = K . Q^T  (q = l31 lane-local)
    f32x16 s = zero16();
    const char* klc = reinterpret_cast<const char*>(kl);
    s = MFMA_B(*reinterpret_cast<const s16x4*>(klc + (0 * 32 + l31) * 16 + hi * 8), qf0, s);
    s = MFMA_B(*reinterpret_cast<const s16x4*>(klc + (1 * 32 + l31) * 16 + hi * 8), qf1, s);
    s = MFMA_B(*reinterpret_cast<const s16x4*>(klc + (2 * 32 + l31) * 16 + hi * 8), qf2, s);
    s = MFMA_B(*reinterpret_cast<const s16x4*>(klc + (3 * 32 + l31) * 16 + hi * 8), qf3, s);
    if (kb + 32 > klen) {  // mask tail keys
#pragma unroll
      for (int r = 0; r < 16; ++r) {
        const int key = kb + (r & 3) + 8 * (r >> 2) + 4 * hi;
        if (key >= klen) s[r] = -1e30f;
      }
    }
    float smax = s[0];
#pragma unroll
    for (int r = 1; r < 16; ++r) smax = fmaxf(smax, s[r]);
    smax = fmaxf(smax, __shfl_xor(smax, 32));
    if (smax > mrun + 8.0f) {  // defer-max: rescale only on large max growth
      const float cor = __expf(mrun - smax);
      lrun *= cor;
#pragma unroll
      for (int r = 0; r < 16; ++r) oacc[r] *= cor;
      mrun = smax;
    }
    float p[16];
    float ps = 0.f;
#pragma unroll
    for (int r = 0; r < 16; ++r) {
      p[r] = __expf(s[r] - mrun);
      ps += p[r];
    }
    lrun += ps;
    // P fragments are lane-local for K=8 MFMA: frag(kc) elems = p[4kc..4kc+3]
    unsigned pw[8];
#pragma unroll
    for (int i = 0; i < 8; ++i)
      pw[i] = (unsigned)f2bf(p[2 * i]) | ((unsigned)f2bf(p[2 * i + 1]) << 16);
    const char* vlc = reinterpret_cast<const char*>(vl);
#pragma unroll
    for (int kc = 0; kc < 4; ++kc) {
      union { unsigned u[2]; s16x4 v; } pf;
      pf.u[0] = pw[2 * kc];
      pf.u[1] = pw[2 * kc + 1];
      const s16x4 vf =
          *reinterpret_cast<const s16x4*>(vlc + (kc * 32 + l31) * 16 + hi * 8);
      oacc = MFMA_B(vf, pf.v, oacc);  // O^T[d][q]
    }
  }
  const float ltot = lrun + __shfl_xor(lrun, 32);
  const float inv = 1.0f / ltot;
  if (q0 + l31 < klen) {
    ushort* orow = O + ((size_t)b * KCAP + q0 + l31) * DM + hh * 32;
#pragma unroll
    for (int rq = 0; rq < 4; ++rq) {
      union { unsigned long long u64; ushort us[4]; } o4;
#pragma unroll
      for (int j = 0; j < 4; ++j) o4.us[j] = f2bf(oacc[4 * rq + j] * inv);
      *reinterpret_cast<unsigned long long*>(orow + 8 * rq + 4 * hi) = o4.u64;
    }
  }
}

// ---- scatter updated tokens back into the feature bank (float4 per thread) ----
__global__ __launch_bounds__(256) void scatter_kernel(
    const float* __restrict__ x, const int* __restrict__ sidx,
    float* __restrict__ feat, int klen) {
  const int gid = blockIdx.x * 256 + threadIdx.x;
  const int m = gid >> 6, li = gid & 63;
  const int b = m / klen, t = m - b * klen;
  const int tok = sidx[b * KCAP + t];
  reinterpret_cast<float4*>(feat + ((size_t)b * NTOK + tok) * DM)[li] =
      reinterpret_cast<const float4*>(x + ((size_t)b * KCAP + t) * DM)[li];
}

extern "C" void kernel_launch(void* const* d_in, const int* in_sizes, int n_in,
                              void* d_out, int out_size, void* d_ws, size_t ws_size,
                              hipStream_t stream) {
  (void)in_sizes; (void)n_in; (void)out_size; (void)ws_size;
  const float* features = (const float*)d_in[0];
  const float* salience = (const float*)d_in[1];
  const float* Wq = (const float*)d_in[2];
  const float* Wk = (const float*)d_in[3];
  const float* Wv = (const float*)d_in[4];
  const float* Wo = (const float*)d_in[5];
  const float* W1 = (const float*)d_in[6];
  const float* W2 = (const float*)d_in[7];
  const float* ln1g = (const float*)d_in[8];
  const float* ln1b = (const float*)d_in[9];
  const float* ln2g = (const float*)d_in[10];
  const float* ln2b = (const float*)d_in[11];
  float* out = (float*)d_out;

  // workspace layout
  const size_t SLAB = (size_t)BATCH * KCAP * DM;  // 1.6384M elems
  char* p = (char*)d_ws;
  int* sidx = (int*)p;                 p += 32768;
  float* xb = (float*)p;               p += SLAB * 4;
  ushort* hb = (ushort*)p;             p += SLAB * 2;
  ushort* qh = (ushort*)p;             p += SLAB * 2;
  ushort* kh = (ushort*)p;             p += SLAB * 2;
  ushort* vt = (ushort*)p;             p += SLAB * 2;
  ushort* ob = (ushort*)p;             p += SLAB * 2;
  ushort* fb = qh;  // FFN intermediate (bf16, 13.1MB) overlays qh|kh|vt|ob
  ushort* wqt = (ushort*)p;            p += (size_t)4 * 256 * 256 * 2;
  ushort* wkt = (ushort*)p;            p += (size_t)4 * 256 * 256 * 2;
  ushort* wvt = (ushort*)p;            p += (size_t)4 * 256 * 256 * 2;
  ushort* wot = (ushort*)p;            p += (size_t)4 * 256 * 256 * 2;
  ushort* w1t = (ushort*)p;            p += (size_t)4 * 256 * 1024 * 2;
  ushort* w2t = (ushort*)p;            p += (size_t)4 * 1024 * 256 * 2;

  hipMemcpyAsync(out, features, (size_t)BATCH * NTOK * DM * sizeof(float),
                 hipMemcpyDeviceToDevice, stream);
  topk_kernel<<<64, 256, 0, stream>>>(salience, sidx);
  wprep_kernel<<<dim3(4096, 1, 6), 256, 0, stream>>>(Wq, Wk, Wv, Wo, W1, W2, wqt,
                                                     wkt, wvt, wot, w1t, w2t);

  const int klens[4] = {3200, 2400, 2000, 1600};
  for (int l = 0; l < 4; ++l) {
    const int klen = klens[l];
    const int nrb = (klen + 63) >> 6;    // GEMM row blocks (64 rows)
    const int nra = (klen + 127) >> 7;   // attn q blocks (128 queries)
    const size_t wsq = (size_t)l * 256 * 256;
    const size_t wff = (size_t)l * 256 * 1024;
    gather_ln_kernel<<<klen / 2, 256, 0, stream>>>(out, sidx, ln1g + l * DM,
                                                   ln1b + l * DM, xb, hb, klen);
    mgemm_kernel<256, 256, 2, 0><<<dim3(2 * nrb, 4), 256, 0, stream>>>(
        hb, wqt + wsq, nullptr, qh, klen);
    mgemm_kernel<256, 256, 3, 0><<<dim3(2 * nrb, 4), 256, 0, stream>>>(
        hb, wkt + wsq, nullptr, kh, klen);
    mgemm_kernel<256, 256, 4, 0><<<dim3(2 * nrb, 4), 256, 0, stream>>>(
        hb, wvt + wsq, nullptr, vt, klen);
    attn_kernel<<<dim3(nra, 8, BATCH), 256, 0, stream>>>(qh, kh, vt, ob, klen);
    mgemm_kernel<256, 256, 1, 0><<<dim3(2 * nrb, 4), 256, 0, stream>>>(
        ob, wot + wsq, xb, xb, klen);
    ln2_kernel<<<klen / 2, 256, 0, stream>>>(xb, ln2g + l * DM, ln2b + l * DM, hb,
                                             klen);
    mgemm_kernel<256, 1024, 0, 1><<<dim3(2 * nrb, 16), 256, 0, stream>>>(
        hb, w1t + wff, nullptr, fb, klen);
    mgemm_kernel<1024, 256, 1, 0><<<dim3(2 * nrb, 4), 256, 0, stream>>>(
        fb, w2t + wff, xb, xb, klen);
    scatter_kernel<<<klen / 2, 256, 0, stream>>>(xb, sidx, out, klen);
  }
}

// Round 4
// 964.678 us; speedup vs baseline: 5.1880x; 1.2089x over previous
//
#include <hip/hip_runtime.h>
#include <math.h>

#define NTOK 8000
#define KCAP 3200
#define BATCH 2
#define DM 256
#define DFF 1024
#define JT 2000  // top-k j-slice per block

typedef __attribute__((ext_vector_type(4))) short s16x4;
typedef __attribute__((ext_vector_type(16))) float f32x16;

#define MFMA_B(a, b, c) __builtin_amdgcn_mfma_f32_32x32x8bf16_1k(a, b, c, 0, 0, 0)

__device__ __forceinline__ ushort f2bf(float f) {  // RNE float->bf16 bits
  unsigned u = __float_as_uint(f);
  u += 0x7fffu + ((u >> 16) & 1u);
  return (ushort)(u >> 16);
}
__device__ __forceinline__ float gelu_tanh(float x) {
  const float z = 0.7978845608028654f * (x + 0.044715f * x * x * x);
  return x * (1.0f / (1.0f + __expf(-2.0f * z)));  // == 0.5x(1+tanh(z))
}
__device__ __forceinline__ f32x16 zero16() {
  f32x16 z;
#pragma unroll
  for (int i = 0; i < 16; ++i) z[i] = 0.f;
  return z;
}

// ---- top-k phase A: partial ranks over a 2000-element j-slice ----
__global__ __launch_bounds__(256) void topk_partial(const float* __restrict__ sal,
                                                    int* __restrict__ partial) {
  const int b = blockIdx.z, jc = blockIdx.y;
  __shared__ float4 s4[JT / 4];
  const float4* src4 = reinterpret_cast<const float4*>(sal + (size_t)b * NTOK + jc * JT);
  for (int e = threadIdx.x; e < JT / 4; e += 256) s4[e] = src4[e];
  __syncthreads();
  const int i = blockIdx.x * 256 + threadIdx.x;
  if (i >= NTOK) return;
  const float si = sal[(size_t)b * NTOK + i];
  int rank = 0;
  const int jbase = jc * JT;
#pragma unroll 4
  for (int e = 0; e < JT / 4; ++e) {
    const float4 v = s4[e];
    const int j = jbase + e * 4;
    rank += (int)((v.x > si) || (v.x == si && j + 0 < i));
    rank += (int)((v.y > si) || (v.y == si && j + 1 < i));
    rank += (int)((v.z > si) || (v.z == si && j + 2 < i));
    rank += (int)((v.w > si) || (v.w == si && j + 3 < i));
  }
  partial[((size_t)jc * BATCH + b) * NTOK + i] = rank;
}

// ---- top-k phase B: sum partials, scatter rank<KCAP into sorted index list ----
__global__ __launch_bounds__(256) void topk_finalize(const int* __restrict__ partial,
                                                     int* __restrict__ sidx) {
  const int gid = blockIdx.x * 256 + threadIdx.x;
  if (gid >= BATCH * NTOK) return;
  const int b = gid / NTOK, i = gid - b * NTOK;
  int rank = 0;
#pragma unroll
  for (int jc = 0; jc < 4; ++jc) rank += partial[((size_t)jc * BATCH + b) * NTOK + i];
  if (rank < KCAP) sidx[b * KCAP + rank] = i;
}

// ---- weight prep: tiled transpose fp32 W[l][K][N] -> bf16 Wt[l][N][K] ----
__global__ __launch_bounds__(256) void wprep_kernel(
    const float* __restrict__ Wq, const float* __restrict__ Wk,
    const float* __restrict__ Wv, const float* __restrict__ Wo,
    const float* __restrict__ W1, const float* __restrict__ W2,
    ushort* __restrict__ wqt, ushort* __restrict__ wkt, ushort* __restrict__ wvt,
    ushort* __restrict__ wot, ushort* __restrict__ w1t, ushort* __restrict__ w2t) {
  const int z = blockIdx.z;
  const float* src;
  ushort* dst;
  int KD, N;
  switch (z) {
    case 0: src = Wq; dst = wqt; KD = 256; N = 256; break;
    case 1: src = Wk; dst = wkt; KD = 256; N = 256; break;
    case 2: src = Wv; dst = wvt; KD = 256; N = 256; break;
    case 3: src = Wo; dst = wot; KD = 256; N = 256; break;
    case 4: src = W1; dst = w1t; KD = 256; N = 1024; break;
    default: src = W2; dst = w2t; KD = 1024; N = 256; break;
  }
  const int ntn = N >> 6;
  const int tpl = (KD >> 6) * ntn;
  if (blockIdx.x >= (unsigned)(4 * tpl)) return;
  const int l = blockIdx.x / tpl;
  const int t = blockIdx.x - l * tpl;
  const int ki = t / ntn, ni = t - ki * ntn;
  __shared__ ushort lds[64][65];
  const int tid = threadIdx.x;
  const int c = tid & 63, rb = tid >> 6;
  const float* sbase = src + ((size_t)l * KD + ki * 64) * N + ni * 64 + c;
#pragma unroll
  for (int rr = 0; rr < 16; ++rr) {
    const int r = rb * 16 + rr;
    lds[c][r] = f2bf(sbase[(size_t)r * N]);
  }
  __syncthreads();
  const int c2 = (tid & 31) << 1, rb2 = tid >> 5;
  ushort* dbase = dst + ((size_t)l * N + ni * 64) * KD + ki * 64 + c2;
#pragma unroll
  for (int rr = 0; rr < 8; ++rr) {
    const int r2 = rb2 * 8 + rr;
    const unsigned u = (unsigned)lds[r2][c2] | ((unsigned)lds[r2][c2 + 1] << 16);
    *reinterpret_cast<unsigned*>(dbase + (size_t)r2 * KD) = u;
  }
}

// ---- gather + LayerNorm1: wave per token, writes x (f32) and h (bf16) ----
__global__ __launch_bounds__(256) void gather_ln_kernel(
    const float* __restrict__ feat, const int* __restrict__ sidx,
    const float* __restrict__ g, const float* __restrict__ bb,
    float* __restrict__ x, ushort* __restrict__ h, int klen) {
  const int w = threadIdx.x >> 6, lane = threadIdx.x & 63;
  const int m = blockIdx.x * 4 + w;
  const int b = m / klen, t = m - b * klen;
  const int tok = sidx[b * KCAP + t];
  const float4 v4 =
      reinterpret_cast<const float4*>(feat + ((size_t)b * NTOK + tok) * DM)[lane];
  reinterpret_cast<float4*>(x + ((size_t)b * KCAP + t) * DM)[lane] = v4;
  float s = v4.x + v4.y + v4.z + v4.w;
#pragma unroll
  for (int off = 1; off < 64; off <<= 1) s += __shfl_xor(s, off);
  const float mu = s * (1.0f / DM);
  const float4 dv = {v4.x - mu, v4.y - mu, v4.z - mu, v4.w - mu};
  float vs = dv.x * dv.x + dv.y * dv.y + dv.z * dv.z + dv.w * dv.w;
#pragma unroll
  for (int off = 1; off < 64; off <<= 1) vs += __shfl_xor(vs, off);
  const float rstd = rsqrtf(vs * (1.0f / DM) + 1e-5f);
  const float4 g4 = reinterpret_cast<const float4*>(g)[lane];
  const float4 b4 = reinterpret_cast<const float4*>(bb)[lane];
  union { unsigned long long u; ushort us[4]; } o;
  o.us[0] = f2bf(dv.x * rstd * g4.x + b4.x);
  o.us[1] = f2bf(dv.y * rstd * g4.y + b4.y);
  o.us[2] = f2bf(dv.z * rstd * g4.z + b4.z);
  o.us[3] = f2bf(dv.w * rstd * g4.w + b4.w);
  reinterpret_cast<unsigned long long*>(h + ((size_t)b * KCAP + t) * DM)[lane] = o.u;
}

// ---- LayerNorm2: wave per token, x (f32) -> h (bf16) ----
__global__ __launch_bounds__(256) void ln2_kernel(
    const float* __restrict__ x, const float* __restrict__ g,
    const float* __restrict__ bb, ushort* __restrict__ h, int klen) {
  const int w = threadIdx.x >> 6, lane = threadIdx.x & 63;
  const int m = blockIdx.x * 4 + w;
  const int b = m / klen, t = m - b * klen;
  const float4 v4 = reinterpret_cast<const float4*>(x + ((size_t)b * KCAP + t) * DM)[lane];
  float s = v4.x + v4.y + v4.z + v4.w;
#pragma unroll
  for (int off = 1; off < 64; off <<= 1) s += __shfl_xor(s, off);
  const float mu = s * (1.0f / DM);
  const float4 dv = {v4.x - mu, v4.y - mu, v4.z - mu, v4.w - mu};
  float vs = dv.x * dv.x + dv.y * dv.y + dv.z * dv.z + dv.w * dv.w;
#pragma unroll
  for (int off = 1; off < 64; off <<= 1) vs += __shfl_xor(vs, off);
  const float rstd = rsqrtf(vs * (1.0f / DM) + 1e-5f);
  const float4 g4 = reinterpret_cast<const float4*>(g)[lane];
  const float4 b4 = reinterpret_cast<const float4*>(bb)[lane];
  union { unsigned long long u; ushort us[4]; } o;
  o.us[0] = f2bf(dv.x * rstd * g4.x + b4.x);
  o.us[1] = f2bf(dv.y * rstd * g4.y + b4.y);
  o.us[2] = f2bf(dv.z * rstd * g4.z + b4.z);
  o.us[3] = f2bf(dv.w * rstd * g4.w + b4.w);
  reinterpret_cast<unsigned long long*>(h + ((size_t)b * KCAP + t) * DM)[lane] = o.u;
}

// ---- MFMA GEMM: wave computes 32x32 tile of C = A[M,KD] @ Wt[N,KD]^T ----
// MODE 0: bf16 out (optional gelu)  MODE 1: f32 out = Res + v
// MODE 5: f32 Res + v scattered to feat via sidx
template <int KD, int ND, int MODE, int ACT>
__global__ __launch_bounds__(256) void mgemm_kernel(
    const ushort* __restrict__ A, const ushort* __restrict__ Wt,
    const float* __restrict__ Res, void* __restrict__ Cv,
    const int* __restrict__ sidx, int klen) {
  const int tid = threadIdx.x;
  const int w = tid >> 6, lane = tid & 63, l31 = lane & 31, hi = lane >> 5;
  const int wrow = w >> 1, wcol = w & 1;
  const int nrb = (klen + 63) >> 6;
  const int b = blockIdx.x / nrb;
  const int t0 = (blockIdx.x - b * nrb) * 64 + wrow * 32;
  const int n0 = blockIdx.y * 64 + wcol * 32;
  const int row = min(t0 + l31, klen - 1);
  const int n = n0 + l31;
  const ushort* Ap = A + ((size_t)b * KCAP + row) * KD + hi * 4;
  const ushort* Wp = Wt + (size_t)n * KD + hi * 4;
  f32x16 acc = zero16();
#pragma unroll 4
  for (int k = 0; k < KD; k += 8) {
    const s16x4 af = *reinterpret_cast<const s16x4*>(Ap + k);
    const s16x4 bf = *reinterpret_cast<const s16x4*>(Wp + k);
    acc = MFMA_B(af, bf, acc);
  }
  const int hi4 = 4 * hi;
#pragma unroll
  for (int r = 0; r < 16; ++r) {
    const int gm = t0 + ((r & 3) + 8 * (r >> 2) + hi4);
    if (gm < klen) {
      const float v0 = acc[r];
      if constexpr (MODE == 0) {
        float v = v0;
        if (ACT) v = gelu_tanh(v);
        ((ushort*)Cv)[((size_t)b * KCAP + gm) * ND + n] = f2bf(v);
      } else if constexpr (MODE == 1) {
        float* C = (float*)Cv;
        const size_t off = ((size_t)b * KCAP + gm) * ND + n;
        C[off] = Res[off] + v0;
      } else {  // MODE 5: residual + scatter to feature bank
        const int tok = sidx[b * KCAP + gm];
        ((float*)Cv)[((size_t)b * NTOK + tok) * ND + n] =
            Res[((size_t)b * KCAP + gm) * ND + n] + v0;
      }
    }
  }
}

// ---- fused Q/K/V projection: z selects weight + epilogue layout ----
__global__ __launch_bounds__(256) void qkv_kernel(
    const ushort* __restrict__ A, const ushort* __restrict__ wq,
    const ushort* __restrict__ wk, const ushort* __restrict__ wv,
    ushort* __restrict__ qh, ushort* __restrict__ kh, ushort* __restrict__ vt,
    int klen) {
  const int z = blockIdx.z;
  const ushort* Wt = z == 0 ? wq : (z == 1 ? wk : wv);
  const int tid = threadIdx.x;
  const int w = tid >> 6, lane = tid & 63, l31 = lane & 31, hi = lane >> 5;
  const int wrow = w >> 1, wcol = w & 1;
  const int nrb = (klen + 63) >> 6;
  const int b = blockIdx.x / nrb;
  const int t0 = (blockIdx.x - b * nrb) * 64 + wrow * 32;
  const int n0 = blockIdx.y * 64 + wcol * 32;
  const int row = min(t0 + l31, klen - 1);
  const int n = n0 + l31;
  const ushort* Ap = A + ((size_t)b * KCAP + row) * 256 + hi * 4;
  const ushort* Wp = Wt + (size_t)n * 256 + hi * 4;
  f32x16 acc = zero16();
#pragma unroll 4
  for (int k = 0; k < 256; k += 8) {
    const s16x4 af = *reinterpret_cast<const s16x4*>(Ap + k);
    const s16x4 bf = *reinterpret_cast<const s16x4*>(Wp + k);
    acc = MFMA_B(af, bf, acc);
  }
  const int hh = n0 >> 5;
  const int hi4 = 4 * hi;
  if (z == 2) {  // V transposed: [b*8+h][d][t]
#pragma unroll
    for (int r = 0; r < 16; ++r) {
      const int gm = t0 + ((r & 3) + 8 * (r >> 2) + hi4);
      if (gm < klen)
        vt[((size_t)(b * 8 + hh) * 32 + l31) * KCAP + gm] = f2bf(acc[r]);
    }
  } else {  // Q (pre-scaled) / K head layout: [b*8+h][t][d]
    const float sc = z == 0 ? 0.17677669529663687f : 1.0f;
    ushort* dst = z == 0 ? qh : kh;
#pragma unroll
    for (int r = 0; r < 16; ++r) {
      const int gm = t0 + ((r & 3) + 8 * (r >> 2) + hi4);
      if (gm < klen)
        dst[((size_t)(b * 8 + hh) * KCAP + gm) * 32 + l31] = f2bf(acc[r] * sc);
    }
  }
}

// ---- flash attention: wave per 32-query tile, 64-key LDS stages, defer-max ----
__global__ __launch_bounds__(256) void attn_kernel(
    const ushort* __restrict__ Q, const ushort* __restrict__ Kb,
    const ushort* __restrict__ Vt, ushort* __restrict__ O, int klen) {
  const int hh = blockIdx.y, b = blockIdx.z;
  const int bh = b * 8 + hh;
  const int tid = threadIdx.x;
  const int w = tid >> 6, lane = tid & 63, l31 = lane & 31, hi = lane >> 5;
  __shared__ uint4 kl[256], vl[256];  // 64 keys x 32 dims each
  const int q0 = (blockIdx.x * 4 + w) * 32;
  const int qg = min(q0 + l31, klen - 1);
  const ushort* qrow = Q + ((size_t)bh * KCAP + qg) * 32;
  const s16x4 qf0 = *reinterpret_cast<const s16x4*>(qrow + 0 + hi * 4);
  const s16x4 qf1 = *reinterpret_cast<const s16x4*>(qrow + 8 + hi * 4);
  const s16x4 qf2 = *reinterpret_cast<const s16x4*>(qrow + 16 + hi * 4);
  const s16x4 qf3 = *reinterpret_cast<const s16x4*>(qrow + 24 + hi * 4);
  f32x16 oacc = zero16();
  float mrun = -INFINITY, lrun = 0.f;
  const ushort* kbase = Kb + (size_t)bh * KCAP * 32;
  const ushort* vbase = Vt + (size_t)bh * 32 * KCAP;
  const int nkb = (klen + 63) >> 6;
  const int skey = tid & 63, sdc = tid >> 6;   // K staging coords
  const int svd = tid & 31, svk = tid >> 5;    // V staging coords
  for (int kt = 0; kt < nkb; ++kt) {
    const int kb = kt << 6;
    __syncthreads();
    uint4 kval = {0u, 0u, 0u, 0u};
    if (kb + skey < klen)
      kval = *reinterpret_cast<const uint4*>(kbase + ((size_t)(kb + skey)) * 32 + sdc * 8);
    kl[sdc * 64 + skey] = kval;
    uint4 vval = {0u, 0u, 0u, 0u};
    if (kb + svk * 8 < klen)  // klen % 8 == 0 -> chunk fully valid or fully out
      vval = *reinterpret_cast<const uint4*>(vbase + (size_t)svd * KCAP + kb + svk * 8);
    vl[svk * 32 + svd] = vval;
    __syncthreads();
    const char* klc = reinterpret_cast<const char*>(kl);
    const char* vlc = reinterpret_cast<const char*>(vl);
#pragma unroll
    for (int sub = 0; sub < 2; ++sub) {
      const int kbs = kb + sub * 32;
      if (kbs >= klen) break;
      f32x16 s = zero16();
      s = MFMA_B(*reinterpret_cast<const s16x4*>(klc + (0 * 64 + sub * 32 + l31) * 16 + hi * 8), qf0, s);
      s = MFMA_B(*reinterpret_cast<const s16x4*>(klc + (1 * 64 + sub * 32 + l31) * 16 + hi * 8), qf1, s);
      s = MFMA_B(*reinterpret_cast<const s16x4*>(klc + (2 * 64 + sub * 32 + l31) * 16 + hi * 8), qf2, s);
      s = MFMA_B(*reinterpret_cast<const s16x4*>(klc + (3 * 64 + sub * 32 + l31) * 16 + hi * 8), qf3, s);
      if (kbs + 32 > klen) {  // mask tail keys
#pragma unroll
        for (int r = 0; r < 16; ++r) {
          const int key = kbs + (r & 3) + 8 * (r >> 2) + 4 * hi;
          if (key >= klen) s[r] = -1e30f;
        }
      }
      float smax = s[0];
#pragma unroll
      for (int r = 1; r < 16; ++r) smax = fmaxf(smax, s[r]);
      smax = fmaxf(smax, __shfl_xor(smax, 32));
      if (smax > mrun + 8.0f) {  // defer-max: rescale only on large max growth
        const float cor = __expf(mrun - smax);
        lrun *= cor;
#pragma unroll
        for (int r = 0; r < 16; ++r) oacc[r] *= cor;
        mrun = smax;
      }
      float p[16];
      float ps = 0.f;
#pragma unroll
      for (int r = 0; r < 16; ++r) {
        p[r] = __expf(s[r] - mrun);
        ps += p[r];
      }
      lrun += ps;
      unsigned pw[8];
#pragma unroll
      for (int i = 0; i < 8; ++i)
        pw[i] = (unsigned)f2bf(p[2 * i]) | ((unsigned)f2bf(p[2 * i + 1]) << 16);
#pragma unroll
      for (int kc = 0; kc < 4; ++kc) {
        union { unsigned u[2]; s16x4 v; } pf;
        pf.u[0] = pw[2 * kc];
        pf.u[1] = pw[2 * kc + 1];
        const s16x4 vf = *reinterpret_cast<const s16x4*>(
            vlc + ((sub * 4 + kc) * 32 + l31) * 16 + hi * 8);
        oacc = MFMA_B(vf, pf.v, oacc);  // O^T[d][q]
      }
    }
  }
  const float ltot = lrun + __shfl_xor(lrun, 32);
  const float inv = 1.0f / ltot;
  if (q0 + l31 < klen) {
    ushort* orow = O + ((size_t)b * KCAP + q0 + l31) * DM + hh * 32;
#pragma unroll
    for (int rq = 0; rq < 4; ++rq) {
      union { unsigned long long u64; ushort us[4]; } o4;
#pragma unroll
      for (int j = 0; j < 4; ++j) o4.us[j] = f2bf(oacc[4 * rq + j] * inv);
      *reinterpret_cast<unsigned long long*>(orow + 8 * rq + 4 * hi) = o4.u64;
    }
  }
}

extern "C" void kernel_launch(void* const* d_in, const int* in_sizes, int n_in,
                              void* d_out, int out_size, void* d_ws, size_t ws_size,
                              hipStream_t stream) {
  (void)in_sizes; (void)n_in; (void)out_size; (void)ws_size;
  const float* features = (const float*)d_in[0];
  const float* salience = (const float*)d_in[1];
  const float* Wq = (const float*)d_in[2];
  const float* Wk = (const float*)d_in[3];
  const float* Wv = (const float*)d_in[4];
  const float* Wo = (const float*)d_in[5];
  const float* W1 = (const float*)d_in[6];
  const float* W2 = (const float*)d_in[7];
  const float* ln1g = (const float*)d_in[8];
  const float* ln1b = (const float*)d_in[9];
  const float* ln2g = (const float*)d_in[10];
  const float* ln2b = (const float*)d_in[11];
  float* out = (float*)d_out;

  // workspace layout
  const size_t SLAB = (size_t)BATCH * KCAP * DM;  // 1.6384M elems
  char* p = (char*)d_ws;
  int* sidx = (int*)p;                 p += 32768;
  int* partial = (int*)p;              p += (size_t)4 * BATCH * NTOK * 4;
  float* xb = (float*)p;               p += SLAB * 4;
  ushort* hb = (ushort*)p;             p += SLAB * 2;
  ushort* qh = (ushort*)p;             p += SLAB * 2;
  ushort* kh = (ushort*)p;             p += SLAB * 2;
  ushort* vt = (ushort*)p;             p += SLAB * 2;
  ushort* ob = (ushort*)p;             p += SLAB * 2;
  ushort* fb = qh;  // FFN intermediate (bf16, 13.1MB) overlays qh|kh|vt|ob
  ushort* wqt = (ushort*)p;            p += (size_t)4 * 256 * 256 * 2;
  ushort* wkt = (ushort*)p;            p += (size_t)4 * 256 * 256 * 2;
  ushort* wvt = (ushort*)p;            p += (size_t)4 * 256 * 256 * 2;
  ushort* wot = (ushort*)p;            p += (size_t)4 * 256 * 256 * 2;
  ushort* w1t = (ushort*)p;            p += (size_t)4 * 256 * 1024 * 2;
  ushort* w2t = (ushort*)p;            p += (size_t)4 * 1024 * 256 * 2;

  hipMemcpyAsync(out, features, (size_t)BATCH * NTOK * DM * sizeof(float),
                 hipMemcpyDeviceToDevice, stream);
  topk_partial<<<dim3((NTOK + 255) / 256, 4, BATCH), 256, 0, stream>>>(salience,
                                                                       partial);
  topk_finalize<<<(BATCH * NTOK + 255) / 256, 256, 0, stream>>>(partial, sidx);
  wprep_kernel<<<dim3(256, 1, 6), 256, 0, stream>>>(Wq, Wk, Wv, Wo, W1, W2, wqt,
                                                    wkt, wvt, wot, w1t, w2t);

  const int klens[4] = {3200, 2400, 2000, 1600};
  for (int l = 0; l < 4; ++l) {
    const int klen = klens[l];
    const int nrb = (klen + 63) >> 6;    // GEMM row blocks (64 rows)
    const int nra = (klen + 127) >> 7;   // attn q blocks (128 queries)
    const size_t wsq = (size_t)l * 256 * 256;
    const size_t wff = (size_t)l * 256 * 1024;
    gather_ln_kernel<<<klen / 2, 256, 0, stream>>>(out, sidx, ln1g + l * DM,
                                                   ln1b + l * DM, xb, hb, klen);
    qkv_kernel<<<dim3(2 * nrb, 4, 3), 256, 0, stream>>>(
        hb, wqt + wsq, wkt + wsq, wvt + wsq, qh, kh, vt, klen);
    attn_kernel<<<dim3(nra, 8, BATCH), 256, 0, stream>>>(qh, kh, vt, ob, klen);
    mgemm_kernel<256, 256, 1, 0><<<dim3(2 * nrb, 4), 256, 0, stream>>>(
        ob, wot + wsq, xb, xb, nullptr, klen);
    ln2_kernel<<<klen / 2, 256, 0, stream>>>(xb, ln2g + l * DM, ln2b + l * DM, hb,
                                             klen);
    mgemm_kernel<256, 1024, 0, 1><<<dim3(2 * nrb, 16), 256, 0, stream>>>(
        hb, w1t + wff, nullptr, fb, nullptr, klen);
    mgemm_kernel<1024, 256, 5, 0><<<dim3(2 * nrb, 4), 256, 0, stream>>>(
        fb, w2t + wff, xb, out, sidx, klen);
  }
}

// Round 5
// 834.854 us; speedup vs baseline: 5.9947x; 1.1555x over previous
//
#include <hip/hip_runtime.h>
#include <math.h>

#define NTOK 8000
#define KCAP 3200
#define BATCH 2
#define DM 256
#define DFF 1024
#define JT 2000       // top-k j-slice per block
#define NB32 (KCAP / 32)  // fragment blocks allocated per (batch,head)

typedef __attribute__((ext_vector_type(4))) short s16x4;
typedef __attribute__((ext_vector_type(16))) float f32x16;

#define MFMA_B(a, b, c) __builtin_amdgcn_mfma_f32_32x32x8bf16_1k(a, b, c, 0, 0, 0)

__device__ __forceinline__ ushort f2bf(float f) {  // RNE float->bf16 bits
  unsigned u = __float_as_uint(f);
  u += 0x7fffu + ((u >> 16) & 1u);
  return (ushort)(u >> 16);
}
__device__ __forceinline__ unsigned cvt_pk_bf16(float lo, float hi) {
  unsigned r;
  asm("v_cvt_pk_bf16_f32 %0, %1, %2" : "=v"(r) : "v"(lo), "v"(hi));
  return r;
}
__device__ __forceinline__ float gelu_tanh(float x) {
  const float z = 0.7978845608028654f * (x + 0.044715f * x * x * x);
  return x * (1.0f / (1.0f + __expf(-2.0f * z)));  // == 0.5x(1+tanh(z))
}
__device__ __forceinline__ f32x16 zero16() {
  f32x16 z;
#pragma unroll
  for (int i = 0; i < 16; ++i) z[i] = 0.f;
  return z;
}

// ---- top-k phase A: partial ranks over a 2000-element j-slice ----
__global__ __launch_bounds__(256) void topk_partial(const float* __restrict__ sal,
                                                    int* __restrict__ partial) {
  const int b = blockIdx.z, jc = blockIdx.y;
  __shared__ float4 s4[JT / 4];
  const float4* src4 = reinterpret_cast<const float4*>(sal + (size_t)b * NTOK + jc * JT);
  for (int e = threadIdx.x; e < JT / 4; e += 256) s4[e] = src4[e];
  __syncthreads();
  const int i = blockIdx.x * 256 + threadIdx.x;
  if (i >= NTOK) return;
  const float si = sal[(size_t)b * NTOK + i];
  int rank = 0;
  const int jbase = jc * JT;
#pragma unroll 4
  for (int e = 0; e < JT / 4; ++e) {
    const float4 v = s4[e];
    const int j = jbase + e * 4;
    rank += (int)((v.x > si) || (v.x == si && j + 0 < i));
    rank += (int)((v.y > si) || (v.y == si && j + 1 < i));
    rank += (int)((v.z > si) || (v.z == si && j + 2 < i));
    rank += (int)((v.w > si) || (v.w == si && j + 3 < i));
  }
  partial[((size_t)jc * BATCH + b) * NTOK + i] = rank;
}

// ---- top-k phase B: sum partials, scatter rank<KCAP into sorted index list ----
__global__ __launch_bounds__(256) void topk_finalize(const int* __restrict__ partial,
                                                     int* __restrict__ sidx) {
  const int gid = blockIdx.x * 256 + threadIdx.x;
  if (gid >= BATCH * NTOK) return;
  const int b = gid / NTOK, i = gid - b * NTOK;
  int rank = 0;
#pragma unroll
  for (int jc = 0; jc < 4; ++jc) rank += partial[((size_t)jc * BATCH + b) * NTOK + i];
  if (rank < KCAP) sidx[b * KCAP + rank] = i;
}

// ---- weight prep: tiled transpose fp32 W[l][K][N] -> bf16 Wt[l][N][K] ----
__global__ __launch_bounds__(256) void wprep_kernel(
    const float* __restrict__ Wq, const float* __restrict__ Wk,
    const float* __restrict__ Wv, const float* __restrict__ Wo,
    const float* __restrict__ W1, const float* __restrict__ W2,
    ushort* __restrict__ wqt, ushort* __restrict__ wkt, ushort* __restrict__ wvt,
    ushort* __restrict__ wot, ushort* __restrict__ w1t, ushort* __restrict__ w2t) {
  const int z = blockIdx.z;
  const float* src;
  ushort* dst;
  int KD, N;
  switch (z) {
    case 0: src = Wq; dst = wqt; KD = 256; N = 256; break;
    case 1: src = Wk; dst = wkt; KD = 256; N = 256; break;
    case 2: src = Wv; dst = wvt; KD = 256; N = 256; break;
    case 3: src = Wo; dst = wot; KD = 256; N = 256; break;
    case 4: src = W1; dst = w1t; KD = 256; N = 1024; break;
    default: src = W2; dst = w2t; KD = 1024; N = 256; break;
  }
  const int ntn = N >> 6;
  const int tpl = (KD >> 6) * ntn;
  if (blockIdx.x >= (unsigned)(4 * tpl)) return;
  const int l = blockIdx.x / tpl;
  const int t = blockIdx.x - l * tpl;
  const int ki = t / ntn, ni = t - ki * ntn;
  __shared__ ushort lds[64][65];
  const int tid = threadIdx.x;
  const int c = tid & 63, rb = tid >> 6;
  const float* sbase = src + ((size_t)l * KD + ki * 64) * N + ni * 64 + c;
#pragma unroll
  for (int rr = 0; rr < 16; ++rr) {
    const int r = rb * 16 + rr;
    lds[c][r] = f2bf(sbase[(size_t)r * N]);
  }
  __syncthreads();
  const int c2 = (tid & 31) << 1, rb2 = tid >> 5;
  ushort* dbase = dst + ((size_t)l * N + ni * 64) * KD + ki * 64 + c2;
#pragma unroll
  for (int rr = 0; rr < 8; ++rr) {
    const int r2 = rb2 * 8 + rr;
    const unsigned u = (unsigned)lds[r2][c2] | ((unsigned)lds[r2][c2 + 1] << 16);
    *reinterpret_cast<unsigned*>(dbase + (size_t)r2 * KD) = u;
  }
}

// ---- gather + LayerNorm1: wave per token, writes x (f32) and h (bf16) ----
__global__ __launch_bounds__(256) void gather_ln_kernel(
    const float* __restrict__ feat, const int* __restrict__ sidx,
    const float* __restrict__ g, const float* __restrict__ bb,
    float* __restrict__ x, ushort* __restrict__ h, int klen) {
  const int w = threadIdx.x >> 6, lane = threadIdx.x & 63;
  const int m = blockIdx.x * 4 + w;
  const int b = m / klen, t = m - b * klen;
  const int tok = sidx[b * KCAP + t];
  const float4 v4 =
      reinterpret_cast<const float4*>(feat + ((size_t)b * NTOK + tok) * DM)[lane];
  reinterpret_cast<float4*>(x + ((size_t)b * KCAP + t) * DM)[lane] = v4;
  float s = v4.x + v4.y + v4.z + v4.w;
#pragma unroll
  for (int off = 1; off < 64; off <<= 1) s += __shfl_xor(s, off);
  const float mu = s * (1.0f / DM);
  const float4 dv = {v4.x - mu, v4.y - mu, v4.z - mu, v4.w - mu};
  float vs = dv.x * dv.x + dv.y * dv.y + dv.z * dv.z + dv.w * dv.w;
#pragma unroll
  for (int off = 1; off < 64; off <<= 1) vs += __shfl_xor(vs, off);
  const float rstd = rsqrtf(vs * (1.0f / DM) + 1e-5f);
  const float4 g4 = reinterpret_cast<const float4*>(g)[lane];
  const float4 b4 = reinterpret_cast<const float4*>(bb)[lane];
  union { unsigned long long u; ushort us[4]; } o;
  o.us[0] = f2bf(dv.x * rstd * g4.x + b4.x);
  o.us[1] = f2bf(dv.y * rstd * g4.y + b4.y);
  o.us[2] = f2bf(dv.z * rstd * g4.z + b4.z);
  o.us[3] = f2bf(dv.w * rstd * g4.w + b4.w);
  reinterpret_cast<unsigned long long*>(h + ((size_t)b * KCAP + t) * DM)[lane] = o.u;
}

// ---- LayerNorm2: wave per token, x (f32) -> h (bf16) ----
__global__ __launch_bounds__(256) void ln2_kernel(
    const float* __restrict__ x, const float* __restrict__ g,
    const float* __restrict__ bb, ushort* __restrict__ h, int klen) {
  const int w = threadIdx.x >> 6, lane = threadIdx.x & 63;
  const int m = blockIdx.x * 4 + w;
  const int b = m / klen, t = m - b * klen;
  const float4 v4 = reinterpret_cast<const float4*>(x + ((size_t)b * KCAP + t) * DM)[lane];
  float s = v4.x + v4.y + v4.z + v4.w;
#pragma unroll
  for (int off = 1; off < 64; off <<= 1) s += __shfl_xor(s, off);
  const float mu = s * (1.0f / DM);
  const float4 dv = {v4.x - mu, v4.y - mu, v4.z - mu, v4.w - mu};
  float vs = dv.x * dv.x + dv.y * dv.y + dv.z * dv.z + dv.w * dv.w;
#pragma unroll
  for (int off = 1; off < 64; off <<= 1) vs += __shfl_xor(vs, off);
  const float rstd = rsqrtf(vs * (1.0f / DM) + 1e-5f);
  const float4 g4 = reinterpret_cast<const float4*>(g)[lane];
  const float4 b4 = reinterpret_cast<const float4*>(bb)[lane];
  union { unsigned long long u; ushort us[4]; } o;
  o.us[0] = f2bf(dv.x * rstd * g4.x + b4.x);
  o.us[1] = f2bf(dv.y * rstd * g4.y + b4.y);
  o.us[2] = f2bf(dv.z * rstd * g4.z + b4.z);
  o.us[3] = f2bf(dv.w * rstd * g4.w + b4.w);
  reinterpret_cast<unsigned long long*>(h + ((size_t)b * KCAP + t) * DM)[lane] = o.u;
}

// ---- MFMA GEMM: wave computes 32x32 tile of C = A[M,KD] @ Wt[N,KD]^T ----
// MODE 0: bf16 out (optional gelu)  MODE 1: f32 out = Res + v
// MODE 5: f32 Res + v scattered to feat via sidx
template <int KD, int ND, int MODE, int ACT>
__global__ __launch_bounds__(256) void mgemm_kernel(
    const ushort* __restrict__ A, const ushort* __restrict__ Wt,
    const float* __restrict__ Res, void* __restrict__ Cv,
    const int* __restrict__ sidx, int klen) {
  const int tid = threadIdx.x;
  const int w = tid >> 6, lane = tid & 63, l31 = lane & 31, hi = lane >> 5;
  const int wrow = w >> 1, wcol = w & 1;
  const int nrb = (klen + 63) >> 6;
  const int b = blockIdx.x / nrb;
  const int t0 = (blockIdx.x - b * nrb) * 64 + wrow * 32;
  const int n0 = blockIdx.y * 64 + wcol * 32;
  const int row = min(t0 + l31, klen - 1);
  const int n = n0 + l31;
  const ushort* Ap = A + ((size_t)b * KCAP + row) * KD + hi * 4;
  const ushort* Wp = Wt + (size_t)n * KD + hi * 4;
  f32x16 acc = zero16();
#pragma unroll 4
  for (int k = 0; k < KD; k += 8) {
    const s16x4 af = *reinterpret_cast<const s16x4*>(Ap + k);
    const s16x4 bf = *reinterpret_cast<const s16x4*>(Wp + k);
    acc = MFMA_B(af, bf, acc);
  }
  const int hi4 = 4 * hi;
#pragma unroll
  for (int r = 0; r < 16; ++r) {
    const int gm = t0 + ((r & 3) + 8 * (r >> 2) + hi4);
    if (gm < klen) {
      const float v0 = acc[r];
      if constexpr (MODE == 0) {
        float v = v0;
        if (ACT) v = gelu_tanh(v);
        ((ushort*)Cv)[((size_t)b * KCAP + gm) * ND + n] = f2bf(v);
      } else if constexpr (MODE == 1) {
        float* C = (float*)Cv;
        const size_t off = ((size_t)b * KCAP + gm) * ND + n;
        C[off] = Res[off] + v0;
      } else {  // MODE 5: residual + scatter to feature bank
        const int tok = sidx[b * KCAP + gm];
        ((float*)Cv)[((size_t)b * NTOK + tok) * ND + n] =
            Res[((size_t)b * KCAP + gm) * ND + n] + v0;
      }
    }
  }
}

// ---- fused Q/K/V projection; K,V written in MFMA-fragment-major layout ----
// Kf/Vf: [bh][kb32][c(4)][lane(64)][4] bf16 — a wave b64-load yields one A-frag.
__global__ __launch_bounds__(256) void qkv_kernel(
    const ushort* __restrict__ A, const ushort* __restrict__ wq,
    const ushort* __restrict__ wk, const ushort* __restrict__ wv,
    ushort* __restrict__ qh, ushort* __restrict__ Kf, ushort* __restrict__ Vf,
    int klen) {
  const int z = blockIdx.z;
  const ushort* Wt = z == 0 ? wq : (z == 1 ? wk : wv);
  const int tid = threadIdx.x;
  const int w = tid >> 6, lane = tid & 63, l31 = lane & 31, hi = lane >> 5;
  const int wrow = w >> 1, wcol = w & 1;
  const int nrb = (klen + 63) >> 6;
  const int b = blockIdx.x / nrb;
  const int t0 = (blockIdx.x - b * nrb) * 64 + wrow * 32;
  const int n0 = blockIdx.y * 64 + wcol * 32;
  const int row = min(t0 + l31, klen - 1);
  const int n = n0 + l31;
  const ushort* Ap = A + ((size_t)b * KCAP + row) * 256 + hi * 4;
  const ushort* Wp = Wt + (size_t)n * 256 + hi * 4;
  f32x16 acc = zero16();
#pragma unroll 4
  for (int k = 0; k < 256; k += 8) {
    const s16x4 af = *reinterpret_cast<const s16x4*>(Ap + k);
    const s16x4 bf = *reinterpret_cast<const s16x4*>(Wp + k);
    acc = MFMA_B(af, bf, acc);
  }
  const int hh = n0 >> 5;
  const int bh = b * 8 + hh;
  const int hi4 = 4 * hi;
  if (z == 0) {  // Q (pre-scaled), head layout [bh][t][32]
#pragma unroll
    for (int r = 0; r < 16; ++r) {
      const int gm = t0 + ((r & 3) + 8 * (r >> 2) + hi4);
      if (gm < klen)
        qh[((size_t)bh * KCAP + gm) * 32 + l31] = f2bf(acc[r] * 0.17677669529663687f);
    }
  } else if (z == 1) {  // K fragment-major: frag dc, lane (hi2,k31), elem e=dim&3
#pragma unroll
    for (int r = 0; r < 16; ++r) {
      const int gm = t0 + ((r & 3) + 8 * (r >> 2) + hi4);
      const ushort val = gm < klen ? f2bf(acc[r]) : (ushort)0;  // zero-fill pad keys
      const int kb = gm >> 5, k31 = gm & 31;
      const int dc = l31 >> 3, hi2 = (l31 >> 2) & 1, e = l31 & 3;
      Kf[(((size_t)bh * NB32 + kb) * 4 + dc) * 256 + (hi2 * 32 + k31) * 4 + e] = val;
    }
  } else {  // V fragment-major: frag kc, lane (hi2,d31), elem e=key&3
#pragma unroll
    for (int r = 0; r < 16; ++r) {
      const int gm = t0 + ((r & 3) + 8 * (r >> 2) + hi4);
      const ushort val = gm < klen ? f2bf(acc[r]) : (ushort)0;
      const int kb = gm >> 5, k31 = gm & 31;
      const int kc = k31 >> 3, hi2 = (k31 >> 2) & 1, e = k31 & 3;
      Vf[(((size_t)bh * NB32 + kb) * 4 + kc) * 256 + (hi2 * 32 + l31) * 4 + e] = val;
    }
  }
}

// ---- flash attention: wave per 32-query tile, LDS-free fragment-direct loads ----
__global__ __launch_bounds__(256) void attn_kernel(
    const ushort* __restrict__ Q, const ushort* __restrict__ Kf,
    const ushort* __restrict__ Vf, ushort* __restrict__ O, int klen) {
  const int hh = blockIdx.y, b = blockIdx.z;
  const int bh = b * 8 + hh;
  const int tid = threadIdx.x;
  const int w = tid >> 6, lane = tid & 63, l31 = lane & 31, hi = lane >> 5;
  const int q0 = (blockIdx.x * 4 + w) * 32;
  const int qg = min(q0 + l31, klen - 1);
  const ushort* qrow = Q + ((size_t)bh * KCAP + qg) * 32;
  const s16x4 qf0 = *reinterpret_cast<const s16x4*>(qrow + 0 + hi * 4);
  const s16x4 qf1 = *reinterpret_cast<const s16x4*>(qrow + 8 + hi * 4);
  const s16x4 qf2 = *reinterpret_cast<const s16x4*>(qrow + 16 + hi * 4);
  const s16x4 qf3 = *reinterpret_cast<const s16x4*>(qrow + 24 + hi * 4);
  const ushort* kfp = Kf + (size_t)bh * NB32 * 1024 + lane * 4;
  const ushort* vfp = Vf + (size_t)bh * NB32 * 1024 + lane * 4;
  f32x16 oacc = zero16();
  float mrun = -INFINITY, lrun = 0.f;
  const int nb = (klen + 31) >> 5;
  // preload K fragments for block 0
  s16x4 kf0 = *reinterpret_cast<const s16x4*>(kfp + 0);
  s16x4 kf1 = *reinterpret_cast<const s16x4*>(kfp + 256);
  s16x4 kf2 = *reinterpret_cast<const s16x4*>(kfp + 512);
  s16x4 kf3 = *reinterpret_cast<const s16x4*>(kfp + 768);
  for (int kb = 0; kb < nb; ++kb) {
    // issue V fragment loads (consumed after softmax)
    const ushort* vb_ = vfp + (size_t)kb * 1024;
    const s16x4 vf0 = *reinterpret_cast<const s16x4*>(vb_ + 0);
    const s16x4 vf1 = *reinterpret_cast<const s16x4*>(vb_ + 256);
    const s16x4 vf2 = *reinterpret_cast<const s16x4*>(vb_ + 512);
    const s16x4 vf3 = *reinterpret_cast<const s16x4*>(vb_ + 768);
    // S^T[key][q] = K . Q^T
    f32x16 s = zero16();
    s = MFMA_B(kf0, qf0, s);
    s = MFMA_B(kf1, qf1, s);
    s = MFMA_B(kf2, qf2, s);
    s = MFMA_B(kf3, qf3, s);
    // prefetch next K block while softmax runs
    if (kb + 1 < nb) {
      const ushort* kn = kfp + (size_t)(kb + 1) * 1024;
      kf0 = *reinterpret_cast<const s16x4*>(kn + 0);
      kf1 = *reinterpret_cast<const s16x4*>(kn + 256);
      kf2 = *reinterpret_cast<const s16x4*>(kn + 512);
      kf3 = *reinterpret_cast<const s16x4*>(kn + 768);
    }
    if ((kb << 5) + 32 > klen) {  // mask tail keys (pad K is zero-filled, no NaN)
#pragma unroll
      for (int r = 0; r < 16; ++r) {
        const int key = (kb << 5) + (r & 3) + 8 * (r >> 2) + 4 * hi;
        if (key >= klen) s[r] = -1e30f;
      }
    }
    float smax = s[0];
#pragma unroll
    for (int r = 1; r < 16; ++r) smax = fmaxf(smax, s[r]);
    smax = fmaxf(smax, __shfl_xor(smax, 32));
    if (smax > mrun + 8.0f) {  // defer-max: rescale only on large max growth
      const float cor = __expf(mrun - smax);
      lrun *= cor;
#pragma unroll
      for (int r = 0; r < 16; ++r) oacc[r] *= cor;
      mrun = smax;
    }
    float p[16];
    float ps = 0.f;
#pragma unroll
    for (int r = 0; r < 16; ++r) {
      p[r] = __expf(s[r] - mrun);
      ps += p[r];
    }
    lrun += ps;
    unsigned pw[8];
#pragma unroll
    for (int i = 0; i < 8; ++i) pw[i] = cvt_pk_bf16(p[2 * i], p[2 * i + 1]);
#pragma unroll
    for (int kc = 0; kc < 4; ++kc) {
      union { unsigned u[2]; s16x4 v; } pf;
      pf.u[0] = pw[2 * kc];
      pf.u[1] = pw[2 * kc + 1];
      const s16x4 vf = kc == 0 ? vf0 : (kc == 1 ? vf1 : (kc == 2 ? vf2 : vf3));
      oacc = MFMA_B(vf, pf.v, oacc);  // O^T[d][q]
    }
  }
  const float ltot = lrun + __shfl_xor(lrun, 32);
  const float inv = 1.0f / ltot;
  if (q0 + l31 < klen) {
    ushort* orow = O + ((size_t)b * KCAP + q0 + l31) * DM + hh * 32;
#pragma unroll
    for (int rq = 0; rq < 4; ++rq) {
      union { unsigned u[2]; unsigned long long u64; } o4;
      o4.u[0] = cvt_pk_bf16(oacc[4 * rq] * inv, oacc[4 * rq + 1] * inv);
      o4.u[1] = cvt_pk_bf16(oacc[4 * rq + 2] * inv, oacc[4 * rq + 3] * inv);
      *reinterpret_cast<unsigned long long*>(orow + 8 * rq + 4 * hi) = o4.u64;
    }
  }
}

extern "C" void kernel_launch(void* const* d_in, const int* in_sizes, int n_in,
                              void* d_out, int out_size, void* d_ws, size_t ws_size,
                              hipStream_t stream) {
  (void)in_sizes; (void)n_in; (void)out_size; (void)ws_size;
  const float* features = (const float*)d_in[0];
  const float* salience = (const float*)d_in[1];
  const float* Wq = (const float*)d_in[2];
  const float* Wk = (const float*)d_in[3];
  const float* Wv = (const float*)d_in[4];
  const float* Wo = (const float*)d_in[5];
  const float* W1 = (const float*)d_in[6];
  const float* W2 = (const float*)d_in[7];
  const float* ln1g = (const float*)d_in[8];
  const float* ln1b = (const float*)d_in[9];
  const float* ln2g = (const float*)d_in[10];
  const float* ln2b = (const float*)d_in[11];
  float* out = (float*)d_out;

  // workspace layout
  const size_t SLAB = (size_t)BATCH * KCAP * DM;  // 1.6384M elems
  char* p = (char*)d_ws;
  int* sidx = (int*)p;                 p += 32768;
  int* partial = (int*)p;              p += (size_t)4 * BATCH * NTOK * 4;
  float* xb = (float*)p;               p += SLAB * 4;
  ushort* hb = (ushort*)p;             p += SLAB * 2;
  ushort* qh = (ushort*)p;             p += SLAB * 2;
  ushort* Kf = (ushort*)p;             p += SLAB * 2;  // fragment-major K
  ushort* Vf = (ushort*)p;             p += SLAB * 2;  // fragment-major V
  ushort* ob = (ushort*)p;             p += SLAB * 2;
  ushort* fb = qh;  // FFN intermediate (bf16, 13.1MB) overlays qh|Kf|Vf|ob
  ushort* wqt = (ushort*)p;            p += (size_t)4 * 256 * 256 * 2;
  ushort* wkt = (ushort*)p;            p += (size_t)4 * 256 * 256 * 2;
  ushort* wvt = (ushort*)p;            p += (size_t)4 * 256 * 256 * 2;
  ushort* wot = (ushort*)p;            p += (size_t)4 * 256 * 256 * 2;
  ushort* w1t = (ushort*)p;            p += (size_t)4 * 256 * 1024 * 2;
  ushort* w2t = (ushort*)p;            p += (size_t)4 * 1024 * 256 * 2;

  hipMemcpyAsync(out, features, (size_t)BATCH * NTOK * DM * sizeof(float),
                 hipMemcpyDeviceToDevice, stream);
  topk_partial<<<dim3((NTOK + 255) / 256, 4, BATCH), 256, 0, stream>>>(salience,
                                                                       partial);
  topk_finalize<<<(BATCH * NTOK + 255) / 256, 256, 0, stream>>>(partial, sidx);
  wprep_kernel<<<dim3(256, 1, 6), 256, 0, stream>>>(Wq, Wk, Wv, Wo, W1, W2, wqt,
                                                    wkt, wvt, wot, w1t, w2t);

  const int klens[4] = {3200, 2400, 2000, 1600};
  for (int l = 0; l < 4; ++l) {
    const int klen = klens[l];
    const int nrb = (klen + 63) >> 6;    // GEMM row blocks (64 rows)
    const int nra = (klen + 127) >> 7;   // attn q blocks (128 queries)
    const size_t wsq = (size_t)l * 256 * 256;
    const size_t wff = (size_t)l * 256 * 1024;
    gather_ln_kernel<<<klen / 2, 256, 0, stream>>>(out, sidx, ln1g + l * DM,
                                                   ln1b + l * DM, xb, hb, klen);
    qkv_kernel<<<dim3(2 * nrb, 4, 3), 256, 0, stream>>>(
        hb, wqt + wsq, wkt + wsq, wvt + wsq, qh, Kf, Vf, klen);
    attn_kernel<<<dim3(nra, 8, BATCH), 256, 0, stream>>>(qh, Kf, Vf, ob, klen);
    mgemm_kernel<256, 256, 1, 0><<<dim3(2 * nrb, 4), 256, 0, stream>>>(
        ob, wot + wsq, xb, xb, nullptr, klen);
    ln2_kernel<<<klen / 2, 256, 0, stream>>>(xb, ln2g + l * DM, ln2b + l * DM, hb,
                                             klen);
    mgemm_kernel<256, 1024, 0, 1><<<dim3(2 * nrb, 16), 256, 0, stream>>>(
        hb, w1t + wff, nullptr, fb, nullptr, klen);
    mgemm_kernel<1024, 256, 5, 0><<<dim3(2 * nrb, 4), 256, 0, stream>>>(
        fb, w2t + wff, xb, out, sidx, klen);
  }
}

// Round 6
// 509.831 us; speedup vs baseline: 9.8164x; 1.6375x over previous
//
#include <hip/hip_runtime.h>
#include <math.h>

#define NTOK 8000
#define KCAP 3200
#define BATCH 2
#define DM 256
#define DFF 1024
#define JT 2000           // top-k j-slice per block
#define NB32 (KCAP / 32)  // fragment blocks per (batch,head)

typedef __attribute__((ext_vector_type(4))) short s16x4;
typedef __attribute__((ext_vector_type(16))) float f32x16;

#define MFMA_B(a, b, c) __builtin_amdgcn_mfma_f32_32x32x8bf16_1k(a, b, c, 0, 0, 0)

__device__ __forceinline__ ushort f2bf(float f) {  // RNE float->bf16 bits
  unsigned u = __float_as_uint(f);
  u += 0x7fffu + ((u >> 16) & 1u);
  return (ushort)(u >> 16);
}
__device__ __forceinline__ unsigned cvt_pk_bf16(float lo, float hi) {
  unsigned r;
  asm("v_cvt_pk_bf16_f32 %0, %1, %2" : "=v"(r) : "v"(lo), "v"(hi));
  return r;
}
__device__ __forceinline__ float gelu_tanh(float x) {
  const float z = 0.7978845608028654f * (x + 0.044715f * x * x * x);
  return x * (1.0f / (1.0f + __expf(-2.0f * z)));  // == 0.5x(1+tanh(z))
}
__device__ __forceinline__ f32x16 zero16() {
  f32x16 z;
#pragma unroll
  for (int i = 0; i < 16; ++i) z[i] = 0.f;
  return z;
}

// ---- top-k phase A: partial ranks over a 2000-element j-slice ----
__global__ __launch_bounds__(256) void topk_partial(const float* __restrict__ sal,
                                                    int* __restrict__ partial) {
  const int b = blockIdx.z, jc = blockIdx.y;
  __shared__ float4 s4[JT / 4];
  const float4* src4 = reinterpret_cast<const float4*>(sal + (size_t)b * NTOK + jc * JT);
  for (int e = threadIdx.x; e < JT / 4; e += 256) s4[e] = src4[e];
  __syncthreads();
  const int i = blockIdx.x * 256 + threadIdx.x;
  if (i >= NTOK) return;
  const float si = sal[(size_t)b * NTOK + i];
  int rank = 0;
  const int jbase = jc * JT;
#pragma unroll 4
  for (int e = 0; e < JT / 4; ++e) {
    const float4 v = s4[e];
    const int j = jbase + e * 4;
    rank += (int)((v.x > si) || (v.x == si && j + 0 < i));
    rank += (int)((v.y > si) || (v.y == si && j + 1 < i));
    rank += (int)((v.z > si) || (v.z == si && j + 2 < i));
    rank += (int)((v.w > si) || (v.w == si && j + 3 < i));
  }
  partial[((size_t)jc * BATCH + b) * NTOK + i] = rank;
}

// ---- top-k phase B: sum partials, scatter rank<KCAP into sorted index list ----
__global__ __launch_bounds__(256) void topk_finalize(const int* __restrict__ partial,
                                                     int* __restrict__ sidx) {
  const int gid = blockIdx.x * 256 + threadIdx.x;
  if (gid >= BATCH * NTOK) return;
  const int b = gid / NTOK, i = gid - b * NTOK;
  int rank = 0;
#pragma unroll
  for (int jc = 0; jc < 4; ++jc) rank += partial[((size_t)jc * BATCH + b) * NTOK + i];
  if (rank < KCAP) sidx[b * KCAP + rank] = i;
}

// ---- weight prep: fp32 W[l][K][N] -> bf16 MFMA-fragment-major ----
// wf[l][g][sg][lane][e] = W[l][sg*8 + (lane>>5)*4 + e][g*32 + (lane&31)]
template <int KD, int N, int LKS, int LN32>
__device__ __forceinline__ void wprep_one(const float* __restrict__ src,
                                          ushort* __restrict__ dst, int slot) {
  const int lane = slot & 63;
  const int sg = (slot >> 6) & ((1 << LKS) - 1);
  const int g = (slot >> (6 + LKS)) & ((1 << LN32) - 1);
  const int l = slot >> (6 + LKS + LN32);
  const int n = g * 32 + (lane & 31);
  const int k = sg * 8 + (lane >> 5) * 4;
  const float* s = src + ((size_t)l * KD + k) * N + n;
  union { unsigned long long u; ushort us[4]; } o;
#pragma unroll
  for (int e = 0; e < 4; ++e) o.us[e] = f2bf(s[(size_t)e * N]);
  *reinterpret_cast<unsigned long long*>(dst + (size_t)slot * 4) = o.u;
}

__global__ __launch_bounds__(256) void wprep_kernel(
    const float* __restrict__ Wq, const float* __restrict__ Wk,
    const float* __restrict__ Wv, const float* __restrict__ Wo,
    const float* __restrict__ W1, const float* __restrict__ W2,
    ushort* __restrict__ wqt, ushort* __restrict__ wkt, ushort* __restrict__ wvt,
    ushort* __restrict__ wot, ushort* __restrict__ w1t, ushort* __restrict__ w2t) {
  const int z = blockIdx.z;
  const int slot = blockIdx.x * 256 + threadIdx.x;
  if (z < 4) {  // 256x256: N32=8, KS=32 -> 65536 slots
    if (slot >= 4 * 8 * 32 * 64) return;
    const float* src = z == 0 ? Wq : (z == 1 ? Wk : (z == 2 ? Wv : Wo));
    ushort* dst = z == 0 ? wqt : (z == 1 ? wkt : (z == 2 ? wvt : wot));
    wprep_one<256, 256, 5, 3>(src, dst, slot);
  } else if (z == 4) {  // 256x1024: N32=32, KS=32 -> 262144 slots
    if (slot >= 4 * 32 * 32 * 64) return;
    wprep_one<256, 1024, 5, 5>(W1, w1t, slot);
  } else {  // 1024x256: N32=8, KS=128 -> 262144 slots
    if (slot >= 4 * 8 * 128 * 64) return;
    wprep_one<1024, 256, 7, 3>(W2, w2t, slot);
  }
}

// ---- gather + LayerNorm1: wave per token, writes x (f32) and h (bf16) ----
__global__ __launch_bounds__(256) void gather_ln_kernel(
    const float* __restrict__ feat, const int* __restrict__ sidx,
    const float* __restrict__ g, const float* __restrict__ bb,
    float* __restrict__ x, ushort* __restrict__ h, int klen) {
  const int w = threadIdx.x >> 6, lane = threadIdx.x & 63;
  const int m = blockIdx.x * 4 + w;
  const int b = m / klen, t = m - b * klen;
  const int tok = sidx[b * KCAP + t];
  const float4 v4 =
      reinterpret_cast<const float4*>(feat + ((size_t)b * NTOK + tok) * DM)[lane];
  reinterpret_cast<float4*>(x + ((size_t)b * KCAP + t) * DM)[lane] = v4;
  float s = v4.x + v4.y + v4.z + v4.w;
#pragma unroll
  for (int off = 1; off < 64; off <<= 1) s += __shfl_xor(s, off);
  const float mu = s * (1.0f / DM);
  const float4 dv = {v4.x - mu, v4.y - mu, v4.z - mu, v4.w - mu};
  float vs = dv.x * dv.x + dv.y * dv.y + dv.z * dv.z + dv.w * dv.w;
#pragma unroll
  for (int off = 1; off < 64; off <<= 1) vs += __shfl_xor(vs, off);
  const float rstd = rsqrtf(vs * (1.0f / DM) + 1e-5f);
  const float4 g4 = reinterpret_cast<const float4*>(g)[lane];
  const float4 b4 = reinterpret_cast<const float4*>(bb)[lane];
  union { unsigned long long u; ushort us[4]; } o;
  o.us[0] = f2bf(dv.x * rstd * g4.x + b4.x);
  o.us[1] = f2bf(dv.y * rstd * g4.y + b4.y);
  o.us[2] = f2bf(dv.z * rstd * g4.z + b4.z);
  o.us[3] = f2bf(dv.w * rstd * g4.w + b4.w);
  reinterpret_cast<unsigned long long*>(h + ((size_t)b * KCAP + t) * DM)[lane] = o.u;
}

// ---- LayerNorm2: wave per token, x (f32) -> h (bf16) ----
__global__ __launch_bounds__(256) void ln2_kernel(
    const float* __restrict__ x, const float* __restrict__ g,
    const float* __restrict__ bb, ushort* __restrict__ h, int klen) {
  const int w = threadIdx.x >> 6, lane = threadIdx.x & 63;
  const int m = blockIdx.x * 4 + w;
  const int b = m / klen, t = m - b * klen;
  const float4 v4 = reinterpret_cast<const float4*>(x + ((size_t)b * KCAP + t) * DM)[lane];
  float s = v4.x + v4.y + v4.z + v4.w;
#pragma unroll
  for (int off = 1; off < 64; off <<= 1) s += __shfl_xor(s, off);
  const float mu = s * (1.0f / DM);
  const float4 dv = {v4.x - mu, v4.y - mu, v4.z - mu, v4.w - mu};
  float vs = dv.x * dv.x + dv.y * dv.y + dv.z * dv.z + dv.w * dv.w;
#pragma unroll
  for (int off = 1; off < 64; off <<= 1) vs += __shfl_xor(vs, off);
  const float rstd = rsqrtf(vs * (1.0f / DM) + 1e-5f);
  const float4 g4 = reinterpret_cast<const float4*>(g)[lane];
  const float4 b4 = reinterpret_cast<const float4*>(bb)[lane];
  union { unsigned long long u; ushort us[4]; } o;
  o.us[0] = f2bf(dv.x * rstd * g4.x + b4.x);
  o.us[1] = f2bf(dv.y * rstd * g4.y + b4.y);
  o.us[2] = f2bf(dv.z * rstd * g4.z + b4.z);
  o.us[3] = f2bf(dv.w * rstd * g4.w + b4.w);
  reinterpret_cast<unsigned long long*>(h + ((size_t)b * KCAP + t) * DM)[lane] = o.u;
}

// ---- GEMM core: block = 32 rows x 256 cols, wave = 32x64 (2 acc tiles) ----
// A row-major [t][APITCH] bf16 staged to LDS (XOR-swizzled), B fragment-major.
template <int APITCH, int KCHUNKS>
__device__ __forceinline__ void gemm_core(
    const ushort* __restrict__ A, const ushort* __restrict__ wf,
    unsigned long long* lA, int b, int t0, int klen, f32x16& acc0, f32x16& acc1) {
  constexpr int KSTEPS = KCHUNKS * 32;
  const int tid = threadIdx.x;
  const int lane = tid & 63, l31 = lane & 31, hi = lane >> 5, w = tid >> 6;
  const int srow = tid >> 5, sl = tid & 31;
  acc0 = zero16();
  acc1 = zero16();
  const ushort* w0 = wf + ((size_t)(w * 2) * KSTEPS + 0) * 256 + lane * 4;
  const ushort* w1p = w0 + (size_t)KSTEPS * 256;
  for (int kc = 0; kc < KCHUNKS; ++kc) {
    if (kc) __syncthreads();
#pragma unroll
    for (int p = 0; p < 4; ++p) {
      const int row = p * 8 + srow;
      const size_t grow = (size_t)(b * KCAP + min(t0 + row, klen - 1));
      union { uint4 q; unsigned long long d[2]; } u;
      u.q = *reinterpret_cast<const uint4*>(A + grow * APITCH + kc * 256 + sl * 8);
      const int rx = row ^ (sl & 15);
      lA[(sl * 2) * 32 + rx] = u.d[0];
      lA[(sl * 2 + 1) * 32 + rx] = u.d[1];
    }
    __syncthreads();
    const ushort* wc0 = w0 + (size_t)kc * 32 * 256;
    const ushort* wc1 = w1p + (size_t)kc * 32 * 256;
#pragma unroll 8
    for (int s = 0; s < 32; ++s) {
      union { unsigned long long d; s16x4 v; } a;
      a.d = lA[(s * 2 + hi) * 32 + (l31 ^ (s & 15))];
      const s16x4 b0 = *reinterpret_cast<const s16x4*>(wc0 + s * 256);
      const s16x4 b1 = *reinterpret_cast<const s16x4*>(wc1 + s * 256);
      acc0 = MFMA_B(a.v, b0, acc0);
      acc1 = MFMA_B(a.v, b1, acc1);
    }
  }
}

// ---- fused Q/K/V projection (blockIdx.y selects q/k/v) ----
__global__ __launch_bounds__(256) void qkv_kernel(
    const ushort* __restrict__ hb, const ushort* __restrict__ wq,
    const ushort* __restrict__ wk, const ushort* __restrict__ wv,
    ushort* __restrict__ qh, ushort* __restrict__ Kf, ushort* __restrict__ Vf,
    int klen) {
  __shared__ unsigned long long lA[2048];
  const int z = blockIdx.y;
  const ushort* wf = z == 0 ? wq : (z == 1 ? wk : wv);
  const int nrb = (klen + 31) >> 5;
  const int b = blockIdx.x / nrb;
  const int t0 = (blockIdx.x - b * nrb) * 32;
  f32x16 a0, a1;
  gemm_core<256, 1>(hb, wf, lA, b, t0, klen, a0, a1);
  const int lane = threadIdx.x & 63, l31 = lane & 31, hi = lane >> 5;
  const int w = threadIdx.x >> 6;
  const int hi4 = 4 * hi;
#pragma unroll
  for (int blk = 0; blk < 2; ++blk) {
    const f32x16& acc = blk ? a1 : a0;
    const int hh = w * 2 + blk;
    const int bh = b * 8 + hh;
    if (z == 0) {  // Q pre-scaled, head layout [bh][t][32]
#pragma unroll
      for (int r = 0; r < 16; ++r) {
        const int gm = t0 + ((r & 3) + 8 * (r >> 2) + hi4);
        if (gm < klen)
          qh[((size_t)bh * KCAP + gm) * 32 + l31] = f2bf(acc[r] * 0.17677669529663687f);
      }
    } else if (z == 1) {  // K fragment-major
#pragma unroll
      for (int r = 0; r < 16; ++r) {
        const int gm = t0 + ((r & 3) + 8 * (r >> 2) + hi4);
        const ushort val = gm < klen ? f2bf(acc[r]) : (ushort)0;
        const int kb = gm >> 5, k31 = gm & 31;
        const int dc = l31 >> 3, hi2 = (l31 >> 2) & 1, e = l31 & 3;
        Kf[(((size_t)bh * NB32 + kb) * 4 + dc) * 256 + (hi2 * 32 + k31) * 4 + e] = val;
      }
    } else {  // V fragment-major
#pragma unroll
      for (int r = 0; r < 16; ++r) {
        const int gm = t0 + ((r & 3) + 8 * (r >> 2) + hi4);
        const ushort val = gm < klen ? f2bf(acc[r]) : (ushort)0;
        const int kb = gm >> 5, k31 = gm & 31;
        const int kc = k31 >> 3, hi2 = (k31 >> 2) & 1, e = k31 & 3;
        Vf[(((size_t)bh * NB32 + kb) * 4 + kc) * 256 + (hi2 * 32 + l31) * 4 + e] = val;
      }
    }
  }
}

// ---- Wo GEMM: xb += ob @ Wo (residual in place) ----
__global__ __launch_bounds__(256) void wo_kernel(const ushort* __restrict__ ob,
                                                 const ushort* __restrict__ wf,
                                                 float* __restrict__ xb, int klen) {
  __shared__ unsigned long long lA[2048];
  const int nrb = (klen + 31) >> 5;
  const int b = blockIdx.x / nrb;
  const int t0 = (blockIdx.x - b * nrb) * 32;
  f32x16 a0, a1;
  gemm_core<256, 1>(ob, wf, lA, b, t0, klen, a0, a1);
  const int lane = threadIdx.x & 63, l31 = lane & 31, hi = lane >> 5;
  const int w = threadIdx.x >> 6;
  const int hi4 = 4 * hi;
#pragma unroll
  for (int blk = 0; blk < 2; ++blk) {
    const f32x16& acc = blk ? a1 : a0;
    const int n = w * 64 + blk * 32 + l31;
#pragma unroll
    for (int r = 0; r < 16; ++r) {
      const int gm = t0 + ((r & 3) + 8 * (r >> 2) + hi4);
      if (gm < klen) {
        const size_t off = ((size_t)b * KCAP + gm) * DM + n;
        xb[off] += acc[r];
      }
    }
  }
}

// ---- W1 GEMM: fb = gelu(hb @ W1), blockIdx.y = 256-col group ----
__global__ __launch_bounds__(256) void w1_kernel(const ushort* __restrict__ hb,
                                                 const ushort* __restrict__ w1,
                                                 ushort* __restrict__ fb, int klen) {
  __shared__ unsigned long long lA[2048];
  const int nrb = (klen + 31) >> 5;
  const int b = blockIdx.x / nrb;
  const int t0 = (blockIdx.x - b * nrb) * 32;
  const ushort* wf = w1 + (size_t)blockIdx.y * 65536;
  f32x16 a0, a1;
  gemm_core<256, 1>(hb, wf, lA, b, t0, klen, a0, a1);
  const int lane = threadIdx.x & 63, l31 = lane & 31, hi = lane >> 5;
  const int w = threadIdx.x >> 6;
  const int hi4 = 4 * hi;
#pragma unroll
  for (int blk = 0; blk < 2; ++blk) {
    const f32x16& acc = blk ? a1 : a0;
    const int n = blockIdx.y * 256 + w * 64 + blk * 32 + l31;
#pragma unroll
    for (int r = 0; r < 16; ++r) {
      const int gm = t0 + ((r & 3) + 8 * (r >> 2) + hi4);
      if (gm < klen)
        fb[((size_t)b * KCAP + gm) * DFF + n] = f2bf(gelu_tanh(acc[r]));
    }
  }
}

// ---- W2 GEMM: out[tok] = xb + fb @ W2 (residual + scatter) ----
__global__ __launch_bounds__(256) void w2_kernel(
    const ushort* __restrict__ fb, const ushort* __restrict__ wf,
    const float* __restrict__ xb, float* __restrict__ out,
    const int* __restrict__ sidx, int klen) {
  __shared__ unsigned long long lA[2048];
  const int nrb = (klen + 31) >> 5;
  const int b = blockIdx.x / nrb;
  const int t0 = (blockIdx.x - b * nrb) * 32;
  f32x16 a0, a1;
  gemm_core<1024, 4>(fb, wf, lA, b, t0, klen, a0, a1);
  const int lane = threadIdx.x & 63, l31 = lane & 31, hi = lane >> 5;
  const int w = threadIdx.x >> 6;
  const int hi4 = 4 * hi;
#pragma unroll
  for (int blk = 0; blk < 2; ++blk) {
    const f32x16& acc = blk ? a1 : a0;
    const int n = w * 64 + blk * 32 + l31;
#pragma unroll
    for (int r = 0; r < 16; ++r) {
      const int gm = t0 + ((r & 3) + 8 * (r >> 2) + hi4);
      if (gm < klen) {
        const int tok = sidx[b * KCAP + gm];
        out[((size_t)b * NTOK + tok) * DM + n] =
            xb[((size_t)b * KCAP + gm) * DM + n] + acc[r];
      }
    }
  }
}

// ---- flash attention: block = one 32-q tile, 4 waves split keys 4-way ----
__global__ __launch_bounds__(256) void attn_kernel(
    const ushort* __restrict__ Q, const ushort* __restrict__ Kf,
    const ushort* __restrict__ Vf, ushort* __restrict__ O, int klen) {
  const int hh = blockIdx.y, b = blockIdx.z;
  const int bh = b * 8 + hh;
  const int tid = threadIdx.x;
  const int w = tid >> 6, lane = tid & 63, l31 = lane & 31, hi = lane >> 5;
  __shared__ float red[4 * 64 * 20];  // per-wave partials: o[16], m, l (stride 20)
  const int q0 = blockIdx.x * 32;
  const int qg = min(q0 + l31, klen - 1);
  const ushort* qrow = Q + ((size_t)bh * KCAP + qg) * 32;
  const s16x4 qf0 = *reinterpret_cast<const s16x4*>(qrow + 0 + hi * 4);
  const s16x4 qf1 = *reinterpret_cast<const s16x4*>(qrow + 8 + hi * 4);
  const s16x4 qf2 = *reinterpret_cast<const s16x4*>(qrow + 16 + hi * 4);
  const s16x4 qf3 = *reinterpret_cast<const s16x4*>(qrow + 24 + hi * 4);
  const ushort* kfp = Kf + (size_t)bh * NB32 * 1024 + lane * 4;
  const ushort* vfp = Vf + (size_t)bh * NB32 * 1024 + lane * 4;
  f32x16 oacc = zero16();
  float mrun = -INFINITY, lrun = 0.f;
  const int nb = (klen + 31) >> 5;
  const int qq = nb >> 2, rr = nb & 3;
  const int kb0 = w * qq + min(w, rr);
  const int kbn = kb0 + qq + (w < rr ? 1 : 0);
  for (int kb = kb0; kb < kbn; ++kb) {
    const ushort* kb_ = kfp + (size_t)kb * 1024;
    const ushort* vb_ = vfp + (size_t)kb * 1024;
    const s16x4 kf0 = *reinterpret_cast<const s16x4*>(kb_ + 0);
    const s16x4 kf1 = *reinterpret_cast<const s16x4*>(kb_ + 256);
    const s16x4 kf2 = *reinterpret_cast<const s16x4*>(kb_ + 512);
    const s16x4 kf3 = *reinterpret_cast<const s16x4*>(kb_ + 768);
    const s16x4 vf0 = *reinterpret_cast<const s16x4*>(vb_ + 0);
    const s16x4 vf1 = *reinterpret_cast<const s16x4*>(vb_ + 256);
    const s16x4 vf2 = *reinterpret_cast<const s16x4*>(vb_ + 512);
    const s16x4 vf3 = *reinterpret_cast<const s16x4*>(vb_ + 768);
    f32x16 s = zero16();
    s = MFMA_B(kf0, qf0, s);
    s = MFMA_B(kf1, qf1, s);
    s = MFMA_B(kf2, qf2, s);
    s = MFMA_B(kf3, qf3, s);
    if ((kb << 5) + 32 > klen) {  // mask tail keys (pad K zero-filled)
#pragma unroll
      for (int r = 0; r < 16; ++r) {
        const int key = (kb << 5) + (r & 3) + 8 * (r >> 2) + 4 * hi;
        if (key >= klen) s[r] = -1e30f;
      }
    }
    float smax = s[0];
#pragma unroll
    for (int r = 1; r < 16; ++r) smax = fmaxf(smax, s[r]);
    smax = fmaxf(smax, __shfl_xor(smax, 32));
    if (smax > mrun + 8.0f) {  // defer-max: rescale only on large max growth
      const float cor = __expf(mrun - smax);
      lrun *= cor;
#pragma unroll
      for (int r = 0; r < 16; ++r) oacc[r] *= cor;
      mrun = smax;
    }
    float p[16];
    float ps = 0.f;
#pragma unroll
    for (int r = 0; r < 16; ++r) {
      p[r] = __expf(s[r] - mrun);
      ps += p[r];
    }
    lrun += ps;
    unsigned pw[8];
#pragma unroll
    for (int i = 0; i < 8; ++i) pw[i] = cvt_pk_bf16(p[2 * i], p[2 * i + 1]);
#pragma unroll
    for (int kc = 0; kc < 4; ++kc) {
      union { unsigned u[2]; s16x4 v; } pf;
      pf.u[0] = pw[2 * kc];
      pf.u[1] = pw[2 * kc + 1];
      const s16x4 vf = kc == 0 ? vf0 : (kc == 1 ? vf1 : (kc == 2 ? vf2 : vf3));
      oacc = MFMA_B(vf, pf.v, oacc);  // O^T[d][q]
    }
  }
  // write per-wave partials, merge in wave 0
  float* myr = red + (w * 64 + lane) * 20;
#pragma unroll
  for (int r = 0; r < 16; ++r) myr[r] = oacc[r];
  myr[16] = mrun;
  myr[17] = lrun;
  __syncthreads();
  if (w == 0) {
    float M = mrun;
#pragma unroll
    for (int w2 = 1; w2 < 4; ++w2) M = fmaxf(M, red[(w2 * 64 + lane) * 20 + 16]);
    const float c0 = __expf(mrun - M);
    float l = lrun * c0;
    f32x16 o;
#pragma unroll
    for (int r = 0; r < 16; ++r) o[r] = oacc[r] * c0;
#pragma unroll
    for (int w2 = 1; w2 < 4; ++w2) {
      const float* pr = red + (w2 * 64 + lane) * 20;
      const float c = __expf(pr[16] - M);
      l += pr[17] * c;
#pragma unroll
      for (int r = 0; r < 16; ++r) o[r] = fmaf(pr[r], c, o[r]);
    }
    const float ltot = l + __shfl_xor(l, 32);
    const float inv = 1.0f / ltot;
    if (q0 + l31 < klen) {
      ushort* orow = O + ((size_t)b * KCAP + q0 + l31) * DM + hh * 32;
#pragma unroll
      for (int rq = 0; rq < 4; ++rq) {
        union { unsigned u[2]; unsigned long long u64; } o4;
        o4.u[0] = cvt_pk_bf16(o[4 * rq] * inv, o[4 * rq + 1] * inv);
        o4.u[1] = cvt_pk_bf16(o[4 * rq + 2] * inv, o[4 * rq + 3] * inv);
        *reinterpret_cast<unsigned long long*>(orow + 8 * rq + 4 * hi) = o4.u64;
      }
    }
  }
}

extern "C" void kernel_launch(void* const* d_in, const int* in_sizes, int n_in,
                              void* d_out, int out_size, void* d_ws, size_t ws_size,
                              hipStream_t stream) {
  (void)in_sizes; (void)n_in; (void)out_size; (void)ws_size;
  const float* features = (const float*)d_in[0];
  const float* salience = (const float*)d_in[1];
  const float* Wq = (const float*)d_in[2];
  const float* Wk = (const float*)d_in[3];
  const float* Wv = (const float*)d_in[4];
  const float* Wo = (const float*)d_in[5];
  const float* W1 = (const float*)d_in[6];
  const float* W2 = (const float*)d_in[7];
  const float* ln1g = (const float*)d_in[8];
  const float* ln1b = (const float*)d_in[9];
  const float* ln2g = (const float*)d_in[10];
  const float* ln2b = (const float*)d_in[11];
  float* out = (float*)d_out;

  // workspace layout (unchanged sizes from round 5)
  const size_t SLAB = (size_t)BATCH * KCAP * DM;
  char* p = (char*)d_ws;
  int* sidx = (int*)p;                 p += 32768;
  int* partial = (int*)p;              p += (size_t)4 * BATCH * NTOK * 4;
  float* xb = (float*)p;               p += SLAB * 4;
  ushort* hb = (ushort*)p;             p += SLAB * 2;
  ushort* qh = (ushort*)p;             p += SLAB * 2;
  ushort* Kf = (ushort*)p;             p += SLAB * 2;
  ushort* Vf = (ushort*)p;             p += SLAB * 2;
  ushort* ob = (ushort*)p;             p += SLAB * 2;
  ushort* fb = qh;  // FFN intermediate (13.1MB) overlays qh|Kf|Vf|ob
  ushort* wqt = (ushort*)p;            p += (size_t)4 * 256 * 256 * 2;
  ushort* wkt = (ushort*)p;            p += (size_t)4 * 256 * 256 * 2;
  ushort* wvt = (ushort*)p;            p += (size_t)4 * 256 * 256 * 2;
  ushort* wot = (ushort*)p;            p += (size_t)4 * 256 * 256 * 2;
  ushort* w1t = (ushort*)p;            p += (size_t)4 * 256 * 1024 * 2;
  ushort* w2t = (ushort*)p;            p += (size_t)4 * 1024 * 256 * 2;

  hipMemcpyAsync(out, features, (size_t)BATCH * NTOK * DM * sizeof(float),
                 hipMemcpyDeviceToDevice, stream);
  topk_partial<<<dim3((NTOK + 255) / 256, 4, BATCH), 256, 0, stream>>>(salience,
                                                                       partial);
  topk_finalize<<<(BATCH * NTOK + 255) / 256, 256, 0, stream>>>(partial, sidx);
  wprep_kernel<<<dim3(1024, 1, 6), 256, 0, stream>>>(Wq, Wk, Wv, Wo, W1, W2, wqt,
                                                     wkt, wvt, wot, w1t, w2t);

  const int klens[4] = {3200, 2400, 2000, 1600};
  for (int l = 0; l < 4; ++l) {
    const int klen = klens[l];
    const int nrb = (klen + 31) >> 5;  // 32-row tiles
    const size_t wsq = (size_t)l * 256 * 256;
    const size_t wff = (size_t)l * 256 * 1024;
    gather_ln_kernel<<<klen / 2, 256, 0, stream>>>(out, sidx, ln1g + l * DM,
                                                   ln1b + l * DM, xb, hb, klen);
    qkv_kernel<<<dim3(2 * nrb, 3), 256, 0, stream>>>(
        hb, wqt + wsq, wkt + wsq, wvt + wsq, qh, Kf, Vf, klen);
    attn_kernel<<<dim3(nrb, 8, BATCH), 256, 0, stream>>>(qh, Kf, Vf, ob, klen);
    wo_kernel<<<dim3(2 * nrb, 1), 256, 0, stream>>>(ob, wot + wsq, xb, klen);
    ln2_kernel<<<klen / 2, 256, 0, stream>>>(xb, ln2g + l * DM, ln2b + l * DM, hb,
                                             klen);
    w1_kernel<<<dim3(2 * nrb, 4), 256, 0, stream>>>(hb, w1t + wff, fb, klen);
    w2_kernel<<<dim3(2 * nrb, 1), 256, 0, stream>>>(fb, w2t + wff, xb, out, sidx,
                                                    klen);
  }
}

// Round 7
// 485.314 us; speedup vs baseline: 10.3123x; 1.0505x over previous
//
#include <hip/hip_runtime.h>
#include <math.h>

#define NTOK 8000
#define KCAP 3200
#define BATCH 2
#define DM 256
#define DFF 1024
#define JT 2000           // top-k j-slice per block
#define NB32 (KCAP / 32)  // fragment blocks per (batch,head)

typedef __attribute__((ext_vector_type(4))) short s16x4;
typedef __attribute__((ext_vector_type(16))) float f32x16;

#define MFMA_B(a, b, c) __builtin_amdgcn_mfma_f32_32x32x8bf16_1k(a, b, c, 0, 0, 0)

__device__ __forceinline__ ushort f2bf(float f) {  // RNE float->bf16 bits
  unsigned u = __float_as_uint(f);
  u += 0x7fffu + ((u >> 16) & 1u);
  return (ushort)(u >> 16);
}
__device__ __forceinline__ unsigned cvt_pk_bf16(float lo, float hi) {
  unsigned r;
  asm("v_cvt_pk_bf16_f32 %0, %1, %2" : "=v"(r) : "v"(lo), "v"(hi));
  return r;
}
__device__ __forceinline__ float fast_exp2(float x) {  // 2^x, raw v_exp
  float r;
  asm("v_exp_f32 %0, %1" : "=v"(r) : "v"(x));
  return r;
}
__device__ __forceinline__ float gelu_tanh(float x) {
  const float z = 0.7978845608028654f * (x + 0.044715f * x * x * x);
  return x * (1.0f / (1.0f + __expf(-2.0f * z)));  // == 0.5x(1+tanh(z))
}
__device__ __forceinline__ f32x16 zero16() {
  f32x16 z;
#pragma unroll
  for (int i = 0; i < 16; ++i) z[i] = 0.f;
  return z;
}

// ---- top-k phase A: partial ranks over a 2000-element j-slice ----
__global__ __launch_bounds__(256) void topk_partial(const float* __restrict__ sal,
                                                    int* __restrict__ partial) {
  const int b = blockIdx.z, jc = blockIdx.y;
  __shared__ float4 s4[JT / 4];
  const float4* src4 = reinterpret_cast<const float4*>(sal + (size_t)b * NTOK + jc * JT);
  for (int e = threadIdx.x; e < JT / 4; e += 256) s4[e] = src4[e];
  __syncthreads();
  const int i = blockIdx.x * 256 + threadIdx.x;
  if (i >= NTOK) return;
  const float si = sal[(size_t)b * NTOK + i];
  int rank = 0;
  const int jbase = jc * JT;
#pragma unroll 4
  for (int e = 0; e < JT / 4; ++e) {
    const float4 v = s4[e];
    const int j = jbase + e * 4;
    rank += (int)((v.x > si) || (v.x == si && j + 0 < i));
    rank += (int)((v.y > si) || (v.y == si && j + 1 < i));
    rank += (int)((v.z > si) || (v.z == si && j + 2 < i));
    rank += (int)((v.w > si) || (v.w == si && j + 3 < i));
  }
  partial[((size_t)jc * BATCH + b) * NTOK + i] = rank;
}

// ---- top-k phase B: sum partials, scatter rank<KCAP into sorted index list ----
__global__ __launch_bounds__(256) void topk_finalize(const int* __restrict__ partial,
                                                     int* __restrict__ sidx) {
  const int gid = blockIdx.x * 256 + threadIdx.x;
  if (gid >= BATCH * NTOK) return;
  const int b = gid / NTOK, i = gid - b * NTOK;
  int rank = 0;
#pragma unroll
  for (int jc = 0; jc < 4; ++jc) rank += partial[((size_t)jc * BATCH + b) * NTOK + i];
  if (rank < KCAP) sidx[b * KCAP + rank] = i;
}

// ---- weight prep: fp32 W[l][K][N] -> bf16 MFMA-fragment-major ----
// wf[l][g][sg][lane][e] = W[l][sg*8 + (lane>>5)*4 + e][g*32 + (lane&31)]
template <int KD, int N, int LKS, int LN32>
__device__ __forceinline__ void wprep_one(const float* __restrict__ src,
                                          ushort* __restrict__ dst, int slot) {
  const int lane = slot & 63;
  const int sg = (slot >> 6) & ((1 << LKS) - 1);
  const int g = (slot >> (6 + LKS)) & ((1 << LN32) - 1);
  const int l = slot >> (6 + LKS + LN32);
  const int n = g * 32 + (lane & 31);
  const int k = sg * 8 + (lane >> 5) * 4;
  const float* s = src + ((size_t)l * KD + k) * N + n;
  union { unsigned long long u; ushort us[4]; } o;
#pragma unroll
  for (int e = 0; e < 4; ++e) o.us[e] = f2bf(s[(size_t)e * N]);
  *reinterpret_cast<unsigned long long*>(dst + (size_t)slot * 4) = o.u;
}

__global__ __launch_bounds__(256) void wprep_kernel(
    const float* __restrict__ Wq, const float* __restrict__ Wk,
    const float* __restrict__ Wv, const float* __restrict__ Wo,
    const float* __restrict__ W1, const float* __restrict__ W2,
    ushort* __restrict__ wqt, ushort* __restrict__ wkt, ushort* __restrict__ wvt,
    ushort* __restrict__ wot, ushort* __restrict__ w1t, ushort* __restrict__ w2t) {
  const int z = blockIdx.z;
  const int slot = blockIdx.x * 256 + threadIdx.x;
  if (z < 4) {  // 256x256: N32=8, KS=32 -> 65536 slots
    if (slot >= 4 * 8 * 32 * 64) return;
    const float* src = z == 0 ? Wq : (z == 1 ? Wk : (z == 2 ? Wv : Wo));
    ushort* dst = z == 0 ? wqt : (z == 1 ? wkt : (z == 2 ? wvt : wot));
    wprep_one<256, 256, 5, 3>(src, dst, slot);
  } else if (z == 4) {  // 256x1024: N32=32, KS=32 -> 262144 slots
    if (slot >= 4 * 32 * 32 * 64) return;
    wprep_one<256, 1024, 5, 5>(W1, w1t, slot);
  } else {  // 1024x256: N32=8, KS=128 -> 262144 slots
    if (slot >= 4 * 8 * 128 * 64) return;
    wprep_one<1024, 256, 7, 3>(W2, w2t, slot);
  }
}

// ---- gather + LayerNorm1 (layer 0 only): wave per token, writes x (f32) and h ----
__global__ __launch_bounds__(256) void gather_ln_kernel(
    const float* __restrict__ feat, const int* __restrict__ sidx,
    const float* __restrict__ g, const float* __restrict__ bb,
    float* __restrict__ x, ushort* __restrict__ h, int klen) {
  const int w = threadIdx.x >> 6, lane = threadIdx.x & 63;
  const int m = blockIdx.x * 4 + w;
  const int b = m / klen, t = m - b * klen;
  const int tok = sidx[b * KCAP + t];
  const float4 v4 =
      reinterpret_cast<const float4*>(feat + ((size_t)b * NTOK + tok) * DM)[lane];
  reinterpret_cast<float4*>(x + ((size_t)b * KCAP + t) * DM)[lane] = v4;
  float s = v4.x + v4.y + v4.z + v4.w;
#pragma unroll
  for (int off = 1; off < 64; off <<= 1) s += __shfl_xor(s, off);
  const float mu = s * (1.0f / DM);
  const float4 dv = {v4.x - mu, v4.y - mu, v4.z - mu, v4.w - mu};
  float vs = dv.x * dv.x + dv.y * dv.y + dv.z * dv.z + dv.w * dv.w;
#pragma unroll
  for (int off = 1; off < 64; off <<= 1) vs += __shfl_xor(vs, off);
  const float rstd = rsqrtf(vs * (1.0f / DM) + 1e-5f);
  const float4 g4 = reinterpret_cast<const float4*>(g)[lane];
  const float4 b4 = reinterpret_cast<const float4*>(bb)[lane];
  union { unsigned long long u; ushort us[4]; } o;
  o.us[0] = f2bf(dv.x * rstd * g4.x + b4.x);
  o.us[1] = f2bf(dv.y * rstd * g4.y + b4.y);
  o.us[2] = f2bf(dv.z * rstd * g4.z + b4.z);
  o.us[3] = f2bf(dv.w * rstd * g4.w + b4.w);
  reinterpret_cast<unsigned long long*>(h + ((size_t)b * KCAP + t) * DM)[lane] = o.u;
}

// ---- LayerNorm: wave per token, x (f32) -> h (bf16). Used for LN1 (l>=1) and LN2 ----
__global__ __launch_bounds__(256) void ln_kernel(
    const float* __restrict__ x, const float* __restrict__ g,
    const float* __restrict__ bb, ushort* __restrict__ h, int klen) {
  const int w = threadIdx.x >> 6, lane = threadIdx.x & 63;
  const int m = blockIdx.x * 4 + w;
  const int b = m / klen, t = m - b * klen;
  const float4 v4 = reinterpret_cast<const float4*>(x + ((size_t)b * KCAP + t) * DM)[lane];
  float s = v4.x + v4.y + v4.z + v4.w;
#pragma unroll
  for (int off = 1; off < 64; off <<= 1) s += __shfl_xor(s, off);
  const float mu = s * (1.0f / DM);
  const float4 dv = {v4.x - mu, v4.y - mu, v4.z - mu, v4.w - mu};
  float vs = dv.x * dv.x + dv.y * dv.y + dv.z * dv.z + dv.w * dv.w;
#pragma unroll
  for (int off = 1; off < 64; off <<= 1) vs += __shfl_xor(vs, off);
  const float rstd = rsqrtf(vs * (1.0f / DM) + 1e-5f);
  const float4 g4 = reinterpret_cast<const float4*>(g)[lane];
  const float4 b4 = reinterpret_cast<const float4*>(bb)[lane];
  union { unsigned long long u; ushort us[4]; } o;
  o.us[0] = f2bf(dv.x * rstd * g4.x + b4.x);
  o.us[1] = f2bf(dv.y * rstd * g4.y + b4.y);
  o.us[2] = f2bf(dv.z * rstd * g4.z + b4.z);
  o.us[3] = f2bf(dv.w * rstd * g4.w + b4.w);
  reinterpret_cast<unsigned long long*>(h + ((size_t)b * KCAP + t) * DM)[lane] = o.u;
}

// ---- GEMM core: block = 32 rows x 256 cols, wave = 32x64 (2 acc tiles) ----
// A row-major [t][APITCH] bf16 staged to LDS (XOR-swizzled), B fragment-major.
template <int APITCH, int KCHUNKS>
__device__ __forceinline__ void gemm_core(
    const ushort* __restrict__ A, const ushort* __restrict__ wf,
    unsigned long long* lA, int b, int t0, int klen, f32x16& acc0, f32x16& acc1) {
  constexpr int KSTEPS = KCHUNKS * 32;
  const int tid = threadIdx.x;
  const int lane = tid & 63, l31 = lane & 31, hi = lane >> 5, w = tid >> 6;
  const int srow = tid >> 5, sl = tid & 31;
  acc0 = zero16();
  acc1 = zero16();
  const ushort* w0 = wf + ((size_t)(w * 2) * KSTEPS + 0) * 256 + lane * 4;
  const ushort* w1p = w0 + (size_t)KSTEPS * 256;
  for (int kc = 0; kc < KCHUNKS; ++kc) {
    if (kc) __syncthreads();
#pragma unroll
    for (int p = 0; p < 4; ++p) {
      const int row = p * 8 + srow;
      const size_t grow = (size_t)(b * KCAP + min(t0 + row, klen - 1));
      union { uint4 q; unsigned long long d[2]; } u;
      u.q = *reinterpret_cast<const uint4*>(A + grow * APITCH + kc * 256 + sl * 8);
      const int rx = row ^ (sl & 15);
      lA[(sl * 2) * 32 + rx] = u.d[0];
      lA[(sl * 2 + 1) * 32 + rx] = u.d[1];
    }
    __syncthreads();
    const ushort* wc0 = w0 + (size_t)kc * 32 * 256;
    const ushort* wc1 = w1p + (size_t)kc * 32 * 256;
#pragma unroll 8
    for (int s = 0; s < 32; ++s) {
      union { unsigned long long d; s16x4 v; } a;
      a.d = lA[(s * 2 + hi) * 32 + (l31 ^ (s & 15))];
      const s16x4 b0 = *reinterpret_cast<const s16x4*>(wc0 + s * 256);
      const s16x4 b1 = *reinterpret_cast<const s16x4*>(wc1 + s * 256);
      acc0 = MFMA_B(a.v, b0, acc0);
      acc1 = MFMA_B(a.v, b1, acc1);
    }
  }
}

// ---- fused Q/K/V projection (blockIdx.y selects q/k/v) ----
// Q pre-scaled by (1/sqrt(32))*log2(e) so attention works in log2 units.
__global__ __launch_bounds__(256) void qkv_kernel(
    const ushort* __restrict__ hb, const ushort* __restrict__ wq,
    const ushort* __restrict__ wk, const ushort* __restrict__ wv,
    ushort* __restrict__ qh, ushort* __restrict__ Kf, ushort* __restrict__ Vf,
    int klen) {
  __shared__ unsigned long long lA[2048];
  const int z = blockIdx.y;
  const ushort* wf = z == 0 ? wq : (z == 1 ? wk : wv);
  const int nrb = (klen + 31) >> 5;
  const int b = blockIdx.x / nrb;
  const int t0 = (blockIdx.x - b * nrb) * 32;
  f32x16 a0, a1;
  gemm_core<256, 1>(hb, wf, lA, b, t0, klen, a0, a1);
  const int lane = threadIdx.x & 63, l31 = lane & 31, hi = lane >> 5;
  const int w = threadIdx.x >> 6;
  const int hi4 = 4 * hi;
#pragma unroll
  for (int blk = 0; blk < 2; ++blk) {
    const f32x16& acc = blk ? a1 : a0;
    const int hh = w * 2 + blk;
    const int bh = b * 8 + hh;
    if (z == 0) {  // Q pre-scaled (log2 units), head layout [bh][t][32]
#pragma unroll
      for (int r = 0; r < 16; ++r) {
        const int gm = t0 + ((r & 3) + 8 * (r >> 2) + hi4);
        if (gm < klen)
          qh[((size_t)bh * KCAP + gm) * 32 + l31] =
              f2bf(acc[r] * (0.17677669529663687f * 1.4426950408889634f));
      }
    } else if (z == 1) {  // K fragment-major
#pragma unroll
      for (int r = 0; r < 16; ++r) {
        const int gm = t0 + ((r & 3) + 8 * (r >> 2) + hi4);
        const ushort val = gm < klen ? f2bf(acc[r]) : (ushort)0;
        const int kb = gm >> 5, k31 = gm & 31;
        const int dc = l31 >> 3, hi2 = (l31 >> 2) & 1, e = l31 & 3;
        Kf[(((size_t)bh * NB32 + kb) * 4 + dc) * 256 + (hi2 * 32 + k31) * 4 + e] = val;
      }
    } else {  // V fragment-major
#pragma unroll
      for (int r = 0; r < 16; ++r) {
        const int gm = t0 + ((r & 3) + 8 * (r >> 2) + hi4);
        const ushort val = gm < klen ? f2bf(acc[r]) : (ushort)0;
        const int kb = gm >> 5, k31 = gm & 31;
        const int kc = k31 >> 3, hi2 = (k31 >> 2) & 1, e = k31 & 3;
        Vf[(((size_t)bh * NB32 + kb) * 4 + kc) * 256 + (hi2 * 32 + l31) * 4 + e] = val;
      }
    }
  }
}

// ---- residual GEMM: xb += A @ W (used for Wo and W2, in-place accumulate) ----
template <int APITCH, int KCHUNKS>
__global__ __launch_bounds__(256) void resadd_kernel(const ushort* __restrict__ A,
                                                     const ushort* __restrict__ wf,
                                                     float* __restrict__ xb, int klen) {
  __shared__ unsigned long long lA[2048];
  const int nrb = (klen + 31) >> 5;
  const int b = blockIdx.x / nrb;
  const int t0 = (blockIdx.x - b * nrb) * 32;
  f32x16 a0, a1;
  gemm_core<APITCH, KCHUNKS>(A, wf, lA, b, t0, klen, a0, a1);
  const int lane = threadIdx.x & 63, l31 = lane & 31, hi = lane >> 5;
  const int w = threadIdx.x >> 6;
  const int hi4 = 4 * hi;
#pragma unroll
  for (int blk = 0; blk < 2; ++blk) {
    const f32x16& acc = blk ? a1 : a0;
    const int n = w * 64 + blk * 32 + l31;
#pragma unroll
    for (int r = 0; r < 16; ++r) {
      const int gm = t0 + ((r & 3) + 8 * (r >> 2) + hi4);
      if (gm < klen) {
        const size_t off = ((size_t)b * KCAP + gm) * DM + n;
        xb[off] += acc[r];
      }
    }
  }
}

// ---- W1 GEMM: fb = gelu(hb @ W1), blockIdx.y = 256-col group ----
__global__ __launch_bounds__(256) void w1_kernel(const ushort* __restrict__ hb,
                                                 const ushort* __restrict__ w1,
                                                 ushort* __restrict__ fb, int klen) {
  __shared__ unsigned long long lA[2048];
  const int nrb = (klen + 31) >> 5;
  const int b = blockIdx.x / nrb;
  const int t0 = (blockIdx.x - b * nrb) * 32;
  const ushort* wf = w1 + (size_t)blockIdx.y * 65536;
  f32x16 a0, a1;
  gemm_core<256, 1>(hb, wf, lA, b, t0, klen, a0, a1);
  const int lane = threadIdx.x & 63, l31 = lane & 31, hi = lane >> 5;
  const int w = threadIdx.x >> 6;
  const int hi4 = 4 * hi;
#pragma unroll
  for (int blk = 0; blk < 2; ++blk) {
    const f32x16& acc = blk ? a1 : a0;
    const int n = blockIdx.y * 256 + w * 64 + blk * 32 + l31;
#pragma unroll
    for (int r = 0; r < 16; ++r) {
      const int gm = t0 + ((r & 3) + 8 * (r >> 2) + hi4);
      if (gm < klen)
        fb[((size_t)b * KCAP + gm) * DFF + n] = f2bf(gelu_tanh(acc[r]));
    }
  }
}

// ---- flash attention: block = one 32-q tile, 4 waves split keys 4-way ----
// Fixed-base softmax: S accumulator init = -M0 (log2 units); p = 2^s directly.
#define M0 12.0f
__global__ __launch_bounds__(256) void attn_kernel(
    const ushort* __restrict__ Q, const ushort* __restrict__ Kf,
    const ushort* __restrict__ Vf, ushort* __restrict__ O, int klen) {
  const int hh = blockIdx.y, b = blockIdx.z;
  const int bh = b * 8 + hh;
  const int tid = threadIdx.x;
  const int w = tid >> 6, lane = tid & 63, l31 = lane & 31, hi = lane >> 5;
  __shared__ float red[3 * 64 * 17];  // waves 1-3 partials: o[16], l (stride 17)
  const int q0 = blockIdx.x * 32;
  const int qg = min(q0 + l31, klen - 1);
  const ushort* qrow = Q + ((size_t)bh * KCAP + qg) * 32;
  const s16x4 qf0 = *reinterpret_cast<const s16x4*>(qrow + 0 + hi * 4);
  const s16x4 qf1 = *reinterpret_cast<const s16x4*>(qrow + 8 + hi * 4);
  const s16x4 qf2 = *reinterpret_cast<const s16x4*>(qrow + 16 + hi * 4);
  const s16x4 qf3 = *reinterpret_cast<const s16x4*>(qrow + 24 + hi * 4);
  const ushort* kfp = Kf + (size_t)bh * NB32 * 1024 + lane * 4;
  const ushort* vfp = Vf + (size_t)bh * NB32 * 1024 + lane * 4;
  f32x16 oacc = zero16();
  float lrun = 0.f;
  const int nb = (klen + 31) >> 5;
  const int qq = nb >> 2, rr = nb & 3;
  const int kb0 = w * qq + min(w, rr);
  const int kbn = kb0 + qq + (w < rr ? 1 : 0);
  for (int kb = kb0; kb < kbn; ++kb) {
    const ushort* kb_ = kfp + (size_t)kb * 1024;
    const ushort* vb_ = vfp + (size_t)kb * 1024;
    const s16x4 kf0 = *reinterpret_cast<const s16x4*>(kb_ + 0);
    const s16x4 kf1 = *reinterpret_cast<const s16x4*>(kb_ + 256);
    const s16x4 kf2 = *reinterpret_cast<const s16x4*>(kb_ + 512);
    const s16x4 kf3 = *reinterpret_cast<const s16x4*>(kb_ + 768);
    const s16x4 vf0 = *reinterpret_cast<const s16x4*>(vb_ + 0);
    const s16x4 vf1 = *reinterpret_cast<const s16x4*>(vb_ + 256);
    const s16x4 vf2 = *reinterpret_cast<const s16x4*>(vb_ + 512);
    const s16x4 vf3 = *reinterpret_cast<const s16x4*>(vb_ + 768);
    f32x16 s;
#pragma unroll
    for (int r = 0; r < 16; ++r) s[r] = -M0;  // bias folded into accumulator
    s = MFMA_B(kf0, qf0, s);
    s = MFMA_B(kf1, qf1, s);
    s = MFMA_B(kf2, qf2, s);
    s = MFMA_B(kf3, qf3, s);
    if ((kb << 5) + 32 > klen) {  // mask tail keys (pad K zero-filled)
#pragma unroll
      for (int r = 0; r < 16; ++r) {
        const int key = (kb << 5) + (r & 3) + 8 * (r >> 2) + 4 * hi;
        if (key >= klen) s[r] = -1e30f;
      }
    }
    float p[16];
    float ps = 0.f;
#pragma unroll
    for (int r = 0; r < 16; ++r) {
      p[r] = fast_exp2(s[r]);  // p = 2^(S*log2e - M0): exact softmax ratio
      ps += p[r];
    }
    lrun += ps;
    unsigned pw[8];
#pragma unroll
    for (int i = 0; i < 8; ++i) pw[i] = cvt_pk_bf16(p[2 * i], p[2 * i + 1]);
#pragma unroll
    for (int kc = 0; kc < 4; ++kc) {
      union { unsigned u[2]; s16x4 v; } pf;
      pf.u[0] = pw[2 * kc];
      pf.u[1] = pw[2 * kc + 1];
      const s16x4 vf = kc == 0 ? vf0 : (kc == 1 ? vf1 : (kc == 2 ? vf2 : vf3));
      oacc = MFMA_B(vf, pf.v, oacc);  // O^T[d][q]
    }
  }
  // fixed base -> partials merge by plain summation
  if (w) {
    float* myr = red + ((w - 1) * 64 + lane) * 17;
#pragma unroll
    for (int r = 0; r < 16; ++r) myr[r] = oacc[r];
    myr[16] = lrun;
  }
  __syncthreads();
  if (w == 0) {
#pragma unroll
    for (int w2 = 0; w2 < 3; ++w2) {
      const float* pr = red + (w2 * 64 + lane) * 17;
#pragma unroll
      for (int r = 0; r < 16; ++r) oacc[r] += pr[r];
      lrun += pr[16];
    }
    const float ltot = lrun + __shfl_xor(lrun, 32);
    const float inv = 1.0f / ltot;
    if (q0 + l31 < klen) {
      ushort* orow = O + ((size_t)b * KCAP + q0 + l31) * DM + hh * 32;
#pragma unroll
      for (int rq = 0; rq < 4; ++rq) {
        union { unsigned u[2]; unsigned long long u64; } o4;
        o4.u[0] = cvt_pk_bf16(oacc[4 * rq] * inv, oacc[4 * rq + 1] * inv);
        o4.u[1] = cvt_pk_bf16(oacc[4 * rq + 2] * inv, oacc[4 * rq + 3] * inv);
        *reinterpret_cast<unsigned long long*>(orow + 8 * rq + 4 * hi) = o4.u64;
      }
    }
  }
}

// ---- final scatter: feature bank gets each rank's last-updated row ----
__global__ __launch_bounds__(256) void scatter_kernel(
    const float* __restrict__ x, const int* __restrict__ sidx,
    float* __restrict__ feat) {
  const int gid = blockIdx.x * 256 + threadIdx.x;
  const int m = gid >> 6, li = gid & 63;
  const int b = m / KCAP, t = m - b * KCAP;
  const int tok = sidx[b * KCAP + t];
  reinterpret_cast<float4*>(feat + ((size_t)b * NTOK + tok) * DM)[li] =
      reinterpret_cast<const float4*>(x + ((size_t)b * KCAP + t) * DM)[li];
}

extern "C" void kernel_launch(void* const* d_in, const int* in_sizes, int n_in,
                              void* d_out, int out_size, void* d_ws, size_t ws_size,
                              hipStream_t stream) {
  (void)in_sizes; (void)n_in; (void)out_size; (void)ws_size;
  const float* features = (const float*)d_in[0];
  const float* salience = (const float*)d_in[1];
  const float* Wq = (const float*)d_in[2];
  const float* Wk = (const float*)d_in[3];
  const float* Wv = (const float*)d_in[4];
  const float* Wo = (const float*)d_in[5];
  const float* W1 = (const float*)d_in[6];
  const float* W2 = (const float*)d_in[7];
  const float* ln1g = (const float*)d_in[8];
  const float* ln1b = (const float*)d_in[9];
  const float* ln2g = (const float*)d_in[10];
  const float* ln2b = (const float*)d_in[11];
  float* out = (float*)d_out;

  // workspace layout
  const size_t SLAB = (size_t)BATCH * KCAP * DM;
  char* p = (char*)d_ws;
  int* sidx = (int*)p;                 p += 32768;
  int* partial = (int*)p;              p += (size_t)4 * BATCH * NTOK * 4;
  float* xb = (float*)p;               p += SLAB * 4;   // persistent token rows (f32)
  ushort* hb = (ushort*)p;             p += SLAB * 2;
  ushort* qh = (ushort*)p;             p += SLAB * 2;
  ushort* Kf = (ushort*)p;             p += SLAB * 2;
  ushort* Vf = (ushort*)p;             p += SLAB * 2;
  ushort* ob = (ushort*)p;             p += SLAB * 2;
  ushort* fb = qh;  // FFN intermediate (13.1MB) overlays qh|Kf|Vf|ob
  ushort* wqt = (ushort*)p;            p += (size_t)4 * 256 * 256 * 2;
  ushort* wkt = (ushort*)p;            p += (size_t)4 * 256 * 256 * 2;
  ushort* wvt = (ushort*)p;            p += (size_t)4 * 256 * 256 * 2;
  ushort* wot = (ushort*)p;            p += (size_t)4 * 256 * 256 * 2;
  ushort* w1t = (ushort*)p;            p += (size_t)4 * 256 * 1024 * 2;
  ushort* w2t = (ushort*)p;            p += (size_t)4 * 1024 * 256 * 2;

  hipMemcpyAsync(out, features, (size_t)BATCH * NTOK * DM * sizeof(float),
                 hipMemcpyDeviceToDevice, stream);
  topk_partial<<<dim3((NTOK + 255) / 256, 4, BATCH), 256, 0, stream>>>(salience,
                                                                       partial);
  topk_finalize<<<(BATCH * NTOK + 255) / 256, 256, 0, stream>>>(partial, sidx);
  wprep_kernel<<<dim3(1024, 1, 6), 256, 0, stream>>>(Wq, Wk, Wv, Wo, W1, W2, wqt,
                                                     wkt, wvt, wot, w1t, w2t);

  const int klens[4] = {3200, 2400, 2000, 1600};
  for (int l = 0; l < 4; ++l) {
    const int klen = klens[l];
    const int nrb = (klen + 31) >> 5;  // 32-row tiles
    const size_t wsq = (size_t)l * 256 * 256;
    const size_t wff = (size_t)l * 256 * 1024;
    if (l == 0) {
      gather_ln_kernel<<<klen / 2, 256, 0, stream>>>(out, sidx, ln1g, ln1b, xb, hb,
                                                     klen);
    } else {
      // nested-prefix top-k: rows of xb persist across layers, no re-gather
      ln_kernel<<<klen / 2, 256, 0, stream>>>(xb, ln1g + l * DM, ln1b + l * DM, hb,
                                              klen);
    }
    qkv_kernel<<<dim3(2 * nrb, 3), 256, 0, stream>>>(
        hb, wqt + wsq, wkt + wsq, wvt + wsq, qh, Kf, Vf, klen);
    attn_kernel<<<dim3(nrb, 8, BATCH), 256, 0, stream>>>(qh, Kf, Vf, ob, klen);
    resadd_kernel<256, 1><<<dim3(2 * nrb, 1), 256, 0, stream>>>(ob, wot + wsq, xb,
                                                                klen);
    ln_kernel<<<klen / 2, 256, 0, stream>>>(xb, ln2g + l * DM, ln2b + l * DM, hb,
                                            klen);
    w1_kernel<<<dim3(2 * nrb, 4), 256, 0, stream>>>(hb, w1t + wff, fb, klen);
    resadd_kernel<1024, 4><<<dim3(2 * nrb, 1), 256, 0, stream>>>(fb, w2t + wff, xb,
                                                                 klen);
  }
  scatter_kernel<<<BATCH * KCAP / 4, 256, 0, stream>>>(xb, sidx, out);
}

// Round 9
// 442.826 us; speedup vs baseline: 11.3018x; 1.0959x over previous
//
#include <hip/hip_runtime.h>
#include <math.h>

#define NTOK 8000
#define KCAP 3200
#define BATCH 2
#define DM 256
#define DFF 1024
#define NSL 16            // top-k j-slices
#define JT (NTOK / NSL)   // 500 elements per slice
#define NB32 (KCAP / 32)  // fragment blocks per (batch,head)

typedef __attribute__((ext_vector_type(4))) short s16x4;
typedef __attribute__((ext_vector_type(16))) float f32x16;

#define MFMA_B(a, b, c) __builtin_amdgcn_mfma_f32_32x32x8bf16_1k(a, b, c, 0, 0, 0)

__device__ __forceinline__ ushort f2bf(float f) {  // RNE float->bf16 bits
  unsigned u = __float_as_uint(f);
  u += 0x7fffu + ((u >> 16) & 1u);
  return (ushort)(u >> 16);
}
__device__ __forceinline__ unsigned cvt_pk_bf16(float lo, float hi) {
  unsigned r;
  asm("v_cvt_pk_bf16_f32 %0, %1, %2" : "=v"(r) : "v"(lo), "v"(hi));
  return r;
}
__device__ __forceinline__ float fast_exp2(float x) {  // 2^x, raw v_exp
  float r;
  asm("v_exp_f32 %0, %1" : "=v"(r) : "v"(x));
  return r;
}
__device__ __forceinline__ float gelu_tanh(float x) {
  const float z = 0.7978845608028654f * (x + 0.044715f * x * x * x);
  return x * (1.0f / (1.0f + __expf(-2.0f * z)));  // == 0.5x(1+tanh(z))
}
__device__ __forceinline__ f32x16 zero16() {
  f32x16 z;
#pragma unroll
  for (int i = 0; i < 16; ++i) z[i] = 0.f;
  return z;
}

// ---- top-k phase A: partial ranks over a 500-element j-slice (16-way split) ----
__global__ __launch_bounds__(256) void topk_partial(const float* __restrict__ sal,
                                                    int* __restrict__ partial) {
  const int b = blockIdx.z, jc = blockIdx.y;
  __shared__ float4 s4[JT / 4];
  const float4* src4 = reinterpret_cast<const float4*>(sal + (size_t)b * NTOK + jc * JT);
  for (int e = threadIdx.x; e < JT / 4; e += 256) s4[e] = src4[e];
  __syncthreads();
  const int i = blockIdx.x * 256 + threadIdx.x;
  if (i >= NTOK) return;
  const float si = sal[(size_t)b * NTOK + i];
  int rank = 0;
  const int jbase = jc * JT;
#pragma unroll 5
  for (int e = 0; e < JT / 4; ++e) {
    const float4 v = s4[e];
    const int j = jbase + e * 4;
    rank += (int)((v.x > si) || (v.x == si && j + 0 < i));
    rank += (int)((v.y > si) || (v.y == si && j + 1 < i));
    rank += (int)((v.z > si) || (v.z == si && j + 2 < i));
    rank += (int)((v.w > si) || (v.w == si && j + 3 < i));
  }
  partial[((size_t)jc * BATCH + b) * NTOK + i] = rank;
}

// ---- top-k phase B: sum partials, scatter rank<KCAP into sorted index list ----
__global__ __launch_bounds__(256) void topk_finalize(const int* __restrict__ partial,
                                                     int* __restrict__ sidx) {
  const int gid = blockIdx.x * 256 + threadIdx.x;
  if (gid >= BATCH * NTOK) return;
  const int b = gid / NTOK, i = gid - b * NTOK;
  int rank = 0;
#pragma unroll
  for (int jc = 0; jc < NSL; ++jc)
    rank += partial[((size_t)jc * BATCH + b) * NTOK + i];
  if (rank < KCAP) sidx[b * KCAP + rank] = i;
}

// ---- weight prep: fp32 W[l][K][N] -> bf16 MFMA-fragment-major ----
// wf[l][g][sg][lane][e] = W[l][sg*8 + (lane>>5)*4 + e][g*32 + (lane&31)]
template <int KD, int N, int LKS, int LN32>
__device__ __forceinline__ void wprep_one(const float* __restrict__ src,
                                          ushort* __restrict__ dst, int slot) {
  const int lane = slot & 63;
  const int sg = (slot >> 6) & ((1 << LKS) - 1);
  const int g = (slot >> (6 + LKS)) & ((1 << LN32) - 1);
  const int l = slot >> (6 + LKS + LN32);
  const int n = g * 32 + (lane & 31);
  const int k = sg * 8 + (lane >> 5) * 4;
  const float* s = src + ((size_t)l * KD + k) * N + n;
  union { unsigned long long u; ushort us[4]; } o;
#pragma unroll
  for (int e = 0; e < 4; ++e) o.us[e] = f2bf(s[(size_t)e * N]);
  *reinterpret_cast<unsigned long long*>(dst + (size_t)slot * 4) = o.u;
}

__global__ __launch_bounds__(256) void wprep_kernel(
    const float* __restrict__ Wq, const float* __restrict__ Wk,
    const float* __restrict__ Wv, const float* __restrict__ Wo,
    const float* __restrict__ W1, const float* __restrict__ W2,
    ushort* __restrict__ wqt, ushort* __restrict__ wkt, ushort* __restrict__ wvt,
    ushort* __restrict__ wot, ushort* __restrict__ w1t, ushort* __restrict__ w2t) {
  const int z = blockIdx.z;
  const int slot = blockIdx.x * 256 + threadIdx.x;
  if (z < 4) {  // 256x256: N32=8, KS=32 -> 65536 slots
    if (slot >= 4 * 8 * 32 * 64) return;
    const float* src = z == 0 ? Wq : (z == 1 ? Wk : (z == 2 ? Wv : Wo));
    ushort* dst = z == 0 ? wqt : (z == 1 ? wkt : (z == 2 ? wvt : wot));
    wprep_one<256, 256, 5, 3>(src, dst, slot);
  } else if (z == 4) {  // 256x1024: N32=32, KS=32 -> 262144 slots
    if (slot >= 4 * 32 * 32 * 64) return;
    wprep_one<256, 1024, 5, 5>(W1, w1t, slot);
  } else {  // 1024x256: N32=8, KS=128 -> 262144 slots
    if (slot >= 4 * 8 * 128 * 64) return;
    wprep_one<1024, 256, 7, 3>(W2, w2t, slot);
  }
}

// ---- gather + LayerNorm1 (layer 0 only): wave per token, writes x (f32) and h ----
__global__ __launch_bounds__(256) void gather_ln_kernel(
    const float* __restrict__ feat, const int* __restrict__ sidx,
    const float* __restrict__ g, const float* __restrict__ bb,
    float* __restrict__ x, ushort* __restrict__ h, int klen) {
  const int w = threadIdx.x >> 6, lane = threadIdx.x & 63;
  const int m = blockIdx.x * 4 + w;
  const int b = m / klen, t = m - b * klen;
  const int tok = sidx[b * KCAP + t];
  const float4 v4 =
      reinterpret_cast<const float4*>(feat + ((size_t)b * NTOK + tok) * DM)[lane];
  reinterpret_cast<float4*>(x + ((size_t)b * KCAP + t) * DM)[lane] = v4;
  float s = v4.x + v4.y + v4.z + v4.w;
#pragma unroll
  for (int off = 1; off < 64; off <<= 1) s += __shfl_xor(s, off);
  const float mu = s * (1.0f / DM);
  const float4 dv = {v4.x - mu, v4.y - mu, v4.z - mu, v4.w - mu};
  float vs = dv.x * dv.x + dv.y * dv.y + dv.z * dv.z + dv.w * dv.w;
#pragma unroll
  for (int off = 1; off < 64; off <<= 1) vs += __shfl_xor(vs, off);
  const float rstd = rsqrtf(vs * (1.0f / DM) + 1e-5f);
  const float4 g4 = reinterpret_cast<const float4*>(g)[lane];
  const float4 b4 = reinterpret_cast<const float4*>(bb)[lane];
  union { unsigned long long u; ushort us[4]; } o;
  o.us[0] = f2bf(dv.x * rstd * g4.x + b4.x);
  o.us[1] = f2bf(dv.y * rstd * g4.y + b4.y);
  o.us[2] = f2bf(dv.z * rstd * g4.z + b4.z);
  o.us[3] = f2bf(dv.w * rstd * g4.w + b4.w);
  reinterpret_cast<unsigned long long*>(h + ((size_t)b * KCAP + t) * DM)[lane] = o.u;
}

// ---- LayerNorm: wave per token, x (f32) -> h (bf16). Used for LN1 (l>=1) and LN2 ----
__global__ __launch_bounds__(256) void ln_kernel(
    const float* __restrict__ x, const float* __restrict__ g,
    const float* __restrict__ bb, ushort* __restrict__ h, int klen) {
  const int w = threadIdx.x >> 6, lane = threadIdx.x & 63;
  const int m = blockIdx.x * 4 + w;
  const int b = m / klen, t = m - b * klen;
  const float4 v4 = reinterpret_cast<const float4*>(x + ((size_t)b * KCAP + t) * DM)[lane];
  float s = v4.x + v4.y + v4.z + v4.w;
#pragma unroll
  for (int off = 1; off < 64; off <<= 1) s += __shfl_xor(s, off);
  const float mu = s * (1.0f / DM);
  const float4 dv = {v4.x - mu, v4.y - mu, v4.z - mu, v4.w - mu};
  float vs = dv.x * dv.x + dv.y * dv.y + dv.z * dv.z + dv.w * dv.w;
#pragma unroll
  for (int off = 1; off < 64; off <<= 1) vs += __shfl_xor(vs, off);
  const float rstd = rsqrtf(vs * (1.0f / DM) + 1e-5f);
  const float4 g4 = reinterpret_cast<const float4*>(g)[lane];
  const float4 b4 = reinterpret_cast<const float4*>(bb)[lane];
  union { unsigned long long u; ushort us[4]; } o;
  o.us[0] = f2bf(dv.x * rstd * g4.x + b4.x);
  o.us[1] = f2bf(dv.y * rstd * g4.y + b4.y);
  o.us[2] = f2bf(dv.z * rstd * g4.z + b4.z);
  o.us[3] = f2bf(dv.w * rstd * g4.w + b4.w);
  reinterpret_cast<unsigned long long*>(h + ((size_t)b * KCAP + t) * DM)[lane] = o.u;
}

// ---- GEMM core: block = 32 rows x 256 cols, wave = 32x64 (2 acc tiles) ----
// A row-major [t][APITCH] bf16 staged to LDS (XOR-swizzled), B fragment-major.
template <int APITCH, int KCHUNKS>
__device__ __forceinline__ void gemm_core(
    const ushort* __restrict__ A, const ushort* __restrict__ wf,
    unsigned long long* lA, int b, int t0, int klen, f32x16& acc0, f32x16& acc1) {
  constexpr int KSTEPS = KCHUNKS * 32;
  const int tid = threadIdx.x;
  const int lane = tid & 63, l31 = lane & 31, hi = lane >> 5, w = tid >> 6;
  const int srow = tid >> 5, sl = tid & 31;
  acc0 = zero16();
  acc1 = zero16();
  const ushort* w0 = wf + ((size_t)(w * 2) * KSTEPS + 0) * 256 + lane * 4;
  const ushort* w1p = w0 + (size_t)KSTEPS * 256;
  for (int kc = 0; kc < KCHUNKS; ++kc) {
    if (kc) __syncthreads();
#pragma unroll
    for (int p = 0; p < 4; ++p) {
      const int row = p * 8 + srow;
      const size_t grow = (size_t)(b * KCAP + min(t0 + row, klen - 1));
      union { uint4 q; unsigned long long d[2]; } u;
      u.q = *reinterpret_cast<const uint4*>(A + grow * APITCH + kc * 256 + sl * 8);
      const int rx = row ^ (sl & 15);
      lA[(sl * 2) * 32 + rx] = u.d[0];
      lA[(sl * 2 + 1) * 32 + rx] = u.d[1];
    }
    __syncthreads();
    const ushort* wc0 = w0 + (size_t)kc * 32 * 256;
    const ushort* wc1 = w1p + (size_t)kc * 32 * 256;
#pragma unroll 8
    for (int s = 0; s < 32; ++s) {
      union { unsigned long long d; s16x4 v; } a;
      a.d = lA[(s * 2 + hi) * 32 + (l31 ^ (s & 15))];
      const s16x4 b0 = *reinterpret_cast<const s16x4*>(wc0 + s * 256);
      const s16x4 b1 = *reinterpret_cast<const s16x4*>(wc1 + s * 256);
      acc0 = MFMA_B(a.v, b0, acc0);
      acc1 = MFMA_B(a.v, b1, acc1);
    }
  }
}

// ---- fused Q/K/V projection (blockIdx.y selects q/k/v) ----
// Q pre-scaled by (1/sqrt(32))*log2(e) so attention works in log2 units.
__global__ __launch_bounds__(256) void qkv_kernel(
    const ushort* __restrict__ hb, const ushort* __restrict__ wq,
    const ushort* __restrict__ wk, const ushort* __restrict__ wv,
    ushort* __restrict__ qh, ushort* __restrict__ Kf, ushort* __restrict__ Vf,
    int klen) {
  __shared__ unsigned long long lA[2048];
  const int z = blockIdx.y;
  const ushort* wf = z == 0 ? wq : (z == 1 ? wk : wv);
  const int nrb = (klen + 31) >> 5;
  const int b = blockIdx.x / nrb;
  const int t0 = (blockIdx.x - b * nrb) * 32;
  f32x16 a0, a1;
  gemm_core<256, 1>(hb, wf, lA, b, t0, klen, a0, a1);
  const int lane = threadIdx.x & 63, l31 = lane & 31, hi = lane >> 5;
  const int w = threadIdx.x >> 6;
  const int hi4 = 4 * hi;
#pragma unroll
  for (int blk = 0; blk < 2; ++blk) {
    const f32x16& acc = blk ? a1 : a0;
    const int hh = w * 2 + blk;
    const int bh = b * 8 + hh;
    if (z == 0) {  // Q pre-scaled (log2 units), head layout [bh][t][32]
#pragma unroll
      for (int r = 0; r < 16; ++r) {
        const int gm = t0 + ((r & 3) + 8 * (r >> 2) + hi4);
        if (gm < klen)
          qh[((size_t)bh * KCAP + gm) * 32 + l31] =
              f2bf(acc[r] * (0.17677669529663687f * 1.4426950408889634f));
      }
    } else if (z == 1) {  // K fragment-major
#pragma unroll
      for (int r = 0; r < 16; ++r) {
        const int gm = t0 + ((r & 3) + 8 * (r >> 2) + hi4);
        const int kb = gm >> 5, k31 = gm & 31;
        const int dc = l31 >> 3, hi2 = (l31 >> 2) & 1, e = l31 & 3;
        Kf[(((size_t)bh * NB32 + kb) * 4 + dc) * 256 + (hi2 * 32 + k31) * 4 + e] =
            f2bf(acc[r]);
      }
    } else {  // V fragment-major
#pragma unroll
      for (int r = 0; r < 16; ++r) {
        const int gm = t0 + ((r & 3) + 8 * (r >> 2) + hi4);
        const int kb = gm >> 5, k31 = gm & 31;
        const int kc = k31 >> 3, hi2 = (k31 >> 2) & 1, e = k31 & 3;
        Vf[(((size_t)bh * NB32 + kb) * 4 + kc) * 256 + (hi2 * 32 + l31) * 4 + e] =
            f2bf(acc[r]);
      }
    }
  }
}

// ---- residual GEMM: xb += A @ W (used for Wo and W2, in-place accumulate) ----
template <int APITCH, int KCHUNKS>
__global__ __launch_bounds__(256) void resadd_kernel(const ushort* __restrict__ A,
                                                     const ushort* __restrict__ wf,
                                                     float* __restrict__ xb, int klen) {
  __shared__ unsigned long long lA[2048];
  const int nrb = (klen + 31) >> 5;
  const int b = blockIdx.x / nrb;
  const int t0 = (blockIdx.x - b * nrb) * 32;
  f32x16 a0, a1;
  gemm_core<APITCH, KCHUNKS>(A, wf, lA, b, t0, klen, a0, a1);
  const int lane = threadIdx.x & 63, l31 = lane & 31, hi = lane >> 5;
  const int w = threadIdx.x >> 6;
  const int hi4 = 4 * hi;
#pragma unroll
  for (int blk = 0; blk < 2; ++blk) {
    const f32x16& acc = blk ? a1 : a0;
    const int n = w * 64 + blk * 32 + l31;
#pragma unroll
    for (int r = 0; r < 16; ++r) {
      const int gm = t0 + ((r & 3) + 8 * (r >> 2) + hi4);
      if (gm < klen) {
        const size_t off = ((size_t)b * KCAP + gm) * DM + n;
        xb[off] += acc[r];
      }
    }
  }
}

// ---- W1 GEMM: fb = gelu(hb @ W1), blockIdx.y = 256-col group ----
__global__ __launch_bounds__(256) void w1_kernel(const ushort* __restrict__ hb,
                                                 const ushort* __restrict__ w1,
                                                 ushort* __restrict__ fb, int klen) {
  __shared__ unsigned long long lA[2048];
  const int nrb = (klen + 31) >> 5;
  const int b = blockIdx.x / nrb;
  const int t0 = (blockIdx.x - b * nrb) * 32;
  const ushort* wf = w1 + (size_t)blockIdx.y * 65536;
  f32x16 a0, a1;
  gemm_core<256, 1>(hb, wf, lA, b, t0, klen, a0, a1);
  const int lane = threadIdx.x & 63, l31 = lane & 31, hi = lane >> 5;
  const int w = threadIdx.x >> 6;
  const int hi4 = 4 * hi;
#pragma unroll
  for (int blk = 0; blk < 2; ++blk) {
    const f32x16& acc = blk ? a1 : a0;
    const int n = blockIdx.y * 256 + w * 64 + blk * 32 + l31;
#pragma unroll
    for (int r = 0; r < 16; ++r) {
      const int gm = t0 + ((r & 3) + 8 * (r >> 2) + hi4);
      if (gm < klen)
        fb[((size_t)b * KCAP + gm) * DFF + n] = f2bf(gelu_tanh(acc[r]));
    }
  }
}

// ---- flash attention: block = one 32-q tile, 4 waves split keys 4-way ----
// Fixed-base softmax: S accumulator init = -M0 (log2 units); p = 2^s directly.
#define M0 12.0f
__global__ __launch_bounds__(256) void attn_kernel(
    const ushort* __restrict__ Q, const ushort* __restrict__ Kf,
    const ushort* __restrict__ Vf, ushort* __restrict__ O, int klen) {
  const int hh = blockIdx.y, b = blockIdx.z;
  const int bh = b * 8 + hh;
  const int tid = threadIdx.x;
  const int w = tid >> 6, lane = tid & 63, l31 = lane & 31, hi = lane >> 5;
  __shared__ float red[3 * 64 * 17];  // waves 1-3 partials: o[16], l (stride 17)
  const int q0 = blockIdx.x * 32;
  const int qg = min(q0 + l31, klen - 1);
  const ushort* qrow = Q + ((size_t)bh * KCAP + qg) * 32;
  const s16x4 qf0 = *reinterpret_cast<const s16x4*>(qrow + 0 + hi * 4);
  const s16x4 qf1 = *reinterpret_cast<const s16x4*>(qrow + 8 + hi * 4);
  const s16x4 qf2 = *reinterpret_cast<const s16x4*>(qrow + 16 + hi * 4);
  const s16x4 qf3 = *reinterpret_cast<const s16x4*>(qrow + 24 + hi * 4);
  const ushort* kfp = Kf + (size_t)bh * NB32 * 1024 + lane * 4;
  const ushort* vfp = Vf + (size_t)bh * NB32 * 1024 + lane * 4;
  f32x16 oacc = zero16();
  float lrun = 0.f;
  const int nb = (klen + 31) >> 5;
  const int qq = nb >> 2, rr = nb & 3;
  const int kb0 = w * qq + min(w, rr);
  const int kbn = kb0 + qq + (w < rr ? 1 : 0);
  for (int kb = kb0; kb < kbn; ++kb) {
    const ushort* kb_ = kfp + (size_t)kb * 1024;
    const ushort* vb_ = vfp + (size_t)kb * 1024;
    const s16x4 kf0 = *reinterpret_cast<const s16x4*>(kb_ + 0);
    const s16x4 kf1 = *reinterpret_cast<const s16x4*>(kb_ + 256);
    const s16x4 kf2 = *reinterpret_cast<const s16x4*>(kb_ + 512);
    const s16x4 kf3 = *reinterpret_cast<const s16x4*>(kb_ + 768);
    const s16x4 vf0 = *reinterpret_cast<const s16x4*>(vb_ + 0);
    const s16x4 vf1 = *reinterpret_cast<const s16x4*>(vb_ + 256);
    const s16x4 vf2 = *reinterpret_cast<const s16x4*>(vb_ + 512);
    const s16x4 vf3 = *reinterpret_cast<const s16x4*>(vb_ + 768);
    f32x16 s;
#pragma unroll
    for (int r = 0; r < 16; ++r) s[r] = -M0;  // bias folded into accumulator
    s = MFMA_B(kf0, qf0, s);
    s = MFMA_B(kf1, qf1, s);
    s = MFMA_B(kf2, qf2, s);
    s = MFMA_B(kf3, qf3, s);
    if ((kb << 5) + 32 > klen) {  // mask tail keys (pad K zero-filled)
#pragma unroll
      for (int r = 0; r < 16; ++r) {
        const int key = (kb << 5) + (r & 3) + 8 * (r >> 2) + 4 * hi;
        if (key >= klen) s[r] = -1e30f;
      }
    }
    float p[16];
    float ps = 0.f;
#pragma unroll
    for (int r = 0; r < 16; ++r) {
      p[r] = fast_exp2(s[r]);  // p = 2^(S*log2e - M0): exact softmax ratio
      ps += p[r];
    }
    lrun += ps;
    unsigned pw[8];
#pragma unroll
    for (int i = 0; i < 8; ++i) pw[i] = cvt_pk_bf16(p[2 * i], p[2 * i + 1]);
#pragma unroll
    for (int kc = 0; kc < 4; ++kc) {
      union { unsigned u[2]; s16x4 v; } pf;
      pf.u[0] = pw[2 * kc];
      pf.u[1] = pw[2 * kc + 1];
      const s16x4 vf = kc == 0 ? vf0 : (kc == 1 ? vf1 : (kc == 2 ? vf2 : vf3));
      oacc = MFMA_B(vf, pf.v, oacc);  // O^T[d][q]
    }
  }
  // fixed base -> partials merge by plain summation
  if (w) {
    float* myr = red + ((w - 1) * 64 + lane) * 17;
#pragma unroll
    for (int r = 0; r < 16; ++r) myr[r] = oacc[r];
    myr[16] = lrun;
  }
  __syncthreads();
  if (w == 0) {
#pragma unroll
    for (int w2 = 0; w2 < 3; ++w2) {
      const float* pr = red + (w2 * 64 + lane) * 17;
#pragma unroll
      for (int r = 0; r < 16; ++r) oacc[r] += pr[r];
      lrun += pr[16];
    }
    const float ltot = lrun + __shfl_xor(lrun, 32);
    const float inv = 1.0f / ltot;
    if (q0 + l31 < klen) {
      ushort* orow = O + ((size_t)b * KCAP + q0 + l31) * DM + hh * 32;
#pragma unroll
      for (int rq = 0; rq < 4; ++rq) {
        union { unsigned u[2]; unsigned long long u64; } o4;
        o4.u[0] = cvt_pk_bf16(oacc[4 * rq] * inv, oacc[4 * rq + 1] * inv);
        o4.u[1] = cvt_pk_bf16(oacc[4 * rq + 2] * inv, oacc[4 * rq + 3] * inv);
        *reinterpret_cast<unsigned long long*>(orow + 8 * rq + 4 * hi) = o4.u64;
      }
    }
  }
}

// ---- final scatter: feature bank gets each rank's last-updated row ----
__global__ __launch_bounds__(256) void scatter_kernel(
    const float* __restrict__ x, const int* __restrict__ sidx,
    float* __restrict__ feat) {
  const int gid = blockIdx.x * 256 + threadIdx.x;
  const int m = gid >> 6, li = gid & 63;
  const int b = m / KCAP, t = m - b * KCAP;
  const int tok = sidx[b * KCAP + t];
  reinterpret_cast<float4*>(feat + ((size_t)b * NTOK + tok) * DM)[li] =
      reinterpret_cast<const float4*>(x + ((size_t)b * KCAP + t) * DM)[li];
}

extern "C" void kernel_launch(void* const* d_in, const int* in_sizes, int n_in,
                              void* d_out, int out_size, void* d_ws, size_t ws_size,
                              hipStream_t stream) {
  (void)in_sizes; (void)n_in; (void)out_size; (void)ws_size;
  const float* features = (const float*)d_in[0];
  const float* salience = (const float*)d_in[1];
  const float* Wq = (const float*)d_in[2];
  const float* Wk = (const float*)d_in[3];
  const float* Wv = (const float*)d_in[4];
  const float* Wo = (const float*)d_in[5];
  const float* W1 = (const float*)d_in[6];
  const float* W2 = (const float*)d_in[7];
  const float* ln1g = (const float*)d_in[8];
  const float* ln1b = (const float*)d_in[9];
  const float* ln2g = (const float*)d_in[10];
  const float* ln2b = (const float*)d_in[11];
  float* out = (float*)d_out;

  // workspace layout
  const size_t SLAB = (size_t)BATCH * KCAP * DM;
  char* p = (char*)d_ws;
  int* sidx = (int*)p;                 p += 32768;
  int* partial = (int*)p;              p += (size_t)NSL * BATCH * NTOK * 4;
  float* xb = (float*)p;               p += SLAB * 4;   // persistent token rows (f32)
  ushort* hb = (ushort*)p;             p += SLAB * 2;
  ushort* qh = (ushort*)p;             p += SLAB * 2;
  ushort* Kf = (ushort*)p;             p += SLAB * 2;
  ushort* Vf = (ushort*)p;             p += SLAB * 2;
  ushort* ob = (ushort*)p;             p += SLAB * 2;
  ushort* fb = qh;  // FFN intermediate (13.1MB) overlays qh|Kf|Vf|ob
  ushort* wqt = (ushort*)p;            p += (size_t)4 * 256 * 256 * 2;
  ushort* wkt = (ushort*)p;            p += (size_t)4 * 256 * 256 * 2;
  ushort* wvt = (ushort*)p;            p += (size_t)4 * 256 * 256 * 2;
  ushort* wot = (ushort*)p;            p += (size_t)4 * 256 * 256 * 2;
  ushort* w1t = (ushort*)p;            p += (size_t)4 * 256 * 1024 * 2;
  ushort* w2t = (ushort*)p;            p += (size_t)4 * 1024 * 256 * 2;

  hipMemcpyAsync(out, features, (size_t)BATCH * NTOK * DM * sizeof(float),
                 hipMemcpyDeviceToDevice, stream);
  topk_partial<<<dim3((NTOK + 255) / 256, NSL, BATCH), 256, 0, stream>>>(salience,
                                                                         partial);
  topk_finalize<<<(BATCH * NTOK + 255) / 256, 256, 0, stream>>>(partial, sidx);
  wprep_kernel<<<dim3(1024, 1, 6), 256, 0, stream>>>(Wq, Wk, Wv, Wo, W1, W2, wqt,
                                                     wkt, wvt, wot, w1t, w2t);

  const int klens[4] = {3200, 2400, 2000, 1600};
  for (int l = 0; l < 4; ++l) {
    const int klen = klens[l];
    const int nrb = (klen + 31) >> 5;  // 32-row tiles
    const size_t wsq = (size_t)l * 256 * 256;
    const size_t wff = (size_t)l * 256 * 1024;
    if (l == 0) {
      gather_ln_kernel<<<klen / 2, 256, 0, stream>>>(out, sidx, ln1g, ln1b, xb, hb,
                                                     klen);
    } else {
      // nested-prefix top-k: rows of xb persist across layers, no re-gather
      ln_kernel<<<klen / 2, 256, 0, stream>>>(xb, ln1g + l * DM, ln1b + l * DM, hb,
                                              klen);
    }
    qkv_kernel<<<dim3(2 * nrb, 3), 256, 0, stream>>>(
        hb, wqt + wsq, wkt + wsq, wvt + wsq, qh, Kf, Vf, klen);
    attn_kernel<<<dim3(nrb, 8, BATCH), 256, 0, stream>>>(qh, Kf, Vf, ob, klen);
    resadd_kernel<256, 1><<<dim3(2 * nrb, 1), 256, 0, stream>>>(ob, wot + wsq, xb,
                                                                klen);
    ln_kernel<<<klen / 2, 256, 0, stream>>>(xb, ln2g + l * DM, ln2b + l * DM, hb,
                                            klen);
    w1_kernel<<<dim3(2 * nrb, 4), 256, 0, stream>>>(hb, w1t + wff, fb, klen);
    resadd_kernel<1024, 4><<<dim3(2 * nrb, 1), 256, 0, stream>>>(fb, w2t + wff, xb,
                                                                 klen);
  }
  scatter_kernel<<<BATCH * KCAP / 4, 256, 0, stream>>>(xb, sidx, out);
}

// Round 10
// 424.632 us; speedup vs baseline: 11.7860x; 1.0428x over previous
//
#include <hip/hip_runtime.h>
#include <math.h>

#define NTOK 8000
#define KCAP 3200
#define BATCH 2
#define DM 256
#define DFF 1024
#define NSL 16            // top-k j-slices
#define JT (NTOK / NSL)   // 500 elements per slice
#define NB32 (KCAP / 32)  // fragment blocks per (batch,head)

typedef __attribute__((ext_vector_type(4))) short s16x4;
typedef __attribute__((ext_vector_type(8))) short s16x8;
typedef __attribute__((ext_vector_type(16))) float f32x16;

#define MFMA_B(a, b, c) __builtin_amdgcn_mfma_f32_32x32x8bf16_1k(a, b, c, 0, 0, 0)
#define MFMA16(a, b, c) __builtin_amdgcn_mfma_f32_32x32x16_bf16(a, b, c, 0, 0, 0)

__device__ __forceinline__ ushort f2bf(float f) {  // RNE float->bf16 bits
  unsigned u = __float_as_uint(f);
  u += 0x7fffu + ((u >> 16) & 1u);
  return (ushort)(u >> 16);
}
__device__ __forceinline__ unsigned cvt_pk_bf16(float lo, float hi) {
  unsigned r;
  asm("v_cvt_pk_bf16_f32 %0, %1, %2" : "=v"(r) : "v"(lo), "v"(hi));
  return r;
}
__device__ __forceinline__ float fast_exp2(float x) {  // 2^x, raw v_exp
  float r;
  asm("v_exp_f32 %0, %1" : "=v"(r) : "v"(x));
  return r;
}
__device__ __forceinline__ float gelu_tanh(float x) {
  const float z = 0.7978845608028654f * (x + 0.044715f * x * x * x);
  return x * (1.0f / (1.0f + __expf(-2.0f * z)));  // == 0.5x(1+tanh(z))
}
__device__ __forceinline__ f32x16 zero16() {
  f32x16 z;
#pragma unroll
  for (int i = 0; i < 16; ++i) z[i] = 0.f;
  return z;
}

// ---- top-k phase A: partial ranks over a 500-element j-slice (16-way split) ----
__global__ __launch_bounds__(256) void topk_partial(const float* __restrict__ sal,
                                                    int* __restrict__ partial) {
  const int b = blockIdx.z, jc = blockIdx.y;
  __shared__ float4 s4[JT / 4];
  const float4* src4 = reinterpret_cast<const float4*>(sal + (size_t)b * NTOK + jc * JT);
  for (int e = threadIdx.x; e < JT / 4; e += 256) s4[e] = src4[e];
  __syncthreads();
  const int i = blockIdx.x * 256 + threadIdx.x;
  if (i >= NTOK) return;
  const float si = sal[(size_t)b * NTOK + i];
  int rank = 0;
  const int jbase = jc * JT;
#pragma unroll 5
  for (int e = 0; e < JT / 4; ++e) {
    const float4 v = s4[e];
    const int j = jbase + e * 4;
    rank += (int)((v.x > si) || (v.x == si && j + 0 < i));
    rank += (int)((v.y > si) || (v.y == si && j + 1 < i));
    rank += (int)((v.z > si) || (v.z == si && j + 2 < i));
    rank += (int)((v.w > si) || (v.w == si && j + 3 < i));
  }
  partial[((size_t)jc * BATCH + b) * NTOK + i] = rank;
}

// ---- top-k phase B: sum partials, scatter rank<KCAP into sorted index list ----
__global__ __launch_bounds__(256) void topk_finalize(const int* __restrict__ partial,
                                                     int* __restrict__ sidx) {
  const int gid = blockIdx.x * 256 + threadIdx.x;
  if (gid >= BATCH * NTOK) return;
  const int b = gid / NTOK, i = gid - b * NTOK;
  int rank = 0;
#pragma unroll
  for (int jc = 0; jc < NSL; ++jc)
    rank += partial[((size_t)jc * BATCH + b) * NTOK + i];
  if (rank < KCAP) sidx[b * KCAP + rank] = i;
}

// ---- weight prep: fp32 W[l][K][N] -> bf16 MFMA K=16-fragment-major ----
// wf[l][g][sg][lane][e] = W[l][sg*16 + (lane>>5)*8 + e][g*32 + (lane&31)], e=0..7
template <int KD, int N, int LKS, int LN32>
__device__ __forceinline__ void wprep_one(const float* __restrict__ src,
                                          ushort* __restrict__ dst, int slot) {
  const int lane = slot & 63;
  const int sg = (slot >> 6) & ((1 << LKS) - 1);
  const int g = (slot >> (6 + LKS)) & ((1 << LN32) - 1);
  const int l = slot >> (6 + LKS + LN32);
  const int n = g * 32 + (lane & 31);
  const int k = sg * 16 + (lane >> 5) * 8;
  const float* s = src + ((size_t)l * KD + k) * N + n;
  union { uint4 q; ushort us[8]; } o;
#pragma unroll
  for (int e = 0; e < 8; ++e) o.us[e] = f2bf(s[(size_t)e * N]);
  *reinterpret_cast<uint4*>(dst + (size_t)slot * 8) = o.q;
}

__global__ __launch_bounds__(256) void wprep_kernel(
    const float* __restrict__ Wq, const float* __restrict__ Wk,
    const float* __restrict__ Wv, const float* __restrict__ Wo,
    const float* __restrict__ W1, const float* __restrict__ W2,
    ushort* __restrict__ wqt, ushort* __restrict__ wkt, ushort* __restrict__ wvt,
    ushort* __restrict__ wot, ushort* __restrict__ w1t, ushort* __restrict__ w2t) {
  const int z = blockIdx.z;
  const int slot = blockIdx.x * 256 + threadIdx.x;
  if (z < 4) {  // 256x256: N32=8, KS16=16 -> 32768 slots
    if (slot >= 4 * 8 * 16 * 64) return;
    const float* src = z == 0 ? Wq : (z == 1 ? Wk : (z == 2 ? Wv : Wo));
    ushort* dst = z == 0 ? wqt : (z == 1 ? wkt : (z == 2 ? wvt : wot));
    wprep_one<256, 256, 4, 3>(src, dst, slot);
  } else if (z == 4) {  // 256x1024: N32=32, KS16=16 -> 131072 slots
    if (slot >= 4 * 32 * 16 * 64) return;
    wprep_one<256, 1024, 4, 5>(W1, w1t, slot);
  } else {  // 1024x256: N32=8, KS16=64 -> 131072 slots
    if (slot >= 4 * 8 * 64 * 64) return;
    wprep_one<1024, 256, 6, 3>(W2, w2t, slot);
  }
}

// ---- gather + LayerNorm1 (layer 0 only): wave per token, writes x (f32) and h ----
__global__ __launch_bounds__(256) void gather_ln_kernel(
    const float* __restrict__ feat, const int* __restrict__ sidx,
    const float* __restrict__ g, const float* __restrict__ bb,
    float* __restrict__ x, ushort* __restrict__ h, int klen) {
  const int w = threadIdx.x >> 6, lane = threadIdx.x & 63;
  const int m = blockIdx.x * 4 + w;
  const int b = m / klen, t = m - b * klen;
  const int tok = sidx[b * KCAP + t];
  const float4 v4 =
      reinterpret_cast<const float4*>(feat + ((size_t)b * NTOK + tok) * DM)[lane];
  reinterpret_cast<float4*>(x + ((size_t)b * KCAP + t) * DM)[lane] = v4;
  float s = v4.x + v4.y + v4.z + v4.w;
#pragma unroll
  for (int off = 1; off < 64; off <<= 1) s += __shfl_xor(s, off);
  const float mu = s * (1.0f / DM);
  const float4 dv = {v4.x - mu, v4.y - mu, v4.z - mu, v4.w - mu};
  float vs = dv.x * dv.x + dv.y * dv.y + dv.z * dv.z + dv.w * dv.w;
#pragma unroll
  for (int off = 1; off < 64; off <<= 1) vs += __shfl_xor(vs, off);
  const float rstd = rsqrtf(vs * (1.0f / DM) + 1e-5f);
  const float4 g4 = reinterpret_cast<const float4*>(g)[lane];
  const float4 b4 = reinterpret_cast<const float4*>(bb)[lane];
  union { unsigned long long u; ushort us[4]; } o;
  o.us[0] = f2bf(dv.x * rstd * g4.x + b4.x);
  o.us[1] = f2bf(dv.y * rstd * g4.y + b4.y);
  o.us[2] = f2bf(dv.z * rstd * g4.z + b4.z);
  o.us[3] = f2bf(dv.w * rstd * g4.w + b4.w);
  reinterpret_cast<unsigned long long*>(h + ((size_t)b * KCAP + t) * DM)[lane] = o.u;
}

// ---- LayerNorm: wave per token, x (f32) -> h (bf16). Used for LN1 (l>=1) and LN2 ----
__global__ __launch_bounds__(256) void ln_kernel(
    const float* __restrict__ x, const float* __restrict__ g,
    const float* __restrict__ bb, ushort* __restrict__ h, int klen) {
  const int w = threadIdx.x >> 6, lane = threadIdx.x & 63;
  const int m = blockIdx.x * 4 + w;
  const int b = m / klen, t = m - b * klen;
  const float4 v4 = reinterpret_cast<const float4*>(x + ((size_t)b * KCAP + t) * DM)[lane];
  float s = v4.x + v4.y + v4.z + v4.w;
#pragma unroll
  for (int off = 1; off < 64; off <<= 1) s += __shfl_xor(s, off);
  const float mu = s * (1.0f / DM);
  const float4 dv = {v4.x - mu, v4.y - mu, v4.z - mu, v4.w - mu};
  float vs = dv.x * dv.x + dv.y * dv.y + dv.z * dv.z + dv.w * dv.w;
#pragma unroll
  for (int off = 1; off < 64; off <<= 1) vs += __shfl_xor(vs, off);
  const float rstd = rsqrtf(vs * (1.0f / DM) + 1e-5f);
  const float4 g4 = reinterpret_cast<const float4*>(g)[lane];
  const float4 b4 = reinterpret_cast<const float4*>(bb)[lane];
  union { unsigned long long u; ushort us[4]; } o;
  o.us[0] = f2bf(dv.x * rstd * g4.x + b4.x);
  o.us[1] = f2bf(dv.y * rstd * g4.y + b4.y);
  o.us[2] = f2bf(dv.z * rstd * g4.z + b4.z);
  o.us[3] = f2bf(dv.w * rstd * g4.w + b4.w);
  reinterpret_cast<unsigned long long*>(h + ((size_t)b * KCAP + t) * DM)[lane] = o.u;
}

// ---- GEMM core: block = 32 rows x 256 cols, wave = 32x64 (2 acc tiles) ----
// A row-major [t][APITCH] bf16 staged to LDS (XOR-swizzled, same tile as before);
// B fragment-major K=16. One K=16 A-frag = two existing u64 quads (base, base+32).
template <int APITCH, int KCHUNKS>
__device__ __forceinline__ void gemm_core(
    const ushort* __restrict__ A, const ushort* __restrict__ wf,
    unsigned long long* lA, int b, int t0, int klen, f32x16& acc0, f32x16& acc1) {
  const int tid = threadIdx.x;
  const int lane = tid & 63, l31 = lane & 31, hi = lane >> 5, w = tid >> 6;
  const int srow = tid >> 5, sl = tid & 31;
  acc0 = zero16();
  acc1 = zero16();
  const ushort* w0 = wf + (size_t)(w * 2) * (KCHUNKS * 8192) + lane * 8;
  const ushort* w1p = w0 + (size_t)KCHUNKS * 8192;
  for (int kc = 0; kc < KCHUNKS; ++kc) {
    if (kc) __syncthreads();
#pragma unroll
    for (int p = 0; p < 4; ++p) {
      const int row = p * 8 + srow;
      const size_t grow = (size_t)(b * KCAP + min(t0 + row, klen - 1));
      union { uint4 q; unsigned long long d[2]; } u;
      u.q = *reinterpret_cast<const uint4*>(A + grow * APITCH + kc * 256 + sl * 8);
      const int rx = row ^ (sl & 15);
      lA[(sl * 2) * 32 + rx] = u.d[0];
      lA[(sl * 2 + 1) * 32 + rx] = u.d[1];
    }
    __syncthreads();
    const ushort* wc0 = w0 + (size_t)kc * 8192;
    const ushort* wc1 = w1p + (size_t)kc * 8192;
#pragma unroll 8
    for (int s = 0; s < 16; ++s) {
      union { unsigned long long d[2]; s16x8 v; } a;
      const int base = (4 * s + 2 * hi) * 32 + (l31 ^ ((2 * s + hi) & 15));
      a.d[0] = lA[base];
      a.d[1] = lA[base + 32];
      const s16x8 b0 = *reinterpret_cast<const s16x8*>(wc0 + s * 512);
      const s16x8 b1 = *reinterpret_cast<const s16x8*>(wc1 + s * 512);
      acc0 = MFMA16(a.v, b0, acc0);
      acc1 = MFMA16(a.v, b1, acc1);
    }
  }
}

// ---- fused Q/K/V projection (blockIdx.y selects q/k/v) ----
// Q pre-scaled by (1/sqrt(32))*log2(e) so attention works in log2 units.
__global__ __launch_bounds__(256) void qkv_kernel(
    const ushort* __restrict__ hb, const ushort* __restrict__ wq,
    const ushort* __restrict__ wk, const ushort* __restrict__ wv,
    ushort* __restrict__ qh, ushort* __restrict__ Kf, ushort* __restrict__ Vf,
    int klen) {
  __shared__ unsigned long long lA[2048];
  const int z = blockIdx.y;
  const ushort* wf = z == 0 ? wq : (z == 1 ? wk : wv);
  const int nrb = (klen + 31) >> 5;
  const int b = blockIdx.x / nrb;
  const int t0 = (blockIdx.x - b * nrb) * 32;
  f32x16 a0, a1;
  gemm_core<256, 1>(hb, wf, lA, b, t0, klen, a0, a1);
  const int lane = threadIdx.x & 63, l31 = lane & 31, hi = lane >> 5;
  const int w = threadIdx.x >> 6;
  const int hi4 = 4 * hi;
#pragma unroll
  for (int blk = 0; blk < 2; ++blk) {
    const f32x16& acc = blk ? a1 : a0;
    const int hh = w * 2 + blk;
    const int bh = b * 8 + hh;
    if (z == 0) {  // Q pre-scaled (log2 units), head layout [bh][t][32]
#pragma unroll
      for (int r = 0; r < 16; ++r) {
        const int gm = t0 + ((r & 3) + 8 * (r >> 2) + hi4);
        if (gm < klen)
          qh[((size_t)bh * KCAP + gm) * 32 + l31] =
              f2bf(acc[r] * (0.17677669529663687f * 1.4426950408889634f));
      }
    } else if (z == 1) {  // K fragment-major (K=8 frags for attention)
#pragma unroll
      for (int r = 0; r < 16; ++r) {
        const int gm = t0 + ((r & 3) + 8 * (r >> 2) + hi4);
        const int kb = gm >> 5, k31 = gm & 31;
        const int dc = l31 >> 3, hi2 = (l31 >> 2) & 1, e = l31 & 3;
        Kf[(((size_t)bh * NB32 + kb) * 4 + dc) * 256 + (hi2 * 32 + k31) * 4 + e] =
            f2bf(acc[r]);
      }
    } else {  // V fragment-major
#pragma unroll
      for (int r = 0; r < 16; ++r) {
        const int gm = t0 + ((r & 3) + 8 * (r >> 2) + hi4);
        const int kb = gm >> 5, k31 = gm & 31;
        const int kc = k31 >> 3, hi2 = (k31 >> 2) & 1, e = k31 & 3;
        Vf[(((size_t)bh * NB32 + kb) * 4 + kc) * 256 + (hi2 * 32 + l31) * 4 + e] =
            f2bf(acc[r]);
      }
    }
  }
}

// ---- residual GEMM: xb += A @ W (used for Wo and W2, in-place accumulate) ----
template <int APITCH, int KCHUNKS>
__global__ __launch_bounds__(256) void resadd_kernel(const ushort* __restrict__ A,
                                                     const ushort* __restrict__ wf,
                                                     float* __restrict__ xb, int klen) {
  __shared__ unsigned long long lA[2048];
  const int nrb = (klen + 31) >> 5;
  const int b = blockIdx.x / nrb;
  const int t0 = (blockIdx.x - b * nrb) * 32;
  f32x16 a0, a1;
  gemm_core<APITCH, KCHUNKS>(A, wf, lA, b, t0, klen, a0, a1);
  const int lane = threadIdx.x & 63, l31 = lane & 31, hi = lane >> 5;
  const int w = threadIdx.x >> 6;
  const int hi4 = 4 * hi;
#pragma unroll
  for (int blk = 0; blk < 2; ++blk) {
    const f32x16& acc = blk ? a1 : a0;
    const int n = w * 64 + blk * 32 + l31;
#pragma unroll
    for (int r = 0; r < 16; ++r) {
      const int gm = t0 + ((r & 3) + 8 * (r >> 2) + hi4);
      if (gm < klen) {
        const size_t off = ((size_t)b * KCAP + gm) * DM + n;
        xb[off] += acc[r];
      }
    }
  }
}

// ---- W1 GEMM: fb = gelu(hb @ W1), blockIdx.y = 256-col group ----
__global__ __launch_bounds__(256) void w1_kernel(const ushort* __restrict__ hb,
                                                 const ushort* __restrict__ w1,
                                                 ushort* __restrict__ fb, int klen) {
  __shared__ unsigned long long lA[2048];
  const int nrb = (klen + 31) >> 5;
  const int b = blockIdx.x / nrb;
  const int t0 = (blockIdx.x - b * nrb) * 32;
  const ushort* wf = w1 + (size_t)blockIdx.y * 65536;
  f32x16 a0, a1;
  gemm_core<256, 1>(hb, wf, lA, b, t0, klen, a0, a1);
  const int lane = threadIdx.x & 63, l31 = lane & 31, hi = lane >> 5;
  const int w = threadIdx.x >> 6;
  const int hi4 = 4 * hi;
#pragma unroll
  for (int blk = 0; blk < 2; ++blk) {
    const f32x16& acc = blk ? a1 : a0;
    const int n = blockIdx.y * 256 + w * 64 + blk * 32 + l31;
#pragma unroll
    for (int r = 0; r < 16; ++r) {
      const int gm = t0 + ((r & 3) + 8 * (r >> 2) + hi4);
      if (gm < klen)
        fb[((size_t)b * KCAP + gm) * DFF + n] = f2bf(gelu_tanh(acc[r]));
    }
  }
}

// ---- flash attention: block = one 32-q tile, 4 waves split keys 4-way ----
// Fixed-base softmax: S accumulator init = -M0 (log2 units); p = 2^s directly.
#define M0 12.0f
__global__ __launch_bounds__(256) void attn_kernel(
    const ushort* __restrict__ Q, const ushort* __restrict__ Kf,
    const ushort* __restrict__ Vf, ushort* __restrict__ O, int klen) {
  const int hh = blockIdx.y, b = blockIdx.z;
  const int bh = b * 8 + hh;
  const int tid = threadIdx.x;
  const int w = tid >> 6, lane = tid & 63, l31 = lane & 31, hi = lane >> 5;
  __shared__ float red[3 * 64 * 17];  // waves 1-3 partials: o[16], l (stride 17)
  const int q0 = blockIdx.x * 32;
  const int qg = min(q0 + l31, klen - 1);
  const ushort* qrow = Q + ((size_t)bh * KCAP + qg) * 32;
  const s16x4 qf0 = *reinterpret_cast<const s16x4*>(qrow + 0 + hi * 4);
  const s16x4 qf1 = *reinterpret_cast<const s16x4*>(qrow + 8 + hi * 4);
  const s16x4 qf2 = *reinterpret_cast<const s16x4*>(qrow + 16 + hi * 4);
  const s16x4 qf3 = *reinterpret_cast<const s16x4*>(qrow + 24 + hi * 4);
  const ushort* kfp = Kf + (size_t)bh * NB32 * 1024 + lane * 4;
  const ushort* vfp = Vf + (size_t)bh * NB32 * 1024 + lane * 4;
  f32x16 oacc = zero16();
  float lrun = 0.f;
  const int nb = (klen + 31) >> 5;
  const int qq = nb >> 2, rr = nb & 3;
  const int kb0 = w * qq + min(w, rr);
  const int kbn = kb0 + qq + (w < rr ? 1 : 0);
  for (int kb = kb0; kb < kbn; ++kb) {
    const ushort* kb_ = kfp + (size_t)kb * 1024;
    const ushort* vb_ = vfp + (size_t)kb * 1024;
    const s16x4 kf0 = *reinterpret_cast<const s16x4*>(kb_ + 0);
    const s16x4 kf1 = *reinterpret_cast<const s16x4*>(kb_ + 256);
    const s16x4 kf2 = *reinterpret_cast<const s16x4*>(kb_ + 512);
    const s16x4 kf3 = *reinterpret_cast<const s16x4*>(kb_ + 768);
    const s16x4 vf0 = *reinterpret_cast<const s16x4*>(vb_ + 0);
    const s16x4 vf1 = *reinterpret_cast<const s16x4*>(vb_ + 256);
    const s16x4 vf2 = *reinterpret_cast<const s16x4*>(vb_ + 512);
    const s16x4 vf3 = *reinterpret_cast<const s16x4*>(vb_ + 768);
    f32x16 s;
#pragma unroll
    for (int r = 0; r < 16; ++r) s[r] = -M0;  // bias folded into accumulator
    s = MFMA_B(kf0, qf0, s);
    s = MFMA_B(kf1, qf1, s);
    s = MFMA_B(kf2, qf2, s);
    s = MFMA_B(kf3, qf3, s);
    if ((kb << 5) + 32 > klen) {  // mask tail keys (pad K zero-filled)
#pragma unroll
      for (int r = 0; r < 16; ++r) {
        const int key = (kb << 5) + (r & 3) + 8 * (r >> 2) + 4 * hi;
        if (key >= klen) s[r] = -1e30f;
      }
    }
    float p[16];
    float ps = 0.f;
#pragma unroll
    for (int r = 0; r < 16; ++r) {
      p[r] = fast_exp2(s[r]);  // p = 2^(S*log2e - M0): exact softmax ratio
      ps += p[r];
    }
    lrun += ps;
    unsigned pw[8];
#pragma unroll
    for (int i = 0; i < 8; ++i) pw[i] = cvt_pk_bf16(p[2 * i], p[2 * i + 1]);
#pragma unroll
    for (int kc = 0; kc < 4; ++kc) {
      union { unsigned u[2]; s16x4 v; } pf;
      pf.u[0] = pw[2 * kc];
      pf.u[1] = pw[2 * kc + 1];
      const s16x4 vf = kc == 0 ? vf0 : (kc == 1 ? vf1 : (kc == 2 ? vf2 : vf3));
      oacc = MFMA_B(vf, pf.v, oacc);  // O^T[d][q]
    }
  }
  // fixed base -> partials merge by plain summation
  if (w) {
    float* myr = red + ((w - 1) * 64 + lane) * 17;
#pragma unroll
    for (int r = 0; r < 16; ++r) myr[r] = oacc[r];
    myr[16] = lrun;
  }
  __syncthreads();
  if (w == 0) {
#pragma unroll
    for (int w2 = 0; w2 < 3; ++w2) {
      const float* pr = red + (w2 * 64 + lane) * 17;
#pragma unroll
      for (int r = 0; r < 16; ++r) oacc[r] += pr[r];
      lrun += pr[16];
    }
    const float ltot = lrun + __shfl_xor(lrun, 32);
    const float inv = 1.0f / ltot;
    if (q0 + l31 < klen) {
      ushort* orow = O + ((size_t)b * KCAP + q0 + l31) * DM + hh * 32;
#pragma unroll
      for (int rq = 0; rq < 4; ++rq) {
        union { unsigned u[2]; unsigned long long u64; } o4;
        o4.u[0] = cvt_pk_bf16(oacc[4 * rq] * inv, oacc[4 * rq + 1] * inv);
        o4.u[1] = cvt_pk_bf16(oacc[4 * rq + 2] * inv, oacc[4 * rq + 3] * inv);
        *reinterpret_cast<unsigned long long*>(orow + 8 * rq + 4 * hi) = o4.u64;
      }
    }
  }
}

// ---- final scatter: feature bank gets each rank's last-updated row ----
__global__ __launch_bounds__(256) void scatter_kernel(
    const float* __restrict__ x, const int* __restrict__ sidx,
    float* __restrict__ feat) {
  const int gid = blockIdx.x * 256 + threadIdx.x;
  const int m = gid >> 6, li = gid & 63;
  const int b = m / KCAP, t = m - b * KCAP;
  const int tok = sidx[b * KCAP + t];
  reinterpret_cast<float4*>(feat + ((size_t)b * NTOK + tok) * DM)[li] =
      reinterpret_cast<const float4*>(x + ((size_t)b * KCAP + t) * DM)[li];
}

extern "C" void kernel_launch(void* const* d_in, const int* in_sizes, int n_in,
                              void* d_out, int out_size, void* d_ws, size_t ws_size,
                              hipStream_t stream) {
  (void)in_sizes; (void)n_in; (void)out_size; (void)ws_size;
  const float* features = (const float*)d_in[0];
  const float* salience = (const float*)d_in[1];
  const float* Wq = (const float*)d_in[2];
  const float* Wk = (const float*)d_in[3];
  const float* Wv = (const float*)d_in[4];
  const float* Wo = (const float*)d_in[5];
  const float* W1 = (const float*)d_in[6];
  const float* W2 = (const float*)d_in[7];
  const float* ln1g = (const float*)d_in[8];
  const float* ln1b = (const float*)d_in[9];
  const float* ln2g = (const float*)d_in[10];
  const float* ln2b = (const float*)d_in[11];
  float* out = (float*)d_out;

  // workspace layout
  const size_t SLAB = (size_t)BATCH * KCAP * DM;
  char* p = (char*)d_ws;
  int* sidx = (int*)p;                 p += 32768;
  int* partial = (int*)p;              p += (size_t)NSL * BATCH * NTOK * 4;
  float* xb = (float*)p;               p += SLAB * 4;   // persistent token rows (f32)
  ushort* hb = (ushort*)p;             p += SLAB * 2;
  ushort* qh = (ushort*)p;             p += SLAB * 2;
  ushort* Kf = (ushort*)p;             p += SLAB * 2;
  ushort* Vf = (ushort*)p;             p += SLAB * 2;
  ushort* ob = (ushort*)p;             p += SLAB * 2;
  ushort* fb = qh;  // FFN intermediate (13.1MB) overlays qh|Kf|Vf|ob
  ushort* wqt = (ushort*)p;            p += (size_t)4 * 256 * 256 * 2;
  ushort* wkt = (ushort*)p;            p += (size_t)4 * 256 * 256 * 2;
  ushort* wvt = (ushort*)p;            p += (size_t)4 * 256 * 256 * 2;
  ushort* wot = (ushort*)p;            p += (size_t)4 * 256 * 256 * 2;
  ushort* w1t = (ushort*)p;            p += (size_t)4 * 256 * 1024 * 2;
  ushort* w2t = (ushort*)p;            p += (size_t)4 * 1024 * 256 * 2;

  hipMemcpyAsync(out, features, (size_t)BATCH * NTOK * DM * sizeof(float),
                 hipMemcpyDeviceToDevice, stream);
  topk_partial<<<dim3((NTOK + 255) / 256, NSL, BATCH), 256, 0, stream>>>(salience,
                                                                         partial);
  topk_finalize<<<(BATCH * NTOK + 255) / 256, 256, 0, stream>>>(partial, sidx);
  wprep_kernel<<<dim3(512, 1, 6), 256, 0, stream>>>(Wq, Wk, Wv, Wo, W1, W2, wqt,
                                                    wkt, wvt, wot, w1t, w2t);

  const int klens[4] = {3200, 2400, 2000, 1600};
  for (int l = 0; l < 4; ++l) {
    const int klen = klens[l];
    const int nrb = (klen + 31) >> 5;  // 32-row tiles
    const size_t wsq = (size_t)l * 256 * 256;
    const size_t wff = (size_t)l * 256 * 1024;
    if (l == 0) {
      gather_ln_kernel<<<klen / 2, 256, 0, stream>>>(out, sidx, ln1g, ln1b, xb, hb,
                                                     klen);
    } else {
      // nested-prefix top-k: rows of xb persist across layers, no re-gather
      ln_kernel<<<klen / 2, 256, 0, stream>>>(xb, ln1g + l * DM, ln1b + l * DM, hb,
                                              klen);
    }
    qkv_kernel<<<dim3(2 * nrb, 3), 256, 0, stream>>>(
        hb, wqt + wsq, wkt + wsq, wvt + wsq, qh, Kf, Vf, klen);
    attn_kernel<<<dim3(nrb, 8, BATCH), 256, 0, stream>>>(qh, Kf, Vf, ob, klen);
    resadd_kernel<256, 1><<<dim3(2 * nrb, 1), 256, 0, stream>>>(ob, wot + wsq, xb,
                                                                klen);
    ln_kernel<<<klen / 2, 256, 0, stream>>>(xb, ln2g + l * DM, ln2b + l * DM, hb,
                                            klen);
    w1_kernel<<<dim3(2 * nrb, 4), 256, 0, stream>>>(hb, w1t + wff, fb, klen);
    resadd_kernel<1024, 4><<<dim3(2 * nrb, 1), 256, 0, stream>>>(fb, w2t + wff, xb,
                                                                 klen);
  }
  scatter_kernel<<<BATCH * KCAP / 4, 256, 0, stream>>>(xb, sidx, out);
}